// Round 3
// baseline (3854.251 us; speedup 1.0000x reference)
//
#include <hip/hip_runtime.h>
#include <hip/hip_bf16.h>

constexpr int SEQ    = 2048;
constexpr int HIDDEN = 2048;
constexpr int NHQ    = 16;
constexpr int DIM    = 128;
constexpr int NCB    = 64;
constexpr int NTOP   = 8;
constexpr int WINSZ  = 512;

#define SCALEF 0.08838834764831845f
#define NEGF  -1e30f

using short8 = __attribute__((ext_vector_type(8))) short;
using f32x4  = __attribute__((ext_vector_type(4))) float;

__device__ inline unsigned short f2bf(float f) {
    unsigned u = __float_as_uint(f);
    unsigned r = (u + 0x7fffu + ((u >> 16) & 1u)) >> 16;
    return (unsigned short)r;
}
__device__ inline float bf2f(unsigned short b) {
    return __uint_as_float(((unsigned)b) << 16);
}
__device__ inline float sigmoidf_(float x) { return 1.0f / (1.0f + __expf(-x)); }

// ---------------------------------------------------------------------------
// split fp32 -> (hi, lo) bf16 pair, elementwise. n % 1024 == 0.
// ---------------------------------------------------------------------------
__global__ __launch_bounds__(256) void split_pair(const float* __restrict__ in,
                                                  unsigned short* __restrict__ hi,
                                                  unsigned short* __restrict__ lo) {
    int i = (blockIdx.x * 256 + threadIdx.x) * 4;
    float4 v = *(const float4*)&in[i];
    ushort4 h, l;
    h.x = f2bf(v.x); l.x = f2bf(v.x - bf2f(h.x));
    h.y = f2bf(v.y); l.y = f2bf(v.y - bf2f(h.y));
    h.z = f2bf(v.z); l.z = f2bf(v.z - bf2f(h.z));
    h.w = f2bf(v.w); l.w = f2bf(v.w - bf2f(h.w));
    *(ushort4*)&hi[i] = h;
    *(ushort4*)&lo[i] = l;
}

// ---------------------------------------------------------------------------
// transpose + split: W[K][N] fp32 -> Th/Tl[N][K] bf16 hi/lo. 32x32 tiles.
// ---------------------------------------------------------------------------
__global__ __launch_bounds__(256) void tsplit(const float* __restrict__ W,
                                              unsigned short* __restrict__ Th,
                                              unsigned short* __restrict__ Tl) {
    __shared__ float t[32][33];
    const int k0 = blockIdx.y * 32, n0 = blockIdx.x * 32;
    const int ty = threadIdx.x >> 3, tx = threadIdx.x & 7;
    float4 v = *(const float4*)&W[(size_t)(k0 + ty) * HIDDEN + n0 + tx * 4];
    t[ty][tx * 4 + 0] = v.x; t[ty][tx * 4 + 1] = v.y;
    t[ty][tx * 4 + 2] = v.z; t[ty][tx * 4 + 3] = v.w;
    __syncthreads();
    ushort4 h, l;
    float a0 = t[tx * 4 + 0][ty], a1 = t[tx * 4 + 1][ty];
    float a2 = t[tx * 4 + 2][ty], a3 = t[tx * 4 + 3][ty];
    h.x = f2bf(a0); l.x = f2bf(a0 - bf2f(h.x));
    h.y = f2bf(a1); l.y = f2bf(a1 - bf2f(h.y));
    h.z = f2bf(a2); l.z = f2bf(a2 - bf2f(h.z));
    h.w = f2bf(a3); l.w = f2bf(a3 - bf2f(h.w));
    *(ushort4*)&Th[(size_t)(n0 + ty) * HIDDEN + k0 + tx * 4] = h;
    *(ushort4*)&Tl[(size_t)(n0 + ty) * HIDDEN + k0 + tx * 4] = l;
}

// ---------------------------------------------------------------------------
// Split-bf16 MFMA GEMM (fp32-grade): C = (Ah+Al) * (Bh+Bl)^T.
// A*: [M][K] bf16 row-major. B*: [N][K] bf16 row-major (pre-transposed).
// 128x128 tile, BK=32, 4 waves (2x2), 16x16x32 MFMA, 4x4 frags/wave,
// 3 MFMA per fragment pair (drop al*bl ~ 2^-18).
// ---------------------------------------------------------------------------
__global__ __launch_bounds__(256) void gemm3s(const unsigned short* __restrict__ Ah,
                                              const unsigned short* __restrict__ Al,
                                              const unsigned short* __restrict__ Bh,
                                              const unsigned short* __restrict__ Bl,
                                              float* __restrict__ C,
                                              int M, int N, int K) {
    __shared__ unsigned short sAh[4][128][8], sAl[4][128][8];
    __shared__ unsigned short sBh[4][128][8], sBl[4][128][8];
    const int tid = threadIdx.x, lane = tid & 63, wave = tid >> 6;
    const int wr = wave >> 1, wc = wave & 1;
    const int brow = blockIdx.y * 128, bcol = blockIdx.x * 128;
    const int lr = lane & 15, lc = lane >> 4;
    const int sr = tid & 127, sc0 = tid >> 7;

    f32x4 acc[4][4];
    #pragma unroll
    for (int a = 0; a < 4; ++a)
        #pragma unroll
        for (int b = 0; b < 4; ++b) acc[a][b] = (f32x4){0.f, 0.f, 0.f, 0.f};

    for (int k0 = 0; k0 < K; k0 += 32) {
        #pragma unroll
        for (int i = 0; i < 2; ++i) {
            int c = i * 2 + sc0;
            size_t ao = (size_t)(brow + sr) * K + k0 + c * 8;
            size_t bo = (size_t)(bcol + sr) * K + k0 + c * 8;
            *(short8*)&sAh[c][sr][0] = *(const short8*)&Ah[ao];
            *(short8*)&sAl[c][sr][0] = *(const short8*)&Al[ao];
            *(short8*)&sBh[c][sr][0] = *(const short8*)&Bh[bo];
            *(short8*)&sBl[c][sr][0] = *(const short8*)&Bl[bo];
        }
        __syncthreads();
        short8 fah[4], fal[4], fbh[4], fbl[4];
        #pragma unroll
        for (int mi = 0; mi < 4; ++mi) {
            fah[mi] = *(short8*)&sAh[lc][wr * 64 + mi * 16 + lr][0];
            fal[mi] = *(short8*)&sAl[lc][wr * 64 + mi * 16 + lr][0];
        }
        #pragma unroll
        for (int ni = 0; ni < 4; ++ni) {
            fbh[ni] = *(short8*)&sBh[lc][wc * 64 + ni * 16 + lr][0];
            fbl[ni] = *(short8*)&sBl[lc][wc * 64 + ni * 16 + lr][0];
        }
        #pragma unroll
        for (int mi = 0; mi < 4; ++mi)
            #pragma unroll
            for (int ni = 0; ni < 4; ++ni) {
                acc[mi][ni] = __builtin_amdgcn_mfma_f32_16x16x32_bf16(fah[mi], fbh[ni], acc[mi][ni], 0, 0, 0);
                acc[mi][ni] = __builtin_amdgcn_mfma_f32_16x16x32_bf16(fal[mi], fbh[ni], acc[mi][ni], 0, 0, 0);
                acc[mi][ni] = __builtin_amdgcn_mfma_f32_16x16x32_bf16(fah[mi], fbl[ni], acc[mi][ni], 0, 0, 0);
            }
        __syncthreads();
    }
    #pragma unroll
    for (int mi = 0; mi < 4; ++mi)
        #pragma unroll
        for (int ni = 0; ni < 4; ++ni) {
            int col  = bcol + wc * 64 + ni * 16 + lr;
            int rowb = brow + wr * 64 + mi * 16 + lc * 4;
            #pragma unroll
            for (int r = 0; r < 4; ++r)
                C[(size_t)(rowb + r) * N + col] = acc[mi][ni][r];
        }
}

// ---------------------------------------------------------------------------
// Narrow fp32 GEMM (k/v/gate projections). BM=32,BN=64,BK=32.
// ---------------------------------------------------------------------------
__global__ __launch_bounds__(256) void gemm_small(const float* __restrict__ A,
                                                  const float* __restrict__ B,
                                                  float* __restrict__ C,
                                                  int M, int Nd, int K) {
    __shared__ float As[32][33];
    __shared__ float Bs[32][64];
    const int tid  = threadIdx.x;
    const int brow = blockIdx.y * 32;
    const int bcol = blockIdx.x * 64;
    const int ty = tid >> 4, tx = tid & 15;
    float acc[2][4] = {{0.f,0.f,0.f,0.f},{0.f,0.f,0.f,0.f}};

    for (int k0 = 0; k0 < K; k0 += 32) {
        for (int t = tid; t < 1024; t += 256) {
            int r = t >> 5, c = t & 31;
            As[c][r] = A[(size_t)(brow + r) * K + k0 + c];
        }
        for (int t = tid; t < 2048; t += 256) {
            int r = t >> 6, c = t & 63;
            int col = bcol + c;
            Bs[r][c] = (col < Nd) ? B[(size_t)(k0 + r) * Nd + col] : 0.f;
        }
        __syncthreads();
        #pragma unroll 8
        for (int kk = 0; kk < 32; ++kk) {
            float a0 = As[kk][ty * 2], a1 = As[kk][ty * 2 + 1];
            float b0 = Bs[kk][tx * 4], b1 = Bs[kk][tx * 4 + 1];
            float b2 = Bs[kk][tx * 4 + 2], b3 = Bs[kk][tx * 4 + 3];
            acc[0][0] = fmaf(a0, b0, acc[0][0]); acc[0][1] = fmaf(a0, b1, acc[0][1]);
            acc[0][2] = fmaf(a0, b2, acc[0][2]); acc[0][3] = fmaf(a0, b3, acc[0][3]);
            acc[1][0] = fmaf(a1, b0, acc[1][0]); acc[1][1] = fmaf(a1, b1, acc[1][1]);
            acc[1][2] = fmaf(a1, b2, acc[1][2]); acc[1][3] = fmaf(a1, b3, acc[1][3]);
        }
        __syncthreads();
    }
    for (int ii = 0; ii < 2; ++ii)
        for (int j = 0; j < 4; ++j) {
            int col = bcol + tx * 4 + j;
            if (col < Nd)
                C[(size_t)(brow + ty * 2 + ii) * Nd + col] = acc[ii][j];
        }
}

// ---------------------------------------------------------------------------
// Compress: ck[m]=rope(mean(k+pe), pos=32m), cv[m]=mean(v). Un-roped k input.
// ---------------------------------------------------------------------------
__global__ void compress_kernel(const float* __restrict__ k,
                                const float* __restrict__ v,
                                const float* __restrict__ pe,
                                float* __restrict__ ck,
                                float* __restrict__ cv) {
    int m = blockIdx.x, d = threadIdx.x;
    float sk = 0.f, sv = 0.f, sp = 0.f;
    for (int s = 0; s < 32; ++s) {
        sk += k[(size_t)(m * 32 + s) * DIM + d];
        sv += v[(size_t)(m * 32 + s) * DIM + d];
        sp += pe[s * DIM + d];
    }
    float ckv = (sk + sp) * (1.0f / 32.0f);
    cv[m * DIM + d] = sv * (1.0f / 32.0f);
    __shared__ float tmp[DIM];
    tmp[d] = ckv;
    __syncthreads();
    int j = d & 63;
    float inv = powf(10000.0f, -(float)(2 * j) / 128.0f);
    float ang = (float)(m * 32) * inv;
    float c = cosf(ang), s = sinf(ang);
    float x1 = tmp[j], x2 = tmp[j + 64];
    ck[m * DIM + d] = (d < 64) ? (x1 * c - x2 * s) : (x2 * c + x1 * s);
}

__global__ void rope_qk(float* __restrict__ q, float* __restrict__ k) {
    int i = blockIdx.x, j = threadIdx.x;
    float inv = powf(10000.0f, -(float)(2 * j) / 128.0f);
    float ang = (float)i * inv;
    float c = cosf(ang), s = sinf(ang);
    for (int h = 0; h < NHQ; ++h) {
        float* p = q + ((size_t)i * NHQ + h) * DIM;
        float x1 = p[j], x2 = p[j + 64];
        p[j]      = x1 * c - x2 * s;
        p[j + 64] = x2 * c + x1 * s;
    }
    float* p = k + (size_t)i * DIM;
    float x1 = p[j], x2 = p[j + 64];
    p[j]      = x1 * c - x2 * s;
    p[j + 64] = x2 * c + x1 * s;
}

// ---------------------------------------------------------------------------
// Compressed attention per token: writes comb (fp32, full init) + blk scores.
// ---------------------------------------------------------------------------
__global__ __launch_bounds__(256) void cmp_flash(const float* __restrict__ q,
                                                 const float* __restrict__ ck,
                                                 const float* __restrict__ cv,
                                                 const float* __restrict__ gl,
                                                 float* __restrict__ comb,
                                                 float* __restrict__ blk) {
    const int i = blockIdx.x, tid = threadIdx.x, wave = tid >> 6, lane = tid & 63;
    __shared__ float Qs[16][132];
    __shared__ float KV[64][132];
    __shared__ float ss[16][66];

    for (int t = tid; t < 512; t += 256) {
        int r = t >> 5, c4 = (t & 31) * 4;
        *(float4*)&Qs[r][c4] = *(const float4*)&q[(size_t)i * HIDDEN + r * DIM + c4];
    }
    for (int t = tid; t < 2048; t += 256) {
        int r = t >> 5, c4 = (t & 31) * 4;
        *(float4*)&KV[r][c4] = *(const float4*)&ck[(size_t)r * DIM + c4];
    }
    __syncthreads();

    const int hi = lane & 15, mg = lane >> 4;
    float s4[4] = {0.f, 0.f, 0.f, 0.f};
    for (int d = 0; d < 128; d += 4) {
        float4 qv = *(float4*)&Qs[hi][d];
        #pragma unroll
        for (int jj = 0; jj < 4; ++jj) {
            float4 kv = *(float4*)&KV[wave * 16 + mg * 4 + jj][d];
            s4[jj] = fmaf(qv.x, kv.x, fmaf(qv.y, kv.y, fmaf(qv.z, kv.z, fmaf(qv.w, kv.w, s4[jj]))));
        }
    }
    #pragma unroll
    for (int jj = 0; jj < 4; ++jj) {
        int m = wave * 16 + mg * 4 + jj;
        ss[hi][m] = (i >= m * 32 + 31) ? s4[jj] * SCALEF : NEGF;
    }
    __syncthreads();

    for (int hh = 0; hh < 4; ++hh) {
        int h = wave * 4 + hh;
        float val = ss[h][lane];
        float mx = val;
        for (int o = 32; o; o >>= 1) mx = fmaxf(mx, __shfl_xor(mx, o));
        float e = (val <= NEGF * 0.5f) ? 0.f : __expf(val - mx);
        float z = e;
        for (int o = 32; o; o >>= 1) z += __shfl_xor(z, o);
        ss[h][lane] = (z > 0.f) ? e * (1.0f / z) : 0.f;
    }
    __syncthreads();

    if (tid < 64) {
        float sb = 0.f;
        for (int h = 0; h < 16; ++h) sb += ss[h][tid];
        blk[(size_t)i * NCB + tid] = sb;
    }

    for (int t = tid; t < 2048; t += 256) {
        int r = t >> 5, c4 = (t & 31) * 4;
        *(float4*)&KV[r][c4] = *(const float4*)&cv[(size_t)r * DIM + c4];
    }
    __syncthreads();

    const int h2 = tid & 15, dg = tid >> 4;
    float o8[8] = {0.f,0.f,0.f,0.f,0.f,0.f,0.f,0.f};
    for (int kk = 0; kk < 64; ++kk) {
        float p = ss[h2][kk];
        float4 va = *(float4*)&KV[kk][dg * 8];
        float4 vb = *(float4*)&KV[kk][dg * 8 + 4];
        o8[0] = fmaf(p, va.x, o8[0]); o8[1] = fmaf(p, va.y, o8[1]);
        o8[2] = fmaf(p, va.z, o8[2]); o8[3] = fmaf(p, va.w, o8[3]);
        o8[4] = fmaf(p, vb.x, o8[4]); o8[5] = fmaf(p, vb.y, o8[5]);
        o8[6] = fmaf(p, vb.z, o8[6]); o8[7] = fmaf(p, vb.w, o8[7]);
    }
    float g0 = sigmoidf_(gl[(size_t)i * 48 + h2 * 3 + 0]);
    #pragma unroll
    for (int x = 0; x < 8; ++x)
        comb[(size_t)i * HIDDEN + h2 * DIM + dg * 8 + x] = g0 * o8[x];
}

// ---------------------------------------------------------------------------
// Top-k (exact jax.lax.top_k tie semantics). LDS-staged, 256 tokens/block.
// ---------------------------------------------------------------------------
__global__ __launch_bounds__(256) void topk2(const float* __restrict__ blk,
                                             int* __restrict__ oidx) {
    __shared__ float L[256][68];
    int base = blockIdx.x * 256;
    for (int t = threadIdx.x; t < 256 * 16; t += 256) {
        int r = t >> 4, c4 = (t & 15) * 4;
        *(float4*)&L[r][c4] = *(const float4*)&blk[(size_t)(base + r) * NCB + c4];
    }
    __syncthreads();
    int i = base + threadIdx.x;
    int tb = i >> 5;
    unsigned long long used = 0ull;
    for (int t = 0; t < NTOP; ++t) {
        float best = -3e38f; int bi = 0;
        for (int m = 0; m < NCB; ++m) {
            if ((used >> m) & 1ull) continue;
            float s = L[threadIdx.x][m];
            if (m > tb) s = NEGF;
            if (m == 0 || (m <= tb && m > tb - 2)) s = 1e30f;
            if (s > best) { best = s; bi = m; }
        }
        used |= 1ull << bi;
        oidx[i * NTOP + t] = bi;
    }
}

// ---------------------------------------------------------------------------
// Sparse top-k attention per token. comb += g1*out. (fp32 comb)
// ---------------------------------------------------------------------------
__global__ __launch_bounds__(256) void sparse_flash(const float* __restrict__ q,
                                                    const float* __restrict__ k,
                                                    const float* __restrict__ v,
                                                    const int* __restrict__ idx,
                                                    const float* __restrict__ gl,
                                                    float* __restrict__ comb) {
    const int i = blockIdx.x, tid = threadIdx.x, wave = tid >> 6, lane = tid & 63;
    __shared__ float Qs[16][132];
    __shared__ float KV[32][132];
    __shared__ float ss[16][266];
    __shared__ int sb[8];
    if (tid < 8) sb[tid] = idx[i * NTOP + tid];
    for (int t = tid; t < 512; t += 256) {
        int r = t >> 5, c4 = (t & 31) * 4;
        *(float4*)&Qs[r][c4] = *(const float4*)&q[(size_t)i * HIDDEN + r * DIM + c4];
    }
    __syncthreads();

    const int hi = lane & 15, kg = lane >> 4;
    for (int c = 0; c < 8; ++c) {
        int kb = sb[c] * 32;
        for (int t = tid; t < 1024; t += 256) {
            int r = t >> 5, c4 = (t & 31) * 4;
            *(float4*)&KV[r][c4] = *(const float4*)&k[(size_t)(kb + r) * DIM + c4];
        }
        __syncthreads();
        float s2[2] = {0.f, 0.f};
        for (int d = 0; d < 128; d += 4) {
            float4 qv = *(float4*)&Qs[hi][d];
            #pragma unroll
            for (int jj = 0; jj < 2; ++jj) {
                float4 kv = *(float4*)&KV[wave * 8 + kg * 2 + jj][d];
                s2[jj] = fmaf(qv.x, kv.x, fmaf(qv.y, kv.y, fmaf(qv.z, kv.z, fmaf(qv.w, kv.w, s2[jj]))));
            }
        }
        #pragma unroll
        for (int jj = 0; jj < 2; ++jj) {
            int kl = wave * 8 + kg * 2 + jj;
            int pos = kb + kl;
            ss[hi][c * 32 + kl] = (pos <= i) ? s2[jj] * SCALEF : NEGF;
        }
        __syncthreads();
    }

    for (int hh = 0; hh < 4; ++hh) {
        int h = wave * 4 + hh;
        float v0 = ss[h][lane], v1 = ss[h][64 + lane], v2 = ss[h][128 + lane], v3 = ss[h][192 + lane];
        float mx = fmaxf(fmaxf(v0, v1), fmaxf(v2, v3));
        for (int o = 32; o; o >>= 1) mx = fmaxf(mx, __shfl_xor(mx, o));
        float e0 = (v0 <= NEGF * 0.5f) ? 0.f : __expf(v0 - mx);
        float e1 = (v1 <= NEGF * 0.5f) ? 0.f : __expf(v1 - mx);
        float e2 = (v2 <= NEGF * 0.5f) ? 0.f : __expf(v2 - mx);
        float e3 = (v3 <= NEGF * 0.5f) ? 0.f : __expf(v3 - mx);
        float z = e0 + e1 + e2 + e3;
        for (int o = 32; o; o >>= 1) z += __shfl_xor(z, o);
        float rz = 1.0f / z;
        ss[h][lane] = e0 * rz; ss[h][64 + lane] = e1 * rz;
        ss[h][128 + lane] = e2 * rz; ss[h][192 + lane] = e3 * rz;
    }
    __syncthreads();

    const int h2 = tid & 15, dg = tid >> 4;
    float o8[8] = {0.f,0.f,0.f,0.f,0.f,0.f,0.f,0.f};
    for (int c = 0; c < 8; ++c) {
        int kb = sb[c] * 32;
        for (int t = tid; t < 1024; t += 256) {
            int r = t >> 5, c4 = (t & 31) * 4;
            *(float4*)&KV[r][c4] = *(const float4*)&v[(size_t)(kb + r) * DIM + c4];
        }
        __syncthreads();
        for (int kk = 0; kk < 32; ++kk) {
            float p = ss[h2][c * 32 + kk];
            float4 va = *(float4*)&KV[kk][dg * 8];
            float4 vb = *(float4*)&KV[kk][dg * 8 + 4];
            o8[0] = fmaf(p, va.x, o8[0]); o8[1] = fmaf(p, va.y, o8[1]);
            o8[2] = fmaf(p, va.z, o8[2]); o8[3] = fmaf(p, va.w, o8[3]);
            o8[4] = fmaf(p, vb.x, o8[4]); o8[5] = fmaf(p, vb.y, o8[5]);
            o8[6] = fmaf(p, vb.z, o8[6]); o8[7] = fmaf(p, vb.w, o8[7]);
        }
        __syncthreads();
    }
    float g1 = sigmoidf_(gl[(size_t)i * 48 + h2 * 3 + 1]);
    #pragma unroll
    for (int x = 0; x < 8; ++x)
        comb[(size_t)i * HIDDEN + h2 * DIM + dg * 8 + x] += g1 * o8[x];
}

// ---------------------------------------------------------------------------
// Sliding-window flash attention: 64-query tile x 1 head per block.
// grid (16 heads, 32 tiles). Online softmax over <=18 chunks of 32 keys.
// ---------------------------------------------------------------------------
__global__ __launch_bounds__(256) void swin_flash(const float* __restrict__ q,
                                                  const float* __restrict__ k,
                                                  const float* __restrict__ v,
                                                  const float* __restrict__ gl,
                                                  float* __restrict__ comb) {
    const int h = blockIdx.x, qt = blockIdx.y;
    const int q0 = qt * 64;
    const int s0 = (q0 - WINSZ > 0) ? (q0 - WINSZ) : 0;
    const int nch = (q0 + 64 - s0) >> 5;
    const int tid = threadIdx.x, wave = tid >> 6, lane = tid & 63;

    __shared__ float Qs[64][132];
    __shared__ float Ks[32][132];
    __shared__ float Vs[32][132];
    __shared__ float Ps[64][33];

    for (int t = tid; t < 2048; t += 256) {
        int r = t >> 5, c4 = (t & 31) * 4;
        *(float4*)&Qs[r][c4] = *(const float4*)&q[((size_t)(q0 + r) * NHQ + h) * DIM + c4];
    }

    const int qi = lane & 15, kg = lane >> 4;
    const int myq = wave * 16 + qi;
    const int gq = q0 + myq;
    float m = -3e38f, l = 0.f;
    float4 acc4[8];
    #pragma unroll
    for (int b = 0; b < 8; ++b) acc4[b] = make_float4(0.f, 0.f, 0.f, 0.f);
    __syncthreads();

    for (int c = 0; c < nch; ++c) {
        int kb = s0 + c * 32;
        for (int t = tid; t < 1024; t += 256) {
            int r = t >> 5, c4 = (t & 31) * 4;
            *(float4*)&Ks[r][c4] = *(const float4*)&k[(size_t)(kb + r) * DIM + c4];
            *(float4*)&Vs[r][c4] = *(const float4*)&v[(size_t)(kb + r) * DIM + c4];
        }
        __syncthreads();

        float s[8];
        #pragma unroll
        for (int b = 0; b < 8; ++b) s[b] = 0.f;
        for (int d = 0; d < 128; d += 4) {
            float4 qv = *(float4*)&Qs[myq][d];
            #pragma unroll
            for (int jj = 0; jj < 8; ++jj) {
                int b = (jj + kg) & 7;
                float4 kv = *(float4*)&Ks[kg * 8 + b][d];
                s[b] = fmaf(qv.x, kv.x, fmaf(qv.y, kv.y, fmaf(qv.z, kv.z, fmaf(qv.w, kv.w, s[b]))));
            }
        }
        float mx = -3e38f;
        #pragma unroll
        for (int b = 0; b < 8; ++b) {
            int pos = kb + kg * 8 + b;
            bool ok = (pos <= gq) && (pos >= gq - WINSZ);
            s[b] = ok ? s[b] * SCALEF : -3e38f;
            mx = fmaxf(mx, s[b]);
        }
        mx = fmaxf(mx, __shfl_xor(mx, 16));
        mx = fmaxf(mx, __shfl_xor(mx, 32));
        float mnew = fmaxf(m, mx);
        float corr = __expf(m - mnew);
        float psum = 0.f;
        #pragma unroll
        for (int b = 0; b < 8; ++b) {
            float p = (s[b] <= -1e37f) ? 0.f : __expf(s[b] - mnew);
            Ps[myq][kg * 8 + b] = p;
            psum += p;
        }
        psum += __shfl_xor(psum, 16);
        psum += __shfl_xor(psum, 32);
        l = l * corr + psum;
        m = mnew;
        #pragma unroll
        for (int b = 0; b < 8; ++b) {
            acc4[b].x *= corr; acc4[b].y *= corr; acc4[b].z *= corr; acc4[b].w *= corr;
        }
        for (int kk = 0; kk < 32; ++kk) {
            float p = Ps[myq][kk];
            #pragma unroll
            for (int x4 = 0; x4 < 8; ++x4) {
                int b = (x4 + kg) & 7;
                float4 vv = *(float4*)&Vs[kk][kg * 32 + b * 4];
                acc4[b].x = fmaf(p, vv.x, acc4[b].x);
                acc4[b].y = fmaf(p, vv.y, acc4[b].y);
                acc4[b].z = fmaf(p, vv.z, acc4[b].z);
                acc4[b].w = fmaf(p, vv.w, acc4[b].w);
            }
        }
        __syncthreads();
    }

    float linv = 1.0f / l;
    float g2 = sigmoidf_(gl[(size_t)gq * 48 + h * 3 + 2]);
    #pragma unroll
    for (int b = 0; b < 8; ++b) {
        size_t o = (size_t)gq * HIDDEN + h * DIM + kg * 32 + b * 4;
        comb[o + 0] += g2 * acc4[b].x * linv;
        comb[o + 1] += g2 * acc4[b].y * linv;
        comb[o + 2] += g2 * acc4[b].z * linv;
        comb[o + 3] += g2 * acc4[b].w * linv;
    }
}

// ---------------------------------------------------------------------------
extern "C" void kernel_launch(void* const* d_in, const int* in_sizes, int n_in,
                              void* d_out, int out_size, void* d_ws, size_t ws_size,
                              hipStream_t stream) {
    const float* x  = (const float*)d_in[0];
    const float* Wq = (const float*)d_in[2];
    const float* Wk = (const float*)d_in[3];
    const float* Wv = (const float*)d_in[4];
    const float* Wo = (const float*)d_in[5];
    const float* Wg = (const float*)d_in[6];
    const float* pe = (const float*)d_in[7];
    float* out = (float*)d_out;

    // workspace layout (36.7 MB, proven footprint)
    char* w = (char*)d_ws;
    float* q    = (float*)(w);               // 16 MB   (later: comb hi/lo)
    float* comb = (float*)(w + 16777216);    // 16 MB   (first: x hi/lo; later: Wo hi/lo)
    float* kbuf = (float*)(w + 33554432);    // 1 MB
    float* vbuf = (float*)(w + 34603008);    // 1 MB
    float* gl   = (float*)(w + 35651584);    // 384 KB
    float* ck   = (float*)(w + 36044800);    // 32 KB
    float* cv   = (float*)(w + 36077568);    // 32 KB
    float* blk  = (float*)(w + 36110336);    // 512 KB
    int*   idx  = (int*)  (w + 36634624);    // 64 KB

    // scratch aliases (each pair = 8 MB + 8 MB bf16)
    unsigned short* Xh  = (unsigned short*)comb;            // comb region (dead)
    unsigned short* Xl  = Xh + 4194304;
    unsigned short* Wqh = (unsigned short*)out;             // d_out region (dead until final)
    unsigned short* Wql = Wqh + 4194304;
    unsigned short* Ch  = (unsigned short*)q;               // q region (dead after attn)
    unsigned short* Cl  = Ch + 4194304;
    unsigned short* Woh = (unsigned short*)comb;            // comb region (dead after split)
    unsigned short* Wol = Woh + 4194304;

    // 1. q projection: split x, transpose-split Wq, 3-pass MFMA GEMM
    split_pair<<<4096, 256, 0, stream>>>(x, Xh, Xl);
    tsplit<<<dim3(64, 64), 256, 0, stream>>>(Wq, Wqh, Wql);
    gemm3s<<<dim3(16, 16), 256, 0, stream>>>(Xh, Xl, Wqh, Wql, q, SEQ, HIDDEN, HIDDEN);

    // 2. small projections (fp32)
    gemm_small<<<dim3(2, 64), 256, 0, stream>>>(x, Wk, kbuf, SEQ, DIM, HIDDEN);
    gemm_small<<<dim3(2, 64), 256, 0, stream>>>(x, Wv, vbuf, SEQ, DIM, HIDDEN);
    gemm_small<<<dim3(1, 64), 256, 0, stream>>>(x, Wg, gl,   SEQ, 48,  HIDDEN);

    // 3. compress (un-roped k) then rope q,k
    compress_kernel<<<NCB, DIM, 0, stream>>>(kbuf, vbuf, pe, ck, cv);
    rope_qk<<<SEQ, 64, 0, stream>>>(q, kbuf);

    // 4. compressed attention -> comb fp32 (full init; overwrites dead Xh/Xl) + blk
    cmp_flash<<<SEQ, 256, 0, stream>>>(q, ck, cv, gl, comb, blk);

    // 5. top-k
    topk2<<<SEQ / 256, 256, 0, stream>>>(blk, idx);

    // 6. sparse attention (comb += g1*out)
    sparse_flash<<<SEQ, 256, 0, stream>>>(q, kbuf, vbuf, idx, gl, comb);

    // 7. sliding-window flash attention (comb += g2*out)
    swin_flash<<<dim3(16, 32), 256, 0, stream>>>(q, kbuf, vbuf, gl, comb);

    // 8. output projection: split comb (into dead q region), transpose-split Wo
    //    (into comb region, dead after the split), 3-pass MFMA GEMM -> out
    split_pair<<<4096, 256, 0, stream>>>(comb, Ch, Cl);
    tsplit<<<dim3(64, 64), 256, 0, stream>>>(Wo, Woh, Wol);
    gemm3s<<<dim3(16, 16), 256, 0, stream>>>(Ch, Cl, Woh, Wol, out, SEQ, HIDDEN, HIDDEN);
}

// Round 4
// 1762.575 us; speedup vs baseline: 2.1867x; 2.1867x over previous
//
#include <hip/hip_runtime.h>
#include <hip/hip_bf16.h>

constexpr int SEQ    = 2048;
constexpr int HIDDEN = 2048;
constexpr int NHQ    = 16;
constexpr int DIM    = 128;
constexpr int NCB    = 64;
constexpr int NTOP   = 8;
constexpr int WINSZ  = 512;

#define SCALEF 0.08838834764831845f
#define NEGF  -1e30f

using short8 = __attribute__((ext_vector_type(8))) short;
using f32x4  = __attribute__((ext_vector_type(4))) float;

__device__ inline unsigned short f2bf(float f) {
    unsigned u = __float_as_uint(f);
    unsigned r = (u + 0x7fffu + ((u >> 16) & 1u)) >> 16;
    return (unsigned short)r;
}
__device__ inline float bf2f(unsigned short b) {
    return __uint_as_float(((unsigned)b) << 16);
}
__device__ inline float sigmoidf_(float x) { return 1.0f / (1.0f + __expf(-x)); }

// ---------------------------------------------------------------------------
// split fp32 -> (hi, lo) bf16 pair, elementwise. n % 1024 == 0.
// ---------------------------------------------------------------------------
__global__ __launch_bounds__(256) void split_pair(const float* __restrict__ in,
                                                  unsigned short* __restrict__ hi,
                                                  unsigned short* __restrict__ lo) {
    int i = (blockIdx.x * 256 + threadIdx.x) * 4;
    float4 v = *(const float4*)&in[i];
    ushort4 h, l;
    h.x = f2bf(v.x); l.x = f2bf(v.x - bf2f(h.x));
    h.y = f2bf(v.y); l.y = f2bf(v.y - bf2f(h.y));
    h.z = f2bf(v.z); l.z = f2bf(v.z - bf2f(h.z));
    h.w = f2bf(v.w); l.w = f2bf(v.w - bf2f(h.w));
    *(ushort4*)&hi[i] = h;
    *(ushort4*)&lo[i] = l;
}

// ---------------------------------------------------------------------------
// transpose + split: W[K][N] fp32 -> Th/Tl[N][K] bf16 hi/lo. 32x32 tiles.
// ---------------------------------------------------------------------------
__global__ __launch_bounds__(256) void tsplit(const float* __restrict__ W,
                                              unsigned short* __restrict__ Th,
                                              unsigned short* __restrict__ Tl) {
    __shared__ float t[32][33];
    const int k0 = blockIdx.y * 32, n0 = blockIdx.x * 32;
    const int ty = threadIdx.x >> 3, tx = threadIdx.x & 7;
    float4 v = *(const float4*)&W[(size_t)(k0 + ty) * HIDDEN + n0 + tx * 4];
    t[ty][tx * 4 + 0] = v.x; t[ty][tx * 4 + 1] = v.y;
    t[ty][tx * 4 + 2] = v.z; t[ty][tx * 4 + 3] = v.w;
    __syncthreads();
    ushort4 h, l;
    float a0 = t[tx * 4 + 0][ty], a1 = t[tx * 4 + 1][ty];
    float a2 = t[tx * 4 + 2][ty], a3 = t[tx * 4 + 3][ty];
    h.x = f2bf(a0); l.x = f2bf(a0 - bf2f(h.x));
    h.y = f2bf(a1); l.y = f2bf(a1 - bf2f(h.y));
    h.z = f2bf(a2); l.z = f2bf(a2 - bf2f(h.z));
    h.w = f2bf(a3); l.w = f2bf(a3 - bf2f(h.w));
    *(ushort4*)&Th[(size_t)(n0 + ty) * HIDDEN + k0 + tx * 4] = h;
    *(ushort4*)&Tl[(size_t)(n0 + ty) * HIDDEN + k0 + tx * 4] = l;
}

// ---------------------------------------------------------------------------
// Split-bf16 MFMA GEMM (fp32-grade): C = (Ah+Al) * (Bh+Bl)^T.
// 128x128 tile, BK=32, 4 waves (2x2), 16x16x32 MFMA, 4x4 frags/wave,
// 3 MFMA per fragment pair (drop al*bl ~ 2^-18).
// ---------------------------------------------------------------------------
__global__ __launch_bounds__(256) void gemm3s(const unsigned short* __restrict__ Ah,
                                              const unsigned short* __restrict__ Al,
                                              const unsigned short* __restrict__ Bh,
                                              const unsigned short* __restrict__ Bl,
                                              float* __restrict__ C,
                                              int M, int N, int K) {
    __shared__ unsigned short sAh[4][128][8], sAl[4][128][8];
    __shared__ unsigned short sBh[4][128][8], sBl[4][128][8];
    const int tid = threadIdx.x, lane = tid & 63, wave = tid >> 6;
    const int wr = wave >> 1, wc = wave & 1;
    const int brow = blockIdx.y * 128, bcol = blockIdx.x * 128;
    const int lr = lane & 15, lc = lane >> 4;
    const int sr = tid & 127, sc0 = tid >> 7;

    f32x4 acc[4][4];
    #pragma unroll
    for (int a = 0; a < 4; ++a)
        #pragma unroll
        for (int b = 0; b < 4; ++b) acc[a][b] = (f32x4){0.f, 0.f, 0.f, 0.f};

    for (int k0 = 0; k0 < K; k0 += 32) {
        #pragma unroll
        for (int i = 0; i < 2; ++i) {
            int c = i * 2 + sc0;
            size_t ao = (size_t)(brow + sr) * K + k0 + c * 8;
            size_t bo = (size_t)(bcol + sr) * K + k0 + c * 8;
            *(short8*)&sAh[c][sr][0] = *(const short8*)&Ah[ao];
            *(short8*)&sAl[c][sr][0] = *(const short8*)&Al[ao];
            *(short8*)&sBh[c][sr][0] = *(const short8*)&Bh[bo];
            *(short8*)&sBl[c][sr][0] = *(const short8*)&Bl[bo];
        }
        __syncthreads();
        short8 fah[4], fal[4], fbh[4], fbl[4];
        #pragma unroll
        for (int mi = 0; mi < 4; ++mi) {
            fah[mi] = *(short8*)&sAh[lc][wr * 64 + mi * 16 + lr][0];
            fal[mi] = *(short8*)&sAl[lc][wr * 64 + mi * 16 + lr][0];
        }
        #pragma unroll
        for (int ni = 0; ni < 4; ++ni) {
            fbh[ni] = *(short8*)&sBh[lc][wc * 64 + ni * 16 + lr][0];
            fbl[ni] = *(short8*)&sBl[lc][wc * 64 + ni * 16 + lr][0];
        }
        #pragma unroll
        for (int mi = 0; mi < 4; ++mi)
            #pragma unroll
            for (int ni = 0; ni < 4; ++ni) {
                acc[mi][ni] = __builtin_amdgcn_mfma_f32_16x16x32_bf16(fah[mi], fbh[ni], acc[mi][ni], 0, 0, 0);
                acc[mi][ni] = __builtin_amdgcn_mfma_f32_16x16x32_bf16(fal[mi], fbh[ni], acc[mi][ni], 0, 0, 0);
                acc[mi][ni] = __builtin_amdgcn_mfma_f32_16x16x32_bf16(fah[mi], fbl[ni], acc[mi][ni], 0, 0, 0);
            }
        __syncthreads();
    }
    #pragma unroll
    for (int mi = 0; mi < 4; ++mi)
        #pragma unroll
        for (int ni = 0; ni < 4; ++ni) {
            int col  = bcol + wc * 64 + ni * 16 + lr;
            int rowb = brow + wr * 64 + mi * 16 + lc * 4;
            #pragma unroll
            for (int r = 0; r < 4; ++r)
                C[(size_t)(rowb + r) * N + col] = acc[mi][ni][r];
        }
}

// ---------------------------------------------------------------------------
// Narrow fp32 GEMM (k/v/gate projections). BM=32,BN=64,BK=32.
// ---------------------------------------------------------------------------
__global__ __launch_bounds__(256) void gemm_small(const float* __restrict__ A,
                                                  const float* __restrict__ B,
                                                  float* __restrict__ C,
                                                  int M, int Nd, int K) {
    __shared__ float As[32][33];
    __shared__ float Bs[32][64];
    const int tid  = threadIdx.x;
    const int brow = blockIdx.y * 32;
    const int bcol = blockIdx.x * 64;
    const int ty = tid >> 4, tx = tid & 15;
    float acc[2][4] = {{0.f,0.f,0.f,0.f},{0.f,0.f,0.f,0.f}};

    for (int k0 = 0; k0 < K; k0 += 32) {
        for (int t = tid; t < 1024; t += 256) {
            int r = t >> 5, c = t & 31;
            As[c][r] = A[(size_t)(brow + r) * K + k0 + c];
        }
        for (int t = tid; t < 2048; t += 256) {
            int r = t >> 6, c = t & 63;
            int col = bcol + c;
            Bs[r][c] = (col < Nd) ? B[(size_t)(k0 + r) * Nd + col] : 0.f;
        }
        __syncthreads();
        #pragma unroll 8
        for (int kk = 0; kk < 32; ++kk) {
            float a0 = As[kk][ty * 2], a1 = As[kk][ty * 2 + 1];
            float b0 = Bs[kk][tx * 4], b1 = Bs[kk][tx * 4 + 1];
            float b2 = Bs[kk][tx * 4 + 2], b3 = Bs[kk][tx * 4 + 3];
            acc[0][0] = fmaf(a0, b0, acc[0][0]); acc[0][1] = fmaf(a0, b1, acc[0][1]);
            acc[0][2] = fmaf(a0, b2, acc[0][2]); acc[0][3] = fmaf(a0, b3, acc[0][3]);
            acc[1][0] = fmaf(a1, b0, acc[1][0]); acc[1][1] = fmaf(a1, b1, acc[1][1]);
            acc[1][2] = fmaf(a1, b2, acc[1][2]); acc[1][3] = fmaf(a1, b3, acc[1][3]);
        }
        __syncthreads();
    }
    for (int ii = 0; ii < 2; ++ii)
        for (int j = 0; j < 4; ++j) {
            int col = bcol + tx * 4 + j;
            if (col < Nd)
                C[(size_t)(brow + ty * 2 + ii) * Nd + col] = acc[ii][j];
        }
}

// ---------------------------------------------------------------------------
// Compress: ck[m]=rope(mean(k+pe), pos=32m), cv[m]=mean(v). Un-roped k input.
// ---------------------------------------------------------------------------
__global__ void compress_kernel(const float* __restrict__ k,
                                const float* __restrict__ v,
                                const float* __restrict__ pe,
                                float* __restrict__ ck,
                                float* __restrict__ cv) {
    int m = blockIdx.x, d = threadIdx.x;
    float sk = 0.f, sv = 0.f, sp = 0.f;
    for (int s = 0; s < 32; ++s) {
        sk += k[(size_t)(m * 32 + s) * DIM + d];
        sv += v[(size_t)(m * 32 + s) * DIM + d];
        sp += pe[s * DIM + d];
    }
    float ckv = (sk + sp) * (1.0f / 32.0f);
    cv[m * DIM + d] = sv * (1.0f / 32.0f);
    __shared__ float tmp[DIM];
    tmp[d] = ckv;
    __syncthreads();
    int j = d & 63;
    float inv = powf(10000.0f, -(float)(2 * j) / 128.0f);
    float ang = (float)(m * 32) * inv;
    float c = cosf(ang), s = sinf(ang);
    float x1 = tmp[j], x2 = tmp[j + 64];
    ck[m * DIM + d] = (d < 64) ? (x1 * c - x2 * s) : (x2 * c + x1 * s);
}

__global__ void rope_qk(float* __restrict__ q, float* __restrict__ k) {
    int i = blockIdx.x, j = threadIdx.x;
    float inv = powf(10000.0f, -(float)(2 * j) / 128.0f);
    float ang = (float)i * inv;
    float c = cosf(ang), s = sinf(ang);
    for (int h = 0; h < NHQ; ++h) {
        float* p = q + ((size_t)i * NHQ + h) * DIM;
        float x1 = p[j], x2 = p[j + 64];
        p[j]      = x1 * c - x2 * s;
        p[j + 64] = x2 * c + x1 * s;
    }
    float* p = k + (size_t)i * DIM;
    float x1 = p[j], x2 = p[j + 64];
    p[j]      = x1 * c - x2 * s;
    p[j + 64] = x2 * c + x1 * s;
}

// ---------------------------------------------------------------------------
// Compressed attention per token: writes comb (fp32, full init) + blk scores.
// ---------------------------------------------------------------------------
__global__ __launch_bounds__(256) void cmp_flash(const float* __restrict__ q,
                                                 const float* __restrict__ ck,
                                                 const float* __restrict__ cv,
                                                 const float* __restrict__ gl,
                                                 float* __restrict__ comb,
                                                 float* __restrict__ blk) {
    const int i = blockIdx.x, tid = threadIdx.x, wave = tid >> 6, lane = tid & 63;
    __shared__ float Qs[16][132];
    __shared__ float KV[64][132];
    __shared__ float ss[16][66];

    for (int t = tid; t < 512; t += 256) {
        int r = t >> 5, c4 = (t & 31) * 4;
        *(float4*)&Qs[r][c4] = *(const float4*)&q[(size_t)i * HIDDEN + r * DIM + c4];
    }
    for (int t = tid; t < 2048; t += 256) {
        int r = t >> 5, c4 = (t & 31) * 4;
        *(float4*)&KV[r][c4] = *(const float4*)&ck[(size_t)r * DIM + c4];
    }
    __syncthreads();

    const int hi = lane & 15, mg = lane >> 4;
    float s4[4] = {0.f, 0.f, 0.f, 0.f};
    for (int d = 0; d < 128; d += 4) {
        float4 qv = *(float4*)&Qs[hi][d];
        #pragma unroll
        for (int jj = 0; jj < 4; ++jj) {
            float4 kv = *(float4*)&KV[wave * 16 + mg * 4 + jj][d];
            s4[jj] = fmaf(qv.x, kv.x, fmaf(qv.y, kv.y, fmaf(qv.z, kv.z, fmaf(qv.w, kv.w, s4[jj]))));
        }
    }
    #pragma unroll
    for (int jj = 0; jj < 4; ++jj) {
        int m = wave * 16 + mg * 4 + jj;
        ss[hi][m] = (i >= m * 32 + 31) ? s4[jj] * SCALEF : NEGF;
    }
    __syncthreads();

    for (int hh = 0; hh < 4; ++hh) {
        int h = wave * 4 + hh;
        float val = ss[h][lane];
        float mx = val;
        for (int o = 32; o; o >>= 1) mx = fmaxf(mx, __shfl_xor(mx, o));
        float e = (val <= NEGF * 0.5f) ? 0.f : __expf(val - mx);
        float z = e;
        for (int o = 32; o; o >>= 1) z += __shfl_xor(z, o);
        ss[h][lane] = (z > 0.f) ? e * (1.0f / z) : 0.f;
    }
    __syncthreads();

    if (tid < 64) {
        float sb = 0.f;
        for (int h = 0; h < 16; ++h) sb += ss[h][tid];
        blk[(size_t)i * NCB + tid] = sb;
    }

    for (int t = tid; t < 2048; t += 256) {
        int r = t >> 5, c4 = (t & 31) * 4;
        *(float4*)&KV[r][c4] = *(const float4*)&cv[(size_t)r * DIM + c4];
    }
    __syncthreads();

    const int h2 = tid & 15, dg = tid >> 4;
    float o8[8] = {0.f,0.f,0.f,0.f,0.f,0.f,0.f,0.f};
    for (int kk = 0; kk < 64; ++kk) {
        float p = ss[h2][kk];
        float4 va = *(float4*)&KV[kk][dg * 8];
        float4 vb = *(float4*)&KV[kk][dg * 8 + 4];
        o8[0] = fmaf(p, va.x, o8[0]); o8[1] = fmaf(p, va.y, o8[1]);
        o8[2] = fmaf(p, va.z, o8[2]); o8[3] = fmaf(p, va.w, o8[3]);
        o8[4] = fmaf(p, vb.x, o8[4]); o8[5] = fmaf(p, vb.y, o8[5]);
        o8[6] = fmaf(p, vb.z, o8[6]); o8[7] = fmaf(p, vb.w, o8[7]);
    }
    float g0 = sigmoidf_(gl[(size_t)i * 48 + h2 * 3 + 0]);
    #pragma unroll
    for (int x = 0; x < 8; ++x)
        comb[(size_t)i * HIDDEN + h2 * DIM + dg * 8 + x] = g0 * o8[x];
}

// ---------------------------------------------------------------------------
// Top-k (exact jax.lax.top_k tie semantics). LDS-staged, 256 tokens/block.
// ---------------------------------------------------------------------------
__global__ __launch_bounds__(256) void topk2(const float* __restrict__ blk,
                                             int* __restrict__ oidx) {
    __shared__ float L[256][68];
    int base = blockIdx.x * 256;
    for (int t = threadIdx.x; t < 256 * 16; t += 256) {
        int r = t >> 4, c4 = (t & 15) * 4;
        *(float4*)&L[r][c4] = *(const float4*)&blk[(size_t)(base + r) * NCB + c4];
    }
    __syncthreads();
    int i = base + threadIdx.x;
    int tb = i >> 5;
    unsigned long long used = 0ull;
    for (int t = 0; t < NTOP; ++t) {
        float best = -3e38f; int bi = 0;
        for (int m = 0; m < NCB; ++m) {
            if ((used >> m) & 1ull) continue;
            float s = L[threadIdx.x][m];
            if (m > tb) s = NEGF;
            if (m == 0 || (m <= tb && m > tb - 2)) s = 1e30f;
            if (s > best) { best = s; bi = m; }
        }
        used |= 1ull << bi;
        oidx[i * NTOP + t] = bi;
    }
}

// ---------------------------------------------------------------------------
// Sparse top-k attention per token. comb += g1*out. (fp32 comb)
// ---------------------------------------------------------------------------
__global__ __launch_bounds__(256) void sparse_flash(const float* __restrict__ q,
                                                    const float* __restrict__ k,
                                                    const float* __restrict__ v,
                                                    const int* __restrict__ idx,
                                                    const float* __restrict__ gl,
                                                    float* __restrict__ comb) {
    const int i = blockIdx.x, tid = threadIdx.x, wave = tid >> 6, lane = tid & 63;
    __shared__ float Qs[16][132];
    __shared__ float KV[32][132];
    __shared__ float ss[16][266];
    __shared__ int sb[8];
    if (tid < 8) sb[tid] = idx[i * NTOP + tid];
    for (int t = tid; t < 512; t += 256) {
        int r = t >> 5, c4 = (t & 31) * 4;
        *(float4*)&Qs[r][c4] = *(const float4*)&q[(size_t)i * HIDDEN + r * DIM + c4];
    }
    __syncthreads();

    const int hi = lane & 15, kg = lane >> 4;
    for (int c = 0; c < 8; ++c) {
        int kb = sb[c] * 32;
        for (int t = tid; t < 1024; t += 256) {
            int r = t >> 5, c4 = (t & 31) * 4;
            *(float4*)&KV[r][c4] = *(const float4*)&k[(size_t)(kb + r) * DIM + c4];
        }
        __syncthreads();
        float s2[2] = {0.f, 0.f};
        for (int d = 0; d < 128; d += 4) {
            float4 qv = *(float4*)&Qs[hi][d];
            #pragma unroll
            for (int jj = 0; jj < 2; ++jj) {
                float4 kv = *(float4*)&KV[wave * 8 + kg * 2 + jj][d];
                s2[jj] = fmaf(qv.x, kv.x, fmaf(qv.y, kv.y, fmaf(qv.z, kv.z, fmaf(qv.w, kv.w, s2[jj]))));
            }
        }
        #pragma unroll
        for (int jj = 0; jj < 2; ++jj) {
            int kl = wave * 8 + kg * 2 + jj;
            int pos = kb + kl;
            ss[hi][c * 32 + kl] = (pos <= i) ? s2[jj] * SCALEF : NEGF;
        }
        __syncthreads();
    }

    for (int hh = 0; hh < 4; ++hh) {
        int h = wave * 4 + hh;
        float v0 = ss[h][lane], v1 = ss[h][64 + lane], v2 = ss[h][128 + lane], v3 = ss[h][192 + lane];
        float mx = fmaxf(fmaxf(v0, v1), fmaxf(v2, v3));
        for (int o = 32; o; o >>= 1) mx = fmaxf(mx, __shfl_xor(mx, o));
        float e0 = (v0 <= NEGF * 0.5f) ? 0.f : __expf(v0 - mx);
        float e1 = (v1 <= NEGF * 0.5f) ? 0.f : __expf(v1 - mx);
        float e2 = (v2 <= NEGF * 0.5f) ? 0.f : __expf(v2 - mx);
        float e3 = (v3 <= NEGF * 0.5f) ? 0.f : __expf(v3 - mx);
        float z = e0 + e1 + e2 + e3;
        for (int o = 32; o; o >>= 1) z += __shfl_xor(z, o);
        float rz = 1.0f / z;
        ss[h][lane] = e0 * rz; ss[h][64 + lane] = e1 * rz;
        ss[h][128 + lane] = e2 * rz; ss[h][192 + lane] = e3 * rz;
    }
    __syncthreads();

    const int h2 = tid & 15, dg = tid >> 4;
    float o8[8] = {0.f,0.f,0.f,0.f,0.f,0.f,0.f,0.f};
    for (int c = 0; c < 8; ++c) {
        int kb = sb[c] * 32;
        for (int t = tid; t < 1024; t += 256) {
            int r = t >> 5, c4 = (t & 31) * 4;
            *(float4*)&KV[r][c4] = *(const float4*)&v[(size_t)(kb + r) * DIM + c4];
        }
        __syncthreads();
        for (int kk = 0; kk < 32; ++kk) {
            float p = ss[h2][c * 32 + kk];
            float4 va = *(float4*)&KV[kk][dg * 8];
            float4 vb = *(float4*)&KV[kk][dg * 8 + 4];
            o8[0] = fmaf(p, va.x, o8[0]); o8[1] = fmaf(p, va.y, o8[1]);
            o8[2] = fmaf(p, va.z, o8[2]); o8[3] = fmaf(p, va.w, o8[3]);
            o8[4] = fmaf(p, vb.x, o8[4]); o8[5] = fmaf(p, vb.y, o8[5]);
            o8[6] = fmaf(p, vb.z, o8[6]); o8[7] = fmaf(p, vb.w, o8[7]);
        }
        __syncthreads();
    }
    float g1 = sigmoidf_(gl[(size_t)i * 48 + h2 * 3 + 1]);
    #pragma unroll
    for (int x = 0; x < 8; ++x)
        comb[(size_t)i * HIDDEN + h2 * DIM + dg * 8 + x] += g1 * o8[x];
}

// ---------------------------------------------------------------------------
// Sliding-window flash attention: 64-query tile x 1 head per block.
// grid (16 heads, 32 tiles). Online softmax over <=18 chunks of 32 keys.
// Lane (qi, kg): query myq = wave*16+qi.
//   Score phase: keys b*4+kg (b static) -> s[b] register-indexed statically;
//                Ks rows for the 4 kg groups land in disjoint bank groups.
//   PV phase: dims b*16+kg*4 -> acc4[b] static; Vs cols disjoint across kg.
// ---------------------------------------------------------------------------
__global__ __launch_bounds__(256) void swin_flash(const float* __restrict__ q,
                                                  const float* __restrict__ k,
                                                  const float* __restrict__ v,
                                                  const float* __restrict__ gl,
                                                  float* __restrict__ comb) {
    const int h = blockIdx.x, qt = blockIdx.y;
    const int q0 = qt * 64;
    const int s0 = (q0 - WINSZ > 0) ? (q0 - WINSZ) : 0;
    const int nch = (q0 + 64 - s0) >> 5;
    const int tid = threadIdx.x, wave = tid >> 6, lane = tid & 63;

    __shared__ float Qs[64][132];
    __shared__ float Ks[32][132];
    __shared__ float Vs[32][132];
    __shared__ float Ps[64][33];

    for (int t = tid; t < 2048; t += 256) {
        int r = t >> 5, c4 = (t & 31) * 4;
        *(float4*)&Qs[r][c4] = *(const float4*)&q[((size_t)(q0 + r) * NHQ + h) * DIM + c4];
    }

    const int qi = lane & 15, kg = lane >> 4;
    const int myq = wave * 16 + qi;
    const int gq = q0 + myq;
    float m = -3e38f, l = 0.f;
    float4 acc4[8];                      // acc4[b] = dims [b*16+kg*4, +4)
    #pragma unroll
    for (int b = 0; b < 8; ++b) acc4[b] = make_float4(0.f, 0.f, 0.f, 0.f);
    __syncthreads();

    for (int c = 0; c < nch; ++c) {
        int kb = s0 + c * 32;
        for (int t = tid; t < 1024; t += 256) {
            int r = t >> 5, c4 = (t & 31) * 4;
            *(float4*)&Ks[r][c4] = *(const float4*)&k[(size_t)(kb + r) * DIM + c4];
            *(float4*)&Vs[r][c4] = *(const float4*)&v[(size_t)(kb + r) * DIM + c4];
        }
        __syncthreads();

        // scores: lane handles keys b*4+kg, b=0..7 (static reg index)
        float s[8] = {0.f,0.f,0.f,0.f,0.f,0.f,0.f,0.f};
        for (int d = 0; d < 128; d += 4) {
            float4 qv = *(float4*)&Qs[myq][d];
            #pragma unroll
            for (int b = 0; b < 8; ++b) {
                float4 kv = *(float4*)&Ks[b * 4 + kg][d];
                s[b] = fmaf(qv.x, kv.x, fmaf(qv.y, kv.y, fmaf(qv.z, kv.z, fmaf(qv.w, kv.w, s[b]))));
            }
        }
        float mx = -3e38f;
        #pragma unroll
        for (int b = 0; b < 8; ++b) {
            int pos = kb + b * 4 + kg;
            bool ok = (pos <= gq) && (pos >= gq - WINSZ);
            s[b] = ok ? s[b] * SCALEF : -3e38f;
            mx = fmaxf(mx, s[b]);
        }
        mx = fmaxf(mx, __shfl_xor(mx, 16));
        mx = fmaxf(mx, __shfl_xor(mx, 32));
        float mnew = fmaxf(m, mx);
        float corr = __expf(m - mnew);
        float psum = 0.f;
        #pragma unroll
        for (int b = 0; b < 8; ++b) {
            float p = (s[b] <= -1e37f) ? 0.f : __expf(s[b] - mnew);
            Ps[myq][b * 4 + kg] = p;
            psum += p;
        }
        psum += __shfl_xor(psum, 16);
        psum += __shfl_xor(psum, 32);
        l = l * corr + psum;
        m = mnew;
        #pragma unroll
        for (int b = 0; b < 8; ++b) {
            acc4[b].x *= corr; acc4[b].y *= corr; acc4[b].z *= corr; acc4[b].w *= corr;
        }
        // PV: lane accumulates dims b*16+kg*4 (static reg index)
        for (int kk = 0; kk < 32; ++kk) {
            float p = Ps[myq][kk];
            #pragma unroll
            for (int b = 0; b < 8; ++b) {
                float4 vv = *(float4*)&Vs[kk][b * 16 + kg * 4];
                acc4[b].x = fmaf(p, vv.x, acc4[b].x);
                acc4[b].y = fmaf(p, vv.y, acc4[b].y);
                acc4[b].z = fmaf(p, vv.z, acc4[b].z);
                acc4[b].w = fmaf(p, vv.w, acc4[b].w);
            }
        }
        __syncthreads();
    }

    float linv = 1.0f / l;
    float g2 = sigmoidf_(gl[(size_t)gq * 48 + h * 3 + 2]);
    #pragma unroll
    for (int b = 0; b < 8; ++b) {
        size_t o = (size_t)gq * HIDDEN + h * DIM + b * 16 + kg * 4;
        comb[o + 0] += g2 * acc4[b].x * linv;
        comb[o + 1] += g2 * acc4[b].y * linv;
        comb[o + 2] += g2 * acc4[b].z * linv;
        comb[o + 3] += g2 * acc4[b].w * linv;
    }
}

// ---------------------------------------------------------------------------
extern "C" void kernel_launch(void* const* d_in, const int* in_sizes, int n_in,
                              void* d_out, int out_size, void* d_ws, size_t ws_size,
                              hipStream_t stream) {
    const float* x  = (const float*)d_in[0];
    const float* Wq = (const float*)d_in[2];
    const float* Wk = (const float*)d_in[3];
    const float* Wv = (const float*)d_in[4];
    const float* Wo = (const float*)d_in[5];
    const float* Wg = (const float*)d_in[6];
    const float* pe = (const float*)d_in[7];
    float* out = (float*)d_out;

    // workspace layout (36.7 MB, proven footprint)
    char* w = (char*)d_ws;
    float* q    = (float*)(w);               // 16 MB   (later: comb hi/lo)
    float* comb = (float*)(w + 16777216);    // 16 MB   (first: x hi/lo; later: Wo hi/lo)
    float* kbuf = (float*)(w + 33554432);    // 1 MB
    float* vbuf = (float*)(w + 34603008);    // 1 MB
    float* gl   = (float*)(w + 35651584);    // 384 KB
    float* ck   = (float*)(w + 36044800);    // 32 KB
    float* cv   = (float*)(w + 36077568);    // 32 KB
    float* blk  = (float*)(w + 36110336);    // 512 KB
    int*   idx  = (int*)  (w + 36634624);    // 64 KB

    // scratch aliases (each pair = 8 MB + 8 MB bf16)
    unsigned short* Xh  = (unsigned short*)comb;            // comb region (dead)
    unsigned short* Xl  = Xh + 4194304;
    unsigned short* Wqh = (unsigned short*)out;             // d_out region (dead until final)
    unsigned short* Wql = Wqh + 4194304;
    unsigned short* Ch  = (unsigned short*)q;               // q region (dead after attn)
    unsigned short* Cl  = Ch + 4194304;
    unsigned short* Woh = (unsigned short*)comb;            // comb region (dead after split)
    unsigned short* Wol = Woh + 4194304;

    // 1. q projection: split x, transpose-split Wq, 3-pass MFMA GEMM
    split_pair<<<4096, 256, 0, stream>>>(x, Xh, Xl);
    tsplit<<<dim3(64, 64), 256, 0, stream>>>(Wq, Wqh, Wql);
    gemm3s<<<dim3(16, 16), 256, 0, stream>>>(Xh, Xl, Wqh, Wql, q, SEQ, HIDDEN, HIDDEN);

    // 2. small projections (fp32)
    gemm_small<<<dim3(2, 64), 256, 0, stream>>>(x, Wk, kbuf, SEQ, DIM, HIDDEN);
    gemm_small<<<dim3(2, 64), 256, 0, stream>>>(x, Wv, vbuf, SEQ, DIM, HIDDEN);
    gemm_small<<<dim3(1, 64), 256, 0, stream>>>(x, Wg, gl,   SEQ, 48,  HIDDEN);

    // 3. compress (un-roped k) then rope q,k
    compress_kernel<<<NCB, DIM, 0, stream>>>(kbuf, vbuf, pe, ck, cv);
    rope_qk<<<SEQ, 64, 0, stream>>>(q, kbuf);

    // 4. compressed attention -> comb fp32 (full init) + blk
    cmp_flash<<<SEQ, 256, 0, stream>>>(q, ck, cv, gl, comb, blk);

    // 5. top-k
    topk2<<<SEQ / 256, 256, 0, stream>>>(blk, idx);

    // 6. sparse attention (comb += g1*out)
    sparse_flash<<<SEQ, 256, 0, stream>>>(q, kbuf, vbuf, idx, gl, comb);

    // 7. sliding-window flash attention (comb += g2*out)
    swin_flash<<<dim3(16, 32), 256, 0, stream>>>(q, kbuf, vbuf, gl, comb);

    // 8. output projection: split comb, transpose-split Wo, 3-pass MFMA GEMM
    split_pair<<<4096, 256, 0, stream>>>(comb, Ch, Cl);
    tsplit<<<dim3(64, 64), 256, 0, stream>>>(Wo, Woh, Wol);
    gemm3s<<<dim3(16, 16), 256, 0, stream>>>(Ch, Cl, Woh, Wol, out, SEQ, HIDDEN, HIDDEN);
}

// Round 5
// 917.944 us; speedup vs baseline: 4.1988x; 1.9201x over previous
//
#include <hip/hip_runtime.h>
#include <hip/hip_bf16.h>

constexpr int SEQ    = 2048;
constexpr int HIDDEN = 2048;
constexpr int NHQ    = 16;
constexpr int DIM    = 128;
constexpr int NCB    = 64;
constexpr int NTOP   = 8;
constexpr int WINSZ  = 512;
constexpr int KVGN   = 384;   // padded width of [Wk|Wv|Wg] (128+128+48 -> 3x128)

#define SCALEF 0.08838834764831845f
#define NEGF  -1e30f

using short8 = __attribute__((ext_vector_type(8))) short;
using f32x4  = __attribute__((ext_vector_type(4))) float;

__device__ inline unsigned short f2bf(float f) {
    unsigned u = __float_as_uint(f);
    unsigned r = (u + 0x7fffu + ((u >> 16) & 1u)) >> 16;
    return (unsigned short)r;
}
__device__ inline float bf2f(unsigned short b) {
    return __uint_as_float(((unsigned)b) << 16);
}
__device__ inline float sigmoidf_(float x) { return 1.0f / (1.0f + __expf(-x)); }

// ---------------------------------------------------------------------------
// split fp32 -> (hi, lo) bf16 pair, elementwise. n % 1024 == 0.
// ---------------------------------------------------------------------------
__global__ __launch_bounds__(256) void split_pair(const float* __restrict__ in,
                                                  unsigned short* __restrict__ hi,
                                                  unsigned short* __restrict__ lo) {
    int i = (blockIdx.x * 256 + threadIdx.x) * 4;
    float4 v = *(const float4*)&in[i];
    ushort4 h, l;
    h.x = f2bf(v.x); l.x = f2bf(v.x - bf2f(h.x));
    h.y = f2bf(v.y); l.y = f2bf(v.y - bf2f(h.y));
    h.z = f2bf(v.z); l.z = f2bf(v.z - bf2f(h.z));
    h.w = f2bf(v.w); l.w = f2bf(v.w - bf2f(h.w));
    *(ushort4*)&hi[i] = h;
    *(ushort4*)&lo[i] = l;
}

// ---------------------------------------------------------------------------
// transpose + split: W[K=2048][N=2048] fp32 -> Th/Tl[N][K] bf16. 32x32 tiles.
// ---------------------------------------------------------------------------
__global__ __launch_bounds__(256) void tsplit(const float* __restrict__ W,
                                              unsigned short* __restrict__ Th,
                                              unsigned short* __restrict__ Tl) {
    __shared__ float t[32][33];
    const int k0 = blockIdx.y * 32, n0 = blockIdx.x * 32;
    const int ty = threadIdx.x >> 3, tx = threadIdx.x & 7;
    float4 v = *(const float4*)&W[(size_t)(k0 + ty) * HIDDEN + n0 + tx * 4];
    t[ty][tx * 4 + 0] = v.x; t[ty][tx * 4 + 1] = v.y;
    t[ty][tx * 4 + 2] = v.z; t[ty][tx * 4 + 3] = v.w;
    __syncthreads();
    ushort4 h, l;
    float a0 = t[tx * 4 + 0][ty], a1 = t[tx * 4 + 1][ty];
    float a2 = t[tx * 4 + 2][ty], a3 = t[tx * 4 + 3][ty];
    h.x = f2bf(a0); l.x = f2bf(a0 - bf2f(h.x));
    h.y = f2bf(a1); l.y = f2bf(a1 - bf2f(h.y));
    h.z = f2bf(a2); l.z = f2bf(a2 - bf2f(h.z));
    h.w = f2bf(a3); l.w = f2bf(a3 - bf2f(h.w));
    *(ushort4*)&Th[(size_t)(n0 + ty) * HIDDEN + k0 + tx * 4] = h;
    *(ushort4*)&Tl[(size_t)(n0 + ty) * HIDDEN + k0 + tx * 4] = l;
}

// ---------------------------------------------------------------------------
// Generic guarded transpose+split: W[2048][Nd] -> Th/Tl rows [rowOff+n][k].
// Cols >= Nd zero-filled. grid (ceil(Nd/32), 64).
// ---------------------------------------------------------------------------
__global__ __launch_bounds__(256) void tsplit_g(const float* __restrict__ W,
                                                unsigned short* __restrict__ Th,
                                                unsigned short* __restrict__ Tl,
                                                int Nd, int rowOff) {
    __shared__ float t[32][33];
    const int k0 = blockIdx.y * 32, n0 = blockIdx.x * 32;
    const int ty = threadIdx.x >> 3, tx = threadIdx.x & 7;
    #pragma unroll
    for (int j = 0; j < 4; ++j) {
        int c = n0 + tx * 4 + j;
        t[ty][tx * 4 + j] = (c < Nd) ? W[(size_t)(k0 + ty) * Nd + c] : 0.f;
    }
    __syncthreads();
    ushort4 h, l;
    float a0 = t[tx * 4 + 0][ty], a1 = t[tx * 4 + 1][ty];
    float a2 = t[tx * 4 + 2][ty], a3 = t[tx * 4 + 3][ty];
    h.x = f2bf(a0); l.x = f2bf(a0 - bf2f(h.x));
    h.y = f2bf(a1); l.y = f2bf(a1 - bf2f(h.y));
    h.z = f2bf(a2); l.z = f2bf(a2 - bf2f(h.z));
    h.w = f2bf(a3); l.w = f2bf(a3 - bf2f(h.w));
    *(ushort4*)&Th[(size_t)(rowOff + n0 + ty) * HIDDEN + k0 + tx * 4] = h;
    *(ushort4*)&Tl[(size_t)(rowOff + n0 + ty) * HIDDEN + k0 + tx * 4] = l;
}

// ---------------------------------------------------------------------------
// unpack kvg[2048][384] -> k[2048][128], v[2048][128], gl[2048][48]
// ---------------------------------------------------------------------------
__global__ __launch_bounds__(256) void unpack_kvg(const float* __restrict__ kvg,
                                                  float* __restrict__ k,
                                                  float* __restrict__ v,
                                                  float* __restrict__ g) {
    int i = blockIdx.x, t = threadIdx.x;
    if (t < 128) {
        k[(size_t)i * DIM + t] = kvg[(size_t)i * KVGN + t];
        v[(size_t)i * DIM + t] = kvg[(size_t)i * KVGN + 128 + t];
    } else if (t < 176) {
        g[(size_t)i * 48 + (t - 128)] = kvg[(size_t)i * KVGN + 256 + (t - 128)];
    }
}

// ---------------------------------------------------------------------------
// Split-bf16 MFMA GEMM (fp32-grade): C = (Ah+Al) * (Bh+Bl)^T.
// 128x128 tile, BK=32, 4 waves (2x2), 16x16x32 MFMA, 4x4 frags/wave,
// 3 MFMA per fragment pair (drop al*bl ~ 2^-18).
// ---------------------------------------------------------------------------
__global__ __launch_bounds__(256) void gemm3s(const unsigned short* __restrict__ Ah,
                                              const unsigned short* __restrict__ Al,
                                              const unsigned short* __restrict__ Bh,
                                              const unsigned short* __restrict__ Bl,
                                              float* __restrict__ C,
                                              int M, int N, int K) {
    __shared__ unsigned short sAh[4][128][8], sAl[4][128][8];
    __shared__ unsigned short sBh[4][128][8], sBl[4][128][8];
    const int tid = threadIdx.x, lane = tid & 63, wave = tid >> 6;
    const int wr = wave >> 1, wc = wave & 1;
    const int brow = blockIdx.y * 128, bcol = blockIdx.x * 128;
    const int lr = lane & 15, lc = lane >> 4;
    const int sr = tid & 127, sc0 = tid >> 7;

    f32x4 acc[4][4];
    #pragma unroll
    for (int a = 0; a < 4; ++a)
        #pragma unroll
        for (int b = 0; b < 4; ++b) acc[a][b] = (f32x4){0.f, 0.f, 0.f, 0.f};

    for (int k0 = 0; k0 < K; k0 += 32) {
        #pragma unroll
        for (int i = 0; i < 2; ++i) {
            int c = i * 2 + sc0;
            size_t ao = (size_t)(brow + sr) * K + k0 + c * 8;
            size_t bo = (size_t)(bcol + sr) * K + k0 + c * 8;
            *(short8*)&sAh[c][sr][0] = *(const short8*)&Ah[ao];
            *(short8*)&sAl[c][sr][0] = *(const short8*)&Al[ao];
            *(short8*)&sBh[c][sr][0] = *(const short8*)&Bh[bo];
            *(short8*)&sBl[c][sr][0] = *(const short8*)&Bl[bo];
        }
        __syncthreads();
        short8 fah[4], fal[4], fbh[4], fbl[4];
        #pragma unroll
        for (int mi = 0; mi < 4; ++mi) {
            fah[mi] = *(short8*)&sAh[lc][wr * 64 + mi * 16 + lr][0];
            fal[mi] = *(short8*)&sAl[lc][wr * 64 + mi * 16 + lr][0];
        }
        #pragma unroll
        for (int ni = 0; ni < 4; ++ni) {
            fbh[ni] = *(short8*)&sBh[lc][wc * 64 + ni * 16 + lr][0];
            fbl[ni] = *(short8*)&sBl[lc][wc * 64 + ni * 16 + lr][0];
        }
        #pragma unroll
        for (int mi = 0; mi < 4; ++mi)
            #pragma unroll
            for (int ni = 0; ni < 4; ++ni) {
                acc[mi][ni] = __builtin_amdgcn_mfma_f32_16x16x32_bf16(fah[mi], fbh[ni], acc[mi][ni], 0, 0, 0);
                acc[mi][ni] = __builtin_amdgcn_mfma_f32_16x16x32_bf16(fal[mi], fbh[ni], acc[mi][ni], 0, 0, 0);
                acc[mi][ni] = __builtin_amdgcn_mfma_f32_16x16x32_bf16(fah[mi], fbl[ni], acc[mi][ni], 0, 0, 0);
            }
        __syncthreads();
    }
    #pragma unroll
    for (int mi = 0; mi < 4; ++mi)
        #pragma unroll
        for (int ni = 0; ni < 4; ++ni) {
            int col  = bcol + wc * 64 + ni * 16 + lr;
            int rowb = brow + wr * 64 + mi * 16 + lc * 4;
            #pragma unroll
            for (int r = 0; r < 4; ++r)
                C[(size_t)(rowb + r) * N + col] = acc[mi][ni][r];
        }
}

// ---------------------------------------------------------------------------
// Compress: ck[m]=rope(mean(k+pe), pos=32m), cv[m]=mean(v). Un-roped k input.
// ---------------------------------------------------------------------------
__global__ void compress_kernel(const float* __restrict__ k,
                                const float* __restrict__ v,
                                const float* __restrict__ pe,
                                float* __restrict__ ck,
                                float* __restrict__ cv) {
    int m = blockIdx.x, d = threadIdx.x;
    float sk = 0.f, sv = 0.f, sp = 0.f;
    for (int s = 0; s < 32; ++s) {
        sk += k[(size_t)(m * 32 + s) * DIM + d];
        sv += v[(size_t)(m * 32 + s) * DIM + d];
        sp += pe[s * DIM + d];
    }
    float ckv = (sk + sp) * (1.0f / 32.0f);
    cv[m * DIM + d] = sv * (1.0f / 32.0f);
    __shared__ float tmp[DIM];
    tmp[d] = ckv;
    __syncthreads();
    int j = d & 63;
    float inv = powf(10000.0f, -(float)(2 * j) / 128.0f);
    float ang = (float)(m * 32) * inv;
    float c = cosf(ang), s = sinf(ang);
    float x1 = tmp[j], x2 = tmp[j + 64];
    ck[m * DIM + d] = (d < 64) ? (x1 * c - x2 * s) : (x2 * c + x1 * s);
}

__global__ void rope_qk(float* __restrict__ q, float* __restrict__ k) {
    int i = blockIdx.x, j = threadIdx.x;
    float inv = powf(10000.0f, -(float)(2 * j) / 128.0f);
    float ang = (float)i * inv;
    float c = cosf(ang), s = sinf(ang);
    for (int h = 0; h < NHQ; ++h) {
        float* p = q + ((size_t)i * NHQ + h) * DIM;
        float x1 = p[j], x2 = p[j + 64];
        p[j]      = x1 * c - x2 * s;
        p[j + 64] = x2 * c + x1 * s;
    }
    float* p = k + (size_t)i * DIM;
    float x1 = p[j], x2 = p[j + 64];
    p[j]      = x1 * c - x2 * s;
    p[j + 64] = x2 * c + x1 * s;
}

// ---------------------------------------------------------------------------
// Compressed attention per token: writes comb (fp32, full init) + blk scores.
// ---------------------------------------------------------------------------
__global__ __launch_bounds__(256) void cmp_flash(const float* __restrict__ q,
                                                 const float* __restrict__ ck,
                                                 const float* __restrict__ cv,
                                                 const float* __restrict__ gl,
                                                 float* __restrict__ comb,
                                                 float* __restrict__ blk) {
    const int i = blockIdx.x, tid = threadIdx.x, wave = tid >> 6, lane = tid & 63;
    __shared__ float Qs[16][132];
    __shared__ float KV[64][132];
    __shared__ float ss[16][66];

    for (int t = tid; t < 512; t += 256) {
        int r = t >> 5, c4 = (t & 31) * 4;
        *(float4*)&Qs[r][c4] = *(const float4*)&q[(size_t)i * HIDDEN + r * DIM + c4];
    }
    for (int t = tid; t < 2048; t += 256) {
        int r = t >> 5, c4 = (t & 31) * 4;
        *(float4*)&KV[r][c4] = *(const float4*)&ck[(size_t)r * DIM + c4];
    }
    __syncthreads();

    const int hi = lane & 15, mg = lane >> 4;
    float s4[4] = {0.f, 0.f, 0.f, 0.f};
    for (int d = 0; d < 128; d += 4) {
        float4 qv = *(float4*)&Qs[hi][d];
        #pragma unroll
        for (int jj = 0; jj < 4; ++jj) {
            float4 kv = *(float4*)&KV[wave * 16 + mg * 4 + jj][d];
            s4[jj] = fmaf(qv.x, kv.x, fmaf(qv.y, kv.y, fmaf(qv.z, kv.z, fmaf(qv.w, kv.w, s4[jj]))));
        }
    }
    #pragma unroll
    for (int jj = 0; jj < 4; ++jj) {
        int m = wave * 16 + mg * 4 + jj;
        ss[hi][m] = (i >= m * 32 + 31) ? s4[jj] * SCALEF : NEGF;
    }
    __syncthreads();

    for (int hh = 0; hh < 4; ++hh) {
        int h = wave * 4 + hh;
        float val = ss[h][lane];
        float mx = val;
        for (int o = 32; o; o >>= 1) mx = fmaxf(mx, __shfl_xor(mx, o));
        float e = (val <= NEGF * 0.5f) ? 0.f : __expf(val - mx);
        float z = e;
        for (int o = 32; o; o >>= 1) z += __shfl_xor(z, o);
        ss[h][lane] = (z > 0.f) ? e * (1.0f / z) : 0.f;
    }
    __syncthreads();

    if (tid < 64) {
        float sb = 0.f;
        for (int h = 0; h < 16; ++h) sb += ss[h][tid];
        blk[(size_t)i * NCB + tid] = sb;
    }

    for (int t = tid; t < 2048; t += 256) {
        int r = t >> 5, c4 = (t & 31) * 4;
        *(float4*)&KV[r][c4] = *(const float4*)&cv[(size_t)r * DIM + c4];
    }
    __syncthreads();

    const int h2 = tid & 15, dg = tid >> 4;
    float o8[8] = {0.f,0.f,0.f,0.f,0.f,0.f,0.f,0.f};
    for (int kk = 0; kk < 64; ++kk) {
        float p = ss[h2][kk];
        float4 va = *(float4*)&KV[kk][dg * 8];
        float4 vb = *(float4*)&KV[kk][dg * 8 + 4];
        o8[0] = fmaf(p, va.x, o8[0]); o8[1] = fmaf(p, va.y, o8[1]);
        o8[2] = fmaf(p, va.z, o8[2]); o8[3] = fmaf(p, va.w, o8[3]);
        o8[4] = fmaf(p, vb.x, o8[4]); o8[5] = fmaf(p, vb.y, o8[5]);
        o8[6] = fmaf(p, vb.z, o8[6]); o8[7] = fmaf(p, vb.w, o8[7]);
    }
    float g0 = sigmoidf_(gl[(size_t)i * 48 + h2 * 3 + 0]);
    #pragma unroll
    for (int x = 0; x < 8; ++x)
        comb[(size_t)i * HIDDEN + h2 * DIM + dg * 8 + x] = g0 * o8[x];
}

// ---------------------------------------------------------------------------
// Top-k (exact jax.lax.top_k tie semantics). LDS-staged, 256 tokens/block.
// ---------------------------------------------------------------------------
__global__ __launch_bounds__(256) void topk2(const float* __restrict__ blk,
                                             int* __restrict__ oidx) {
    __shared__ float L[256][68];
    int base = blockIdx.x * 256;
    for (int t = threadIdx.x; t < 256 * 16; t += 256) {
        int r = t >> 4, c4 = (t & 15) * 4;
        *(float4*)&L[r][c4] = *(const float4*)&blk[(size_t)(base + r) * NCB + c4];
    }
    __syncthreads();
    int i = base + threadIdx.x;
    int tb = i >> 5;
    unsigned long long used = 0ull;
    for (int t = 0; t < NTOP; ++t) {
        float best = -3e38f; int bi = 0;
        for (int m = 0; m < NCB; ++m) {
            if ((used >> m) & 1ull) continue;
            float s = L[threadIdx.x][m];
            if (m > tb) s = NEGF;
            if (m == 0 || (m <= tb && m > tb - 2)) s = 1e30f;
            if (s > best) { best = s; bi = m; }
        }
        used |= 1ull << bi;
        oidx[i * NTOP + t] = bi;
    }
}

// ---------------------------------------------------------------------------
// Sparse top-k attention per token. comb += g1*out. (fp32 comb)
// ---------------------------------------------------------------------------
__global__ __launch_bounds__(256) void sparse_flash(const float* __restrict__ q,
                                                    const float* __restrict__ k,
                                                    const float* __restrict__ v,
                                                    const int* __restrict__ idx,
                                                    const float* __restrict__ gl,
                                                    float* __restrict__ comb) {
    const int i = blockIdx.x, tid = threadIdx.x, wave = tid >> 6, lane = tid & 63;
    __shared__ float Qs[16][132];
    __shared__ float KV[32][132];
    __shared__ float ss[16][266];
    __shared__ int sb[8];
    if (tid < 8) sb[tid] = idx[i * NTOP + tid];
    for (int t = tid; t < 512; t += 256) {
        int r = t >> 5, c4 = (t & 31) * 4;
        *(float4*)&Qs[r][c4] = *(const float4*)&q[(size_t)i * HIDDEN + r * DIM + c4];
    }
    __syncthreads();

    const int hi = lane & 15, kg = lane >> 4;
    for (int c = 0; c < 8; ++c) {
        int kb = sb[c] * 32;
        for (int t = tid; t < 1024; t += 256) {
            int r = t >> 5, c4 = (t & 31) * 4;
            *(float4*)&KV[r][c4] = *(const float4*)&k[(size_t)(kb + r) * DIM + c4];
        }
        __syncthreads();
        float s2[2] = {0.f, 0.f};
        for (int d = 0; d < 128; d += 4) {
            float4 qv = *(float4*)&Qs[hi][d];
            #pragma unroll
            for (int jj = 0; jj < 2; ++jj) {
                float4 kv = *(float4*)&KV[wave * 8 + kg * 2 + jj][d];
                s2[jj] = fmaf(qv.x, kv.x, fmaf(qv.y, kv.y, fmaf(qv.z, kv.z, fmaf(qv.w, kv.w, s2[jj]))));
            }
        }
        #pragma unroll
        for (int jj = 0; jj < 2; ++jj) {
            int kl = wave * 8 + kg * 2 + jj;
            int pos = kb + kl;
            ss[hi][c * 32 + kl] = (pos <= i) ? s2[jj] * SCALEF : NEGF;
        }
        __syncthreads();
    }

    for (int hh = 0; hh < 4; ++hh) {
        int h = wave * 4 + hh;
        float v0 = ss[h][lane], v1 = ss[h][64 + lane], v2 = ss[h][128 + lane], v3 = ss[h][192 + lane];
        float mx = fmaxf(fmaxf(v0, v1), fmaxf(v2, v3));
        for (int o = 32; o; o >>= 1) mx = fmaxf(mx, __shfl_xor(mx, o));
        float e0 = (v0 <= NEGF * 0.5f) ? 0.f : __expf(v0 - mx);
        float e1 = (v1 <= NEGF * 0.5f) ? 0.f : __expf(v1 - mx);
        float e2 = (v2 <= NEGF * 0.5f) ? 0.f : __expf(v2 - mx);
        float e3 = (v3 <= NEGF * 0.5f) ? 0.f : __expf(v3 - mx);
        float z = e0 + e1 + e2 + e3;
        for (int o = 32; o; o >>= 1) z += __shfl_xor(z, o);
        float rz = 1.0f / z;
        ss[h][lane] = e0 * rz; ss[h][64 + lane] = e1 * rz;
        ss[h][128 + lane] = e2 * rz; ss[h][192 + lane] = e3 * rz;
    }
    __syncthreads();

    const int h2 = tid & 15, dg = tid >> 4;
    float o8[8] = {0.f,0.f,0.f,0.f,0.f,0.f,0.f,0.f};
    for (int c = 0; c < 8; ++c) {
        int kb = sb[c] * 32;
        for (int t = tid; t < 1024; t += 256) {
            int r = t >> 5, c4 = (t & 31) * 4;
            *(float4*)&KV[r][c4] = *(const float4*)&v[(size_t)(kb + r) * DIM + c4];
        }
        __syncthreads();
        for (int kk = 0; kk < 32; ++kk) {
            float p = ss[h2][c * 32 + kk];
            float4 va = *(float4*)&KV[kk][dg * 8];
            float4 vb = *(float4*)&KV[kk][dg * 8 + 4];
            o8[0] = fmaf(p, va.x, o8[0]); o8[1] = fmaf(p, va.y, o8[1]);
            o8[2] = fmaf(p, va.z, o8[2]); o8[3] = fmaf(p, va.w, o8[3]);
            o8[4] = fmaf(p, vb.x, o8[4]); o8[5] = fmaf(p, vb.y, o8[5]);
            o8[6] = fmaf(p, vb.z, o8[6]); o8[7] = fmaf(p, vb.w, o8[7]);
        }
        __syncthreads();
    }
    float g1 = sigmoidf_(gl[(size_t)i * 48 + h2 * 3 + 1]);
    #pragma unroll
    for (int x = 0; x < 8; ++x)
        comb[(size_t)i * HIDDEN + h2 * DIM + dg * 8 + x] += g1 * o8[x];
}

// ---------------------------------------------------------------------------
// Sliding-window flash attention: 64-query tile x 1 head per block.
// grid (16 heads, 32 tiles). Static register indices; conflict-free geometry.
// ---------------------------------------------------------------------------
__global__ __launch_bounds__(256) void swin_flash(const float* __restrict__ q,
                                                  const float* __restrict__ k,
                                                  const float* __restrict__ v,
                                                  const float* __restrict__ gl,
                                                  float* __restrict__ comb) {
    const int h = blockIdx.x, qt = blockIdx.y;
    const int q0 = qt * 64;
    const int s0 = (q0 - WINSZ > 0) ? (q0 - WINSZ) : 0;
    const int nch = (q0 + 64 - s0) >> 5;
    const int tid = threadIdx.x, wave = tid >> 6, lane = tid & 63;

    __shared__ float Qs[64][132];
    __shared__ float Ks[32][132];
    __shared__ float Vs[32][132];
    __shared__ float Ps[64][33];

    for (int t = tid; t < 2048; t += 256) {
        int r = t >> 5, c4 = (t & 31) * 4;
        *(float4*)&Qs[r][c4] = *(const float4*)&q[((size_t)(q0 + r) * NHQ + h) * DIM + c4];
    }

    const int qi = lane & 15, kg = lane >> 4;
    const int myq = wave * 16 + qi;
    const int gq = q0 + myq;
    float m = -3e38f, l = 0.f;
    float4 acc4[8];
    #pragma unroll
    for (int b = 0; b < 8; ++b) acc4[b] = make_float4(0.f, 0.f, 0.f, 0.f);
    __syncthreads();

    for (int c = 0; c < nch; ++c) {
        int kb = s0 + c * 32;
        for (int t = tid; t < 1024; t += 256) {
            int r = t >> 5, c4 = (t & 31) * 4;
            *(float4*)&Ks[r][c4] = *(const float4*)&k[(size_t)(kb + r) * DIM + c4];
            *(float4*)&Vs[r][c4] = *(const float4*)&v[(size_t)(kb + r) * DIM + c4];
        }
        __syncthreads();

        float s[8] = {0.f,0.f,0.f,0.f,0.f,0.f,0.f,0.f};
        for (int d = 0; d < 128; d += 4) {
            float4 qv = *(float4*)&Qs[myq][d];
            #pragma unroll
            for (int b = 0; b < 8; ++b) {
                float4 kv = *(float4*)&Ks[b * 4 + kg][d];
                s[b] = fmaf(qv.x, kv.x, fmaf(qv.y, kv.y, fmaf(qv.z, kv.z, fmaf(qv.w, kv.w, s[b]))));
            }
        }
        float mx = -3e38f;
        #pragma unroll
        for (int b = 0; b < 8; ++b) {
            int pos = kb + b * 4 + kg;
            bool ok = (pos <= gq) && (pos >= gq - WINSZ);
            s[b] = ok ? s[b] * SCALEF : -3e38f;
            mx = fmaxf(mx, s[b]);
        }
        mx = fmaxf(mx, __shfl_xor(mx, 16));
        mx = fmaxf(mx, __shfl_xor(mx, 32));
        float mnew = fmaxf(m, mx);
        float corr = __expf(m - mnew);
        float psum = 0.f;
        #pragma unroll
        for (int b = 0; b < 8; ++b) {
            float p = (s[b] <= -1e37f) ? 0.f : __expf(s[b] - mnew);
            Ps[myq][b * 4 + kg] = p;
            psum += p;
        }
        psum += __shfl_xor(psum, 16);
        psum += __shfl_xor(psum, 32);
        l = l * corr + psum;
        m = mnew;
        #pragma unroll
        for (int b = 0; b < 8; ++b) {
            acc4[b].x *= corr; acc4[b].y *= corr; acc4[b].z *= corr; acc4[b].w *= corr;
        }
        for (int kk = 0; kk < 32; ++kk) {
            float p = Ps[myq][kk];
            #pragma unroll
            for (int b = 0; b < 8; ++b) {
                float4 vv = *(float4*)&Vs[kk][b * 16 + kg * 4];
                acc4[b].x = fmaf(p, vv.x, acc4[b].x);
                acc4[b].y = fmaf(p, vv.y, acc4[b].y);
                acc4[b].z = fmaf(p, vv.z, acc4[b].z);
                acc4[b].w = fmaf(p, vv.w, acc4[b].w);
            }
        }
        __syncthreads();
    }

    float linv = 1.0f / l;
    float g2 = sigmoidf_(gl[(size_t)gq * 48 + h * 3 + 2]);
    #pragma unroll
    for (int b = 0; b < 8; ++b) {
        size_t o = (size_t)gq * HIDDEN + h * DIM + b * 16 + kg * 4;
        comb[o + 0] += g2 * acc4[b].x * linv;
        comb[o + 1] += g2 * acc4[b].y * linv;
        comb[o + 2] += g2 * acc4[b].z * linv;
        comb[o + 3] += g2 * acc4[b].w * linv;
    }
}

// ---------------------------------------------------------------------------
extern "C" void kernel_launch(void* const* d_in, const int* in_sizes, int n_in,
                              void* d_out, int out_size, void* d_ws, size_t ws_size,
                              hipStream_t stream) {
    const float* x  = (const float*)d_in[0];
    const float* Wq = (const float*)d_in[2];
    const float* Wk = (const float*)d_in[3];
    const float* Wv = (const float*)d_in[4];
    const float* Wo = (const float*)d_in[5];
    const float* Wg = (const float*)d_in[6];
    const float* pe = (const float*)d_in[7];
    float* out = (float*)d_out;

    // workspace layout (36.7 MB, proven footprint)
    char* w = (char*)d_ws;
    float* q    = (float*)(w);               // 16 MB  (early: kvgOut + kvgBt scratch)
    float* comb = (float*)(w + 16777216);    // 16 MB  (early: x hi/lo; late: Wo hi/lo)
    float* kbuf = (float*)(w + 33554432);    // 1 MB
    float* vbuf = (float*)(w + 34603008);    // 1 MB
    float* gl   = (float*)(w + 35651584);    // 384 KB
    float* ck   = (float*)(w + 36044800);    // 32 KB
    float* cv   = (float*)(w + 36077568);    // 32 KB
    float* blk  = (float*)(w + 36110336);    // 512 KB
    int*   idx  = (int*)  (w + 36634624);    // 64 KB

    // scratch aliases
    unsigned short* Xh   = (unsigned short*)comb;            // 8 MB (x hi)
    unsigned short* Xl   = Xh + 4194304;                     // 8 MB (x lo)
    unsigned short* Wqh  = (unsigned short*)out;             // d_out dead until final
    unsigned short* Wql  = Wqh + 4194304;
    unsigned short* Ch   = (unsigned short*)q;               // q dead after attn
    unsigned short* Cl   = Ch + 4194304;
    unsigned short* Woh  = (unsigned short*)comb;            // comb dead after split
    unsigned short* Wol  = Woh + 4194304;
    float*          kvgOut = q;                              // q region offset 0 (3 MB)
    unsigned short* kvgBth = (unsigned short*)(w + 4194304); // q region +4 MB (1.5 MB)
    unsigned short* kvgBtl = kvgBth + 786432;                // +1.5 MB

    // 1. split x (comb region)
    split_pair<<<4096, 256, 0, stream>>>(x, Xh, Xl);

    // 2. combined k/v/gate projection via MFMA: Bt = [Wk|Wv|Wg] padded to 384
    tsplit_g<<<dim3(4, 64), 256, 0, stream>>>(Wk, kvgBth, kvgBtl, 128, 0);
    tsplit_g<<<dim3(4, 64), 256, 0, stream>>>(Wv, kvgBth, kvgBtl, 128, 128);
    tsplit_g<<<dim3(2, 64), 256, 0, stream>>>(Wg, kvgBth, kvgBtl, 48,  256);
    gemm3s<<<dim3(3, 16), 256, 0, stream>>>(Xh, Xl, kvgBth, kvgBtl, kvgOut,
                                            SEQ, KVGN, HIDDEN);
    unpack_kvg<<<SEQ, 256, 0, stream>>>(kvgOut, kbuf, vbuf, gl);

    // 3. q projection (overwrites kvg scratch in q region)
    tsplit<<<dim3(64, 64), 256, 0, stream>>>(Wq, Wqh, Wql);
    gemm3s<<<dim3(16, 16), 256, 0, stream>>>(Xh, Xl, Wqh, Wql, q, SEQ, HIDDEN, HIDDEN);

    // 4. compress (un-roped k) then rope q,k
    compress_kernel<<<NCB, DIM, 0, stream>>>(kbuf, vbuf, pe, ck, cv);
    rope_qk<<<SEQ, 64, 0, stream>>>(q, kbuf);

    // 5. compressed attention -> comb fp32 (full init; x dead now) + blk
    cmp_flash<<<SEQ, 256, 0, stream>>>(q, ck, cv, gl, comb, blk);

    // 6. top-k
    topk2<<<SEQ / 256, 256, 0, stream>>>(blk, idx);

    // 7. sparse attention (comb += g1*out)
    sparse_flash<<<SEQ, 256, 0, stream>>>(q, kbuf, vbuf, idx, gl, comb);

    // 8. sliding-window flash attention (comb += g2*out)
    swin_flash<<<dim3(16, 32), 256, 0, stream>>>(q, kbuf, vbuf, gl, comb);

    // 9. output projection: split comb, transpose-split Wo, 3-pass MFMA GEMM
    split_pair<<<4096, 256, 0, stream>>>(comb, Ch, Cl);
    tsplit<<<dim3(64, 64), 256, 0, stream>>>(Wo, Woh, Wol);
    gemm3s<<<dim3(16, 16), 256, 0, stream>>>(Ch, Cl, Woh, Wol, out, SEQ, HIDDEN, HIDDEN);
}

// Round 6
// 750.215 us; speedup vs baseline: 5.1375x; 1.2236x over previous
//
#include <hip/hip_runtime.h>
#include <hip/hip_bf16.h>

constexpr int SEQ    = 2048;
constexpr int HIDDEN = 2048;
constexpr int NHQ    = 16;
constexpr int DIM    = 128;
constexpr int NCB    = 64;
constexpr int NTOP   = 8;
constexpr int WINSZ  = 512;
constexpr int KVGN   = 384;

#define SCALEF 0.08838834764831845f
#define NEGF  -1e30f

using short8 = __attribute__((ext_vector_type(8))) short;
using f32x4  = __attribute__((ext_vector_type(4))) float;

__device__ inline unsigned short f2bf(float f) {
    unsigned u = __float_as_uint(f);
    unsigned r = (u + 0x7fffu + ((u >> 16) & 1u)) >> 16;
    return (unsigned short)r;
}
__device__ inline float bf2f(unsigned short b) {
    return __uint_as_float(((unsigned)b) << 16);
}
__device__ inline float sigmoidf_(float x) { return 1.0f / (1.0f + __expf(-x)); }

// ---------------------------------------------------------------------------
// split fp32 -> (hi, lo) bf16 pair, elementwise.
// ---------------------------------------------------------------------------
__global__ __launch_bounds__(256) void split_pair(const float* __restrict__ in,
                                                  unsigned short* __restrict__ hi,
                                                  unsigned short* __restrict__ lo) {
    int i = (blockIdx.x * 256 + threadIdx.x) * 4;
    float4 v = *(const float4*)&in[i];
    ushort4 h, l;
    h.x = f2bf(v.x); l.x = f2bf(v.x - bf2f(h.x));
    h.y = f2bf(v.y); l.y = f2bf(v.y - bf2f(h.y));
    h.z = f2bf(v.z); l.z = f2bf(v.z - bf2f(h.z));
    h.w = f2bf(v.w); l.w = f2bf(v.w - bf2f(h.w));
    *(ushort4*)&hi[i] = h;
    *(ushort4*)&lo[i] = l;
}

// ---------------------------------------------------------------------------
// transpose + split: W[2048][2048] fp32 -> Th/Tl[N][K] bf16. 32x32 tiles.
// ---------------------------------------------------------------------------
__global__ __launch_bounds__(256) void tsplit(const float* __restrict__ W,
                                              unsigned short* __restrict__ Th,
                                              unsigned short* __restrict__ Tl) {
    __shared__ float t[32][33];
    const int k0 = blockIdx.y * 32, n0 = blockIdx.x * 32;
    const int ty = threadIdx.x >> 3, tx = threadIdx.x & 7;
    float4 v = *(const float4*)&W[(size_t)(k0 + ty) * HIDDEN + n0 + tx * 4];
    t[ty][tx * 4 + 0] = v.x; t[ty][tx * 4 + 1] = v.y;
    t[ty][tx * 4 + 2] = v.z; t[ty][tx * 4 + 3] = v.w;
    __syncthreads();
    ushort4 h, l;
    float a0 = t[tx * 4 + 0][ty], a1 = t[tx * 4 + 1][ty];
    float a2 = t[tx * 4 + 2][ty], a3 = t[tx * 4 + 3][ty];
    h.x = f2bf(a0); l.x = f2bf(a0 - bf2f(h.x));
    h.y = f2bf(a1); l.y = f2bf(a1 - bf2f(h.y));
    h.z = f2bf(a2); l.z = f2bf(a2 - bf2f(h.z));
    h.w = f2bf(a3); l.w = f2bf(a3 - bf2f(h.w));
    *(ushort4*)&Th[(size_t)(n0 + ty) * HIDDEN + k0 + tx * 4] = h;
    *(ushort4*)&Tl[(size_t)(n0 + ty) * HIDDEN + k0 + tx * 4] = l;
}

// ---------------------------------------------------------------------------
// Generic guarded transpose+split: W[2048][Nd] -> rows [rowOff+n][k].
// ---------------------------------------------------------------------------
__global__ __launch_bounds__(256) void tsplit_g(const float* __restrict__ W,
                                                unsigned short* __restrict__ Th,
                                                unsigned short* __restrict__ Tl,
                                                int Nd, int rowOff) {
    __shared__ float t[32][33];
    const int k0 = blockIdx.y * 32, n0 = blockIdx.x * 32;
    const int ty = threadIdx.x >> 3, tx = threadIdx.x & 7;
    #pragma unroll
    for (int j = 0; j < 4; ++j) {
        int c = n0 + tx * 4 + j;
        t[ty][tx * 4 + j] = (c < Nd) ? W[(size_t)(k0 + ty) * Nd + c] : 0.f;
    }
    __syncthreads();
    ushort4 h, l;
    float a0 = t[tx * 4 + 0][ty], a1 = t[tx * 4 + 1][ty];
    float a2 = t[tx * 4 + 2][ty], a3 = t[tx * 4 + 3][ty];
    h.x = f2bf(a0); l.x = f2bf(a0 - bf2f(h.x));
    h.y = f2bf(a1); l.y = f2bf(a1 - bf2f(h.y));
    h.z = f2bf(a2); l.z = f2bf(a2 - bf2f(h.z));
    h.w = f2bf(a3); l.w = f2bf(a3 - bf2f(h.w));
    *(ushort4*)&Th[(size_t)(rowOff + n0 + ty) * HIDDEN + k0 + tx * 4] = h;
    *(ushort4*)&Tl[(size_t)(rowOff + n0 + ty) * HIDDEN + k0 + tx * 4] = l;
}

// ---------------------------------------------------------------------------
// unpack kvg[2048][384] -> k, v, gl
// ---------------------------------------------------------------------------
__global__ __launch_bounds__(256) void unpack_kvg(const float* __restrict__ kvg,
                                                  float* __restrict__ k,
                                                  float* __restrict__ v,
                                                  float* __restrict__ g) {
    int i = blockIdx.x, t = threadIdx.x;
    if (t < 128) {
        k[(size_t)i * DIM + t] = kvg[(size_t)i * KVGN + t];
        v[(size_t)i * DIM + t] = kvg[(size_t)i * KVGN + 128 + t];
    } else if (t < 176) {
        g[(size_t)i * 48 + (t - 128)] = kvg[(size_t)i * KVGN + 256 + (t - 128)];
    }
}

// ---------------------------------------------------------------------------
// Split-bf16 MFMA GEMM (fp32-grade), 128x128 tile, BK=32, 3 MFMA/frag pair.
// ---------------------------------------------------------------------------
__global__ __launch_bounds__(256) void gemm3s(const unsigned short* __restrict__ Ah,
                                              const unsigned short* __restrict__ Al,
                                              const unsigned short* __restrict__ Bh,
                                              const unsigned short* __restrict__ Bl,
                                              float* __restrict__ C,
                                              int M, int N, int K) {
    __shared__ unsigned short sAh[4][128][8], sAl[4][128][8];
    __shared__ unsigned short sBh[4][128][8], sBl[4][128][8];
    const int tid = threadIdx.x, lane = tid & 63, wave = tid >> 6;
    const int wr = wave >> 1, wc = wave & 1;
    const int brow = blockIdx.y * 128, bcol = blockIdx.x * 128;
    const int lr = lane & 15, lc = lane >> 4;
    const int sr = tid & 127, sc0 = tid >> 7;

    f32x4 acc[4][4];
    #pragma unroll
    for (int a = 0; a < 4; ++a)
        #pragma unroll
        for (int b = 0; b < 4; ++b) acc[a][b] = (f32x4){0.f, 0.f, 0.f, 0.f};

    for (int k0 = 0; k0 < K; k0 += 32) {
        #pragma unroll
        for (int i = 0; i < 2; ++i) {
            int c = i * 2 + sc0;
            size_t ao = (size_t)(brow + sr) * K + k0 + c * 8;
            size_t bo = (size_t)(bcol + sr) * K + k0 + c * 8;
            *(short8*)&sAh[c][sr][0] = *(const short8*)&Ah[ao];
            *(short8*)&sAl[c][sr][0] = *(const short8*)&Al[ao];
            *(short8*)&sBh[c][sr][0] = *(const short8*)&Bh[bo];
            *(short8*)&sBl[c][sr][0] = *(const short8*)&Bl[bo];
        }
        __syncthreads();
        short8 fah[4], fal[4], fbh[4], fbl[4];
        #pragma unroll
        for (int mi = 0; mi < 4; ++mi) {
            fah[mi] = *(short8*)&sAh[lc][wr * 64 + mi * 16 + lr][0];
            fal[mi] = *(short8*)&sAl[lc][wr * 64 + mi * 16 + lr][0];
        }
        #pragma unroll
        for (int ni = 0; ni < 4; ++ni) {
            fbh[ni] = *(short8*)&sBh[lc][wc * 64 + ni * 16 + lr][0];
            fbl[ni] = *(short8*)&sBl[lc][wc * 64 + ni * 16 + lr][0];
        }
        #pragma unroll
        for (int mi = 0; mi < 4; ++mi)
            #pragma unroll
            for (int ni = 0; ni < 4; ++ni) {
                acc[mi][ni] = __builtin_amdgcn_mfma_f32_16x16x32_bf16(fah[mi], fbh[ni], acc[mi][ni], 0, 0, 0);
                acc[mi][ni] = __builtin_amdgcn_mfma_f32_16x16x32_bf16(fal[mi], fbh[ni], acc[mi][ni], 0, 0, 0);
                acc[mi][ni] = __builtin_amdgcn_mfma_f32_16x16x32_bf16(fah[mi], fbl[ni], acc[mi][ni], 0, 0, 0);
            }
        __syncthreads();
    }
    #pragma unroll
    for (int mi = 0; mi < 4; ++mi)
        #pragma unroll
        for (int ni = 0; ni < 4; ++ni) {
            int col  = bcol + wc * 64 + ni * 16 + lr;
            int rowb = brow + wr * 64 + mi * 16 + lc * 4;
            #pragma unroll
            for (int r = 0; r < 4; ++r)
                C[(size_t)(rowb + r) * N + col] = acc[mi][ni][r];
        }
}

// ---------------------------------------------------------------------------
// Compress: ck[m]=rope(mean(k+pe), pos=32m), cv[m]=mean(v). Un-roped k input.
// ---------------------------------------------------------------------------
__global__ void compress_kernel(const float* __restrict__ k,
                                const float* __restrict__ v,
                                const float* __restrict__ pe,
                                float* __restrict__ ck,
                                float* __restrict__ cv) {
    int m = blockIdx.x, d = threadIdx.x;
    float sk = 0.f, sv = 0.f, sp = 0.f;
    for (int s = 0; s < 32; ++s) {
        sk += k[(size_t)(m * 32 + s) * DIM + d];
        sv += v[(size_t)(m * 32 + s) * DIM + d];
        sp += pe[s * DIM + d];
    }
    float ckv = (sk + sp) * (1.0f / 32.0f);
    cv[m * DIM + d] = sv * (1.0f / 32.0f);
    __shared__ float tmp[DIM];
    tmp[d] = ckv;
    __syncthreads();
    int j = d & 63;
    float inv = powf(10000.0f, -(float)(2 * j) / 128.0f);
    float ang = (float)(m * 32) * inv;
    float c = cosf(ang), s = sinf(ang);
    float x1 = tmp[j], x2 = tmp[j + 64];
    ck[m * DIM + d] = (d < 64) ? (x1 * c - x2 * s) : (x2 * c + x1 * s);
}

__global__ void rope_qk(float* __restrict__ q, float* __restrict__ k) {
    int i = blockIdx.x, j = threadIdx.x;
    float inv = powf(10000.0f, -(float)(2 * j) / 128.0f);
    float ang = (float)i * inv;
    float c = cosf(ang), s = sinf(ang);
    for (int h = 0; h < NHQ; ++h) {
        float* p = q + ((size_t)i * NHQ + h) * DIM;
        float x1 = p[j], x2 = p[j + 64];
        p[j]      = x1 * c - x2 * s;
        p[j + 64] = x2 * c + x1 * s;
    }
    float* p = k + (size_t)i * DIM;
    float x1 = p[j], x2 = p[j + 64];
    p[j]      = x1 * c - x2 * s;
    p[j + 64] = x2 * c + x1 * s;
}

// ---------------------------------------------------------------------------
// prep: qb16 = bf16(q * SCALE) [2048][2048]; kb16 = bf16(k) [2048][128]
// ---------------------------------------------------------------------------
__global__ __launch_bounds__(256) void prep_cast(const float* __restrict__ q,
                                                 const float* __restrict__ k,
                                                 unsigned short* __restrict__ qb,
                                                 unsigned short* __restrict__ kb) {
    int i = blockIdx.x, t = threadIdx.x;
    {
        int d0 = t * 8;
        float4 a = *(const float4*)&q[(size_t)i * HIDDEN + d0];
        float4 b = *(const float4*)&q[(size_t)i * HIDDEN + d0 + 4];
        ushort4 ha, hb;
        ha.x = f2bf(a.x * SCALEF); ha.y = f2bf(a.y * SCALEF);
        ha.z = f2bf(a.z * SCALEF); ha.w = f2bf(a.w * SCALEF);
        hb.x = f2bf(b.x * SCALEF); hb.y = f2bf(b.y * SCALEF);
        hb.z = f2bf(b.z * SCALEF); hb.w = f2bf(b.w * SCALEF);
        *(ushort4*)&qb[(size_t)i * HIDDEN + d0] = ha;
        *(ushort4*)&qb[(size_t)i * HIDDEN + d0 + 4] = hb;
    }
    if (t < 16) {
        int d0 = t * 8;
        float4 a = *(const float4*)&k[(size_t)i * DIM + d0];
        float4 b = *(const float4*)&k[(size_t)i * DIM + d0 + 4];
        ushort4 ha, hb;
        ha.x = f2bf(a.x); ha.y = f2bf(a.y); ha.z = f2bf(a.z); ha.w = f2bf(a.w);
        hb.x = f2bf(b.x); hb.y = f2bf(b.y); hb.z = f2bf(b.z); hb.w = f2bf(b.w);
        *(ushort4*)&kb[(size_t)i * DIM + d0] = ha;
        *(ushort4*)&kb[(size_t)i * DIM + d0 + 4] = hb;
    }
}

// ---------------------------------------------------------------------------
// vT16[128][2048] = bf16(v[2048][128])^T. 32x32 tiles, grid (4, 64).
// ---------------------------------------------------------------------------
__global__ __launch_bounds__(256) void tcast_v(const float* __restrict__ v,
                                               unsigned short* __restrict__ vT) {
    __shared__ float tbuf[32][33];
    const int r0 = blockIdx.y * 32, c0 = blockIdx.x * 32;
    const int ty = threadIdx.x >> 3, tx = threadIdx.x & 7;
    float4 val = *(const float4*)&v[(size_t)(r0 + ty) * DIM + c0 + tx * 4];
    tbuf[ty][tx * 4 + 0] = val.x; tbuf[ty][tx * 4 + 1] = val.y;
    tbuf[ty][tx * 4 + 2] = val.z; tbuf[ty][tx * 4 + 3] = val.w;
    __syncthreads();
    ushort4 o;
    o.x = f2bf(tbuf[tx * 4 + 0][ty]);
    o.y = f2bf(tbuf[tx * 4 + 1][ty]);
    o.z = f2bf(tbuf[tx * 4 + 2][ty]);
    o.w = f2bf(tbuf[tx * 4 + 3][ty]);
    *(ushort4*)&vT[(size_t)(c0 + ty) * SEQ + r0 + tx * 4] = o;
}

// ---------------------------------------------------------------------------
// Compressed attention per token: writes comb (fp32, full init) + blk scores.
// ---------------------------------------------------------------------------
__global__ __launch_bounds__(256) void cmp_flash(const float* __restrict__ q,
                                                 const float* __restrict__ ck,
                                                 const float* __restrict__ cv,
                                                 const float* __restrict__ gl,
                                                 float* __restrict__ comb,
                                                 float* __restrict__ blk) {
    const int i = blockIdx.x, tid = threadIdx.x, wave = tid >> 6, lane = tid & 63;
    __shared__ float Qs[16][132];
    __shared__ float KV[64][132];
    __shared__ float ss[16][66];

    for (int t = tid; t < 512; t += 256) {
        int r = t >> 5, c4 = (t & 31) * 4;
        *(float4*)&Qs[r][c4] = *(const float4*)&q[(size_t)i * HIDDEN + r * DIM + c4];
    }
    for (int t = tid; t < 2048; t += 256) {
        int r = t >> 5, c4 = (t & 31) * 4;
        *(float4*)&KV[r][c4] = *(const float4*)&ck[(size_t)r * DIM + c4];
    }
    __syncthreads();

    const int hi = lane & 15, mg = lane >> 4;
    float s4[4] = {0.f, 0.f, 0.f, 0.f};
    for (int d = 0; d < 128; d += 4) {
        float4 qv = *(float4*)&Qs[hi][d];
        #pragma unroll
        for (int jj = 0; jj < 4; ++jj) {
            float4 kv = *(float4*)&KV[wave * 16 + mg * 4 + jj][d];
            s4[jj] = fmaf(qv.x, kv.x, fmaf(qv.y, kv.y, fmaf(qv.z, kv.z, fmaf(qv.w, kv.w, s4[jj]))));
        }
    }
    #pragma unroll
    for (int jj = 0; jj < 4; ++jj) {
        int m = wave * 16 + mg * 4 + jj;
        ss[hi][m] = (i >= m * 32 + 31) ? s4[jj] * SCALEF : NEGF;
    }
    __syncthreads();

    for (int hh = 0; hh < 4; ++hh) {
        int h = wave * 4 + hh;
        float val = ss[h][lane];
        float mx = val;
        for (int o = 32; o; o >>= 1) mx = fmaxf(mx, __shfl_xor(mx, o));
        float e = (val <= NEGF * 0.5f) ? 0.f : __expf(val - mx);
        float z = e;
        for (int o = 32; o; o >>= 1) z += __shfl_xor(z, o);
        ss[h][lane] = (z > 0.f) ? e * (1.0f / z) : 0.f;
    }
    __syncthreads();

    if (tid < 64) {
        float sb = 0.f;
        for (int h = 0; h < 16; ++h) sb += ss[h][tid];
        blk[(size_t)i * NCB + tid] = sb;
    }

    for (int t = tid; t < 2048; t += 256) {
        int r = t >> 5, c4 = (t & 31) * 4;
        *(float4*)&KV[r][c4] = *(const float4*)&cv[(size_t)r * DIM + c4];
    }
    __syncthreads();

    const int h2 = tid & 15, dg = tid >> 4;
    float o8[8] = {0.f,0.f,0.f,0.f,0.f,0.f,0.f,0.f};
    for (int kk = 0; kk < 64; ++kk) {
        float p = ss[h2][kk];
        float4 va = *(float4*)&KV[kk][dg * 8];
        float4 vb = *(float4*)&KV[kk][dg * 8 + 4];
        o8[0] = fmaf(p, va.x, o8[0]); o8[1] = fmaf(p, va.y, o8[1]);
        o8[2] = fmaf(p, va.z, o8[2]); o8[3] = fmaf(p, va.w, o8[3]);
        o8[4] = fmaf(p, vb.x, o8[4]); o8[5] = fmaf(p, vb.y, o8[5]);
        o8[6] = fmaf(p, vb.z, o8[6]); o8[7] = fmaf(p, vb.w, o8[7]);
    }
    float g0 = sigmoidf_(gl[(size_t)i * 48 + h2 * 3 + 0]);
    #pragma unroll
    for (int x = 0; x < 8; ++x)
        comb[(size_t)i * HIDDEN + h2 * DIM + dg * 8 + x] = g0 * o8[x];
}

// ---------------------------------------------------------------------------
// Top-k (exact jax.lax.top_k tie semantics).
// ---------------------------------------------------------------------------
__global__ __launch_bounds__(256) void topk2(const float* __restrict__ blk,
                                             int* __restrict__ oidx) {
    __shared__ float L[256][68];
    int base = blockIdx.x * 256;
    for (int t = threadIdx.x; t < 256 * 16; t += 256) {
        int r = t >> 4, c4 = (t & 15) * 4;
        *(float4*)&L[r][c4] = *(const float4*)&blk[(size_t)(base + r) * NCB + c4];
    }
    __syncthreads();
    int i = base + threadIdx.x;
    int tb = i >> 5;
    unsigned long long used = 0ull;
    for (int t = 0; t < NTOP; ++t) {
        float best = -3e38f; int bi = 0;
        for (int m = 0; m < NCB; ++m) {
            if ((used >> m) & 1ull) continue;
            float s = L[threadIdx.x][m];
            if (m > tb) s = NEGF;
            if (m == 0 || (m <= tb && m > tb - 2)) s = 1e30f;
            if (s > best) { best = s; bi = m; }
        }
        used |= 1ull << bi;
        oidx[i * NTOP + t] = bi;
    }
}

// ---------------------------------------------------------------------------
// Sparse top-k attention per token. comb += g1*out. (fp32 comb)
// ---------------------------------------------------------------------------
__global__ __launch_bounds__(256) void sparse_flash(const float* __restrict__ q,
                                                    const float* __restrict__ k,
                                                    const float* __restrict__ v,
                                                    const int* __restrict__ idx,
                                                    const float* __restrict__ gl,
                                                    float* __restrict__ comb) {
    const int i = blockIdx.x, tid = threadIdx.x, wave = tid >> 6, lane = tid & 63;
    __shared__ float Qs[16][132];
    __shared__ float KV[32][132];
    __shared__ float ss[16][266];
    __shared__ int sb[8];
    if (tid < 8) sb[tid] = idx[i * NTOP + tid];
    for (int t = tid; t < 512; t += 256) {
        int r = t >> 5, c4 = (t & 31) * 4;
        *(float4*)&Qs[r][c4] = *(const float4*)&q[(size_t)i * HIDDEN + r * DIM + c4];
    }
    __syncthreads();

    const int hi = lane & 15, kg = lane >> 4;
    for (int c = 0; c < 8; ++c) {
        int kb = sb[c] * 32;
        for (int t = tid; t < 1024; t += 256) {
            int r = t >> 5, c4 = (t & 31) * 4;
            *(float4*)&KV[r][c4] = *(const float4*)&k[(size_t)(kb + r) * DIM + c4];
        }
        __syncthreads();
        float s2[2] = {0.f, 0.f};
        for (int d = 0; d < 128; d += 4) {
            float4 qv = *(float4*)&Qs[hi][d];
            #pragma unroll
            for (int jj = 0; jj < 2; ++jj) {
                float4 kv = *(float4*)&KV[wave * 8 + kg * 2 + jj][d];
                s2[jj] = fmaf(qv.x, kv.x, fmaf(qv.y, kv.y, fmaf(qv.z, kv.z, fmaf(qv.w, kv.w, s2[jj]))));
            }
        }
        #pragma unroll
        for (int jj = 0; jj < 2; ++jj) {
            int kl = wave * 8 + kg * 2 + jj;
            int pos = kb + kl;
            ss[hi][c * 32 + kl] = (pos <= i) ? s2[jj] * SCALEF : NEGF;
        }
        __syncthreads();
    }

    for (int hh = 0; hh < 4; ++hh) {
        int h = wave * 4 + hh;
        float v0 = ss[h][lane], v1 = ss[h][64 + lane], v2 = ss[h][128 + lane], v3 = ss[h][192 + lane];
        float mx = fmaxf(fmaxf(v0, v1), fmaxf(v2, v3));
        for (int o = 32; o; o >>= 1) mx = fmaxf(mx, __shfl_xor(mx, o));
        float e0 = (v0 <= NEGF * 0.5f) ? 0.f : __expf(v0 - mx);
        float e1 = (v1 <= NEGF * 0.5f) ? 0.f : __expf(v1 - mx);
        float e2 = (v2 <= NEGF * 0.5f) ? 0.f : __expf(v2 - mx);
        float e3 = (v3 <= NEGF * 0.5f) ? 0.f : __expf(v3 - mx);
        float z = e0 + e1 + e2 + e3;
        for (int o = 32; o; o >>= 1) z += __shfl_xor(z, o);
        float rz = 1.0f / z;
        ss[h][lane] = e0 * rz; ss[h][64 + lane] = e1 * rz;
        ss[h][128 + lane] = e2 * rz; ss[h][192 + lane] = e3 * rz;
    }
    __syncthreads();

    const int h2 = tid & 15, dg = tid >> 4;
    float o8[8] = {0.f,0.f,0.f,0.f,0.f,0.f,0.f,0.f};
    for (int c = 0; c < 8; ++c) {
        int kb = sb[c] * 32;
        for (int t = tid; t < 1024; t += 256) {
            int r = t >> 5, c4 = (t & 31) * 4;
            *(float4*)&KV[r][c4] = *(const float4*)&v[(size_t)(kb + r) * DIM + c4];
        }
        __syncthreads();
        for (int kk = 0; kk < 32; ++kk) {
            float p = ss[h2][c * 32 + kk];
            float4 va = *(float4*)&KV[kk][dg * 8];
            float4 vb = *(float4*)&KV[kk][dg * 8 + 4];
            o8[0] = fmaf(p, va.x, o8[0]); o8[1] = fmaf(p, va.y, o8[1]);
            o8[2] = fmaf(p, va.z, o8[2]); o8[3] = fmaf(p, va.w, o8[3]);
            o8[4] = fmaf(p, vb.x, o8[4]); o8[5] = fmaf(p, vb.y, o8[5]);
            o8[6] = fmaf(p, vb.z, o8[6]); o8[7] = fmaf(p, vb.w, o8[7]);
        }
        __syncthreads();
    }
    float g1 = sigmoidf_(gl[(size_t)i * 48 + h2 * 3 + 1]);
    #pragma unroll
    for (int x = 0; x < 8; ++x)
        comb[(size_t)i * HIDDEN + h2 * DIM + dg * 8 + x] += g1 * o8[x];
}

// ---------------------------------------------------------------------------
// Sliding-window attention via MFMA (swapped QK^T), bf16 inputs.
// Block: 1 head x 64 queries, 4 waves (16 queries each). Chunks of 32 keys.
// qb pre-scaled by SCALE. vT is [128][2048] bf16 (V transposed).
// Lane (c = lane&15, g = lane>>4):
//   QK: C=S^T -> lane holds keys kf*16+g*4+r for query c (softmax state here)
//   PV: A=P (via per-wave LDS tile), B=V^T frag -> lane holds O[q=g*4+r][d=nf*16+c]
// ---------------------------------------------------------------------------
__global__ __launch_bounds__(256) void swin_mfma(const unsigned short* __restrict__ qb,
                                                 const unsigned short* __restrict__ kb,
                                                 const unsigned short* __restrict__ vT,
                                                 const float* __restrict__ gl,
                                                 float* __restrict__ comb) {
    const int h = blockIdx.x, qt = blockIdx.y;
    const int q0 = qt * 64;
    const int s0 = (q0 - WINSZ > 0) ? (q0 - WINSZ) : 0;
    const int nch = (q0 + 64 - s0) >> 5;
    const int tid = threadIdx.x, wave = tid >> 6, lane = tid & 63;
    const int c = lane & 15, g = lane >> 4;

    __shared__ unsigned short Qs[64 * 128];   // 16 KB, XOR-swizzled rows
    __shared__ unsigned short Ks[32 * 128];   // 8 KB, XOR-swizzled rows
    __shared__ unsigned short VtS[128 * 36];  // 9 KB, row pad 36 (18-word stride)
    __shared__ float Ps[4][32][17];           // 8.5 KB per-wave P tiles

    // stage Q (64 rows x 128 bf16), swizzle d0 ^ ((row&7)<<3)
    {
        int r = tid >> 2;
        int base = (tid & 3) * 32;
        #pragma unroll
        for (int s = 0; s < 4; ++s) {
            int d0 = base + s * 8;
            short8 v = *(const short8*)&qb[(size_t)(q0 + r) * HIDDEN + h * DIM + d0];
            *(short8*)&Qs[r * 128 + (d0 ^ ((r & 7) << 3))] = v;
        }
    }
    __syncthreads();

    // hoist Q B-fragments (col = query c of this wave)
    short8 Qf[4];
    {
        int qrow = wave * 16 + c;
        #pragma unroll
        for (int kc = 0; kc < 4; ++kc) {
            int d0 = kc * 32 + g * 8;
            Qf[kc] = *(short8*)&Qs[qrow * 128 + (d0 ^ ((qrow & 7) << 3))];
        }
    }

    const int gq = q0 + wave * 16 + c;     // query whose softmax state this lane keeps
    float m = -3e38f, l = 0.f;
    f32x4 accO[8];
    #pragma unroll
    for (int nf = 0; nf < 8; ++nf) accO[nf] = (f32x4){0.f, 0.f, 0.f, 0.f};

    for (int ch = 0; ch < nch; ++ch) {
        int kbase = s0 + ch * 32;
        // stage K (swizzled) and V^T slab
        {
            int r = tid >> 3;
            int d0 = (tid & 7) * 16;
            #pragma unroll
            for (int s = 0; s < 2; ++s) {
                int dd = d0 + s * 8;
                short8 v = *(const short8*)&kb[(size_t)(kbase + r) * DIM + dd];
                *(short8*)&Ks[r * 128 + (dd ^ ((r & 7) << 3))] = v;
            }
            int d = tid >> 1;
            int k0 = (tid & 1) * 16;
            short8 v0 = *(const short8*)&vT[(size_t)d * SEQ + kbase + k0];
            short8 v1 = *(const short8*)&vT[(size_t)d * SEQ + kbase + k0 + 8];
            *(short8*)&VtS[d * 36 + k0] = v0;
            *(short8*)&VtS[d * 36 + k0 + 8] = v1;
        }
        __syncthreads();

        // QK^T swapped: accS[kf] = S^T tile (keys kf*16.., queries of wave)
        f32x4 accS[2];
        accS[0] = (f32x4){0.f, 0.f, 0.f, 0.f};
        accS[1] = (f32x4){0.f, 0.f, 0.f, 0.f};
        #pragma unroll
        for (int kf = 0; kf < 2; ++kf) {
            int krow = kf * 16 + c;
            #pragma unroll
            for (int kc = 0; kc < 4; ++kc) {
                int d0 = kc * 32 + g * 8;
                short8 Kf = *(short8*)&Ks[krow * 128 + (d0 ^ ((krow & 7) << 3))];
                accS[kf] = __builtin_amdgcn_mfma_f32_16x16x32_bf16(Kf, Qf[kc], accS[kf], 0, 0, 0);
            }
        }

        // masked scores; per-lane keys kf*16+g*4+r for query c
        float s8[8];
        float mx = -3e38f;
        #pragma unroll
        for (int kf = 0; kf < 2; ++kf)
            #pragma unroll
            for (int r = 0; r < 4; ++r) {
                int pos = kbase + kf * 16 + g * 4 + r;
                bool ok = (pos <= gq) && (pos >= gq - WINSZ);
                float sv = ok ? accS[kf][r] : -3e38f;
                s8[kf * 4 + r] = sv;
                mx = fmaxf(mx, sv);
            }
        mx = fmaxf(mx, __shfl_xor(mx, 16));
        mx = fmaxf(mx, __shfl_xor(mx, 32));
        float mnew = fmaxf(m, mx);
        float corr = __expf(m - mnew);
        float psum = 0.f;
        float p8[8];
        #pragma unroll
        for (int j = 0; j < 8; ++j) {
            float p = (s8[j] <= -1e37f) ? 0.f : __expf(s8[j] - mnew);
            p8[j] = p;
            psum += p;
        }
        psum += __shfl_xor(psum, 16);
        psum += __shfl_xor(psum, 32);
        l = l * corr + psum;
        m = mnew;

        // P -> per-wave LDS tile [key][query]
        #pragma unroll
        for (int kf = 0; kf < 2; ++kf)
            #pragma unroll
            for (int r = 0; r < 4; ++r)
                Ps[wave][kf * 16 + g * 4 + r][c] = p8[kf * 4 + r];

        // rescale accO (its query index is g*4+r, corr lives at lane=query)
        #pragma unroll
        for (int r = 0; r < 4; ++r) {
            float cr = __shfl(corr, g * 4 + r);
            #pragma unroll
            for (int nf = 0; nf < 8; ++nf)
                accO[nf][r] *= cr;
        }

        // read P back as A-fragment: keys g*8+j for query c (per-wave tile)
        short8 paf;
        #pragma unroll
        for (int j = 0; j < 8; ++j)
            paf[j] = (short)f2bf(Ps[wave][g * 8 + j][c]);

        // PV: accO[nf] += P * V  (B-frag from V^T rows, 18-word stride)
        #pragma unroll
        for (int nf = 0; nf < 8; ++nf) {
            short8 vf = *(short8*)&VtS[(nf * 16 + c) * 36 + g * 8];
            accO[nf] = __builtin_amdgcn_mfma_f32_16x16x32_bf16(paf, vf, accO[nf], 0, 0, 0);
        }
        __syncthreads();   // staging of next chunk overwrites Ks/VtS
    }

    // epilogue: O[query g*4+r][dim nf*16+c] * g2 / l
    #pragma unroll
    for (int r = 0; r < 4; ++r) {
        float lq = __shfl(l, g * 4 + r);
        int token = q0 + wave * 16 + g * 4 + r;
        float g2 = sigmoidf_(gl[(size_t)token * 48 + h * 3 + 2]);
        float sc = g2 / lq;
        #pragma unroll
        for (int nf = 0; nf < 8; ++nf)
            comb[(size_t)token * HIDDEN + h * DIM + nf * 16 + c] += accO[nf][r] * sc;
    }
}

// ---------------------------------------------------------------------------
extern "C" void kernel_launch(void* const* d_in, const int* in_sizes, int n_in,
                              void* d_out, int out_size, void* d_ws, size_t ws_size,
                              hipStream_t stream) {
    const float* x  = (const float*)d_in[0];
    const float* Wq = (const float*)d_in[2];
    const float* Wk = (const float*)d_in[3];
    const float* Wv = (const float*)d_in[4];
    const float* Wo = (const float*)d_in[5];
    const float* Wg = (const float*)d_in[6];
    const float* pe = (const float*)d_in[7];
    float* out = (float*)d_out;

    // workspace layout (36.7 MB, proven footprint)
    char* w = (char*)d_ws;
    float* q    = (float*)(w);               // 16 MB  (early: kvg scratch; late: comb hi/lo)
    float* comb = (float*)(w + 16777216);    // 16 MB  (early: x hi/lo; late: Wo hi/lo)
    float* kbuf = (float*)(w + 33554432);    // 1 MB
    float* vbuf = (float*)(w + 34603008);    // 1 MB
    float* gl   = (float*)(w + 35651584);    // 384 KB
    float* ck   = (float*)(w + 36044800);    // 32 KB
    float* cv   = (float*)(w + 36077568);    // 32 KB
    float* blk  = (float*)(w + 36110336);    // 512 KB
    int*   idx  = (int*)  (w + 36634624);    // 64 KB

    // scratch aliases
    unsigned short* Xh   = (unsigned short*)comb;            // x hi/lo (comb region)
    unsigned short* Xl   = Xh + 4194304;
    unsigned short* Wqh  = (unsigned short*)out;             // d_out dead until final
    unsigned short* Wql  = Wqh + 4194304;
    unsigned short* Ch   = (unsigned short*)q;               // q dead after attn
    unsigned short* Cl   = Ch + 4194304;
    unsigned short* Woh  = (unsigned short*)comb;            // comb dead after split
    unsigned short* Wol  = Woh + 4194304;
    float*          kvgOut = q;                              // q region (3 MB)
    unsigned short* kvgBth = (unsigned short*)(w + 4194304); // q region +4 MB
    unsigned short* kvgBtl = kvgBth + 786432;
    // bf16 attention inputs (d_out region, after q-proj consumes Wqh/Wql)
    unsigned short* qb16 = (unsigned short*)out;             // 8 MB
    unsigned short* kb16 = qb16 + 4194304;                   // 0.5 MB
    unsigned short* vT16 = kb16 + 262144;                    // 0.5 MB

    // 1. split x
    split_pair<<<4096, 256, 0, stream>>>(x, Xh, Xl);

    // 2. combined k/v/gate projection
    tsplit_g<<<dim3(4, 64), 256, 0, stream>>>(Wk, kvgBth, kvgBtl, 128, 0);
    tsplit_g<<<dim3(4, 64), 256, 0, stream>>>(Wv, kvgBth, kvgBtl, 128, 128);
    tsplit_g<<<dim3(2, 64), 256, 0, stream>>>(Wg, kvgBth, kvgBtl, 48,  256);
    gemm3s<<<dim3(3, 16), 256, 0, stream>>>(Xh, Xl, kvgBth, kvgBtl, kvgOut,
                                            SEQ, KVGN, HIDDEN);
    unpack_kvg<<<SEQ, 256, 0, stream>>>(kvgOut, kbuf, vbuf, gl);

    // 3. q projection
    tsplit<<<dim3(64, 64), 256, 0, stream>>>(Wq, Wqh, Wql);
    gemm3s<<<dim3(16, 16), 256, 0, stream>>>(Xh, Xl, Wqh, Wql, q, SEQ, HIDDEN, HIDDEN);

    // 4. compress (un-roped k) then rope q,k
    compress_kernel<<<NCB, DIM, 0, stream>>>(kbuf, vbuf, pe, ck, cv);
    rope_qk<<<SEQ, 64, 0, stream>>>(q, kbuf);

    // 5. bf16 prep for MFMA attention (d_out region now free)
    prep_cast<<<SEQ, 256, 0, stream>>>(q, kbuf, qb16, kb16);
    tcast_v<<<dim3(4, 64), 256, 0, stream>>>(vbuf, vT16);

    // 6. compressed attention -> comb fp32 (full init) + blk
    cmp_flash<<<SEQ, 256, 0, stream>>>(q, ck, cv, gl, comb, blk);

    // 7. top-k
    topk2<<<SEQ / 256, 256, 0, stream>>>(blk, idx);

    // 8. sparse attention (comb += g1*out)
    sparse_flash<<<SEQ, 256, 0, stream>>>(q, kbuf, vbuf, idx, gl, comb);

    // 9. sliding-window attention via MFMA (comb += g2*out)
    swin_mfma<<<dim3(16, 32), 256, 0, stream>>>(qb16, kb16, vT16, gl, comb);

    // 10. output projection
    split_pair<<<4096, 256, 0, stream>>>(comb, Ch, Cl);
    tsplit<<<dim3(64, 64), 256, 0, stream>>>(Wo, Woh, Wol);
    gemm3s<<<dim3(16, 16), 256, 0, stream>>>(Ch, Cl, Woh, Wol, out, SEQ, HIDDEN, HIDDEN);
}

// Round 7
// 652.756 us; speedup vs baseline: 5.9046x; 1.1493x over previous
//
#include <hip/hip_runtime.h>
#include <hip/hip_bf16.h>

constexpr int SEQ    = 2048;
constexpr int HIDDEN = 2048;
constexpr int NHQ    = 16;
constexpr int DIM    = 128;
constexpr int NCB    = 64;
constexpr int NTOP   = 8;
constexpr int WINSZ  = 512;
constexpr int KVGN   = 384;

#define SCALEF 0.08838834764831845f
#define NEGF  -1e30f

using short8 = __attribute__((ext_vector_type(8))) short;
using f32x4  = __attribute__((ext_vector_type(4))) float;

__device__ inline unsigned short f2bf(float f) {
    unsigned u = __float_as_uint(f);
    unsigned r = (u + 0x7fffu + ((u >> 16) & 1u)) >> 16;
    return (unsigned short)r;
}
__device__ inline float bf2f(unsigned short b) {
    return __uint_as_float(((unsigned)b) << 16);
}
__device__ inline float sigmoidf_(float x) { return 1.0f / (1.0f + __expf(-x)); }

// ---------------------------------------------------------------------------
// split fp32 -> (hi, lo) bf16 pair, elementwise.
// ---------------------------------------------------------------------------
__global__ __launch_bounds__(256) void split_pair(const float* __restrict__ in,
                                                  unsigned short* __restrict__ hi,
                                                  unsigned short* __restrict__ lo) {
    int i = (blockIdx.x * 256 + threadIdx.x) * 4;
    float4 v = *(const float4*)&in[i];
    ushort4 h, l;
    h.x = f2bf(v.x); l.x = f2bf(v.x - bf2f(h.x));
    h.y = f2bf(v.y); l.y = f2bf(v.y - bf2f(h.y));
    h.z = f2bf(v.z); l.z = f2bf(v.z - bf2f(h.z));
    h.w = f2bf(v.w); l.w = f2bf(v.w - bf2f(h.w));
    *(ushort4*)&hi[i] = h;
    *(ushort4*)&lo[i] = l;
}

// ---------------------------------------------------------------------------
// transpose + split: W[2048][2048] fp32 -> Th/Tl[N][K] bf16. 32x32 tiles.
// ---------------------------------------------------------------------------
__global__ __launch_bounds__(256) void tsplit(const float* __restrict__ W,
                                              unsigned short* __restrict__ Th,
                                              unsigned short* __restrict__ Tl) {
    __shared__ float t[32][33];
    const int k0 = blockIdx.y * 32, n0 = blockIdx.x * 32;
    const int ty = threadIdx.x >> 3, tx = threadIdx.x & 7;
    float4 v = *(const float4*)&W[(size_t)(k0 + ty) * HIDDEN + n0 + tx * 4];
    t[ty][tx * 4 + 0] = v.x; t[ty][tx * 4 + 1] = v.y;
    t[ty][tx * 4 + 2] = v.z; t[ty][tx * 4 + 3] = v.w;
    __syncthreads();
    ushort4 h, l;
    float a0 = t[tx * 4 + 0][ty], a1 = t[tx * 4 + 1][ty];
    float a2 = t[tx * 4 + 2][ty], a3 = t[tx * 4 + 3][ty];
    h.x = f2bf(a0); l.x = f2bf(a0 - bf2f(h.x));
    h.y = f2bf(a1); l.y = f2bf(a1 - bf2f(h.y));
    h.z = f2bf(a2); l.z = f2bf(a2 - bf2f(h.z));
    h.w = f2bf(a3); l.w = f2bf(a3 - bf2f(h.w));
    *(ushort4*)&Th[(size_t)(n0 + ty) * HIDDEN + k0 + tx * 4] = h;
    *(ushort4*)&Tl[(size_t)(n0 + ty) * HIDDEN + k0 + tx * 4] = l;
}

// ---------------------------------------------------------------------------
// Generic guarded transpose+split: W[2048][Nd] -> rows [rowOff+n][k].
// ---------------------------------------------------------------------------
__global__ __launch_bounds__(256) void tsplit_g(const float* __restrict__ W,
                                                unsigned short* __restrict__ Th,
                                                unsigned short* __restrict__ Tl,
                                                int Nd, int rowOff) {
    __shared__ float t[32][33];
    const int k0 = blockIdx.y * 32, n0 = blockIdx.x * 32;
    const int ty = threadIdx.x >> 3, tx = threadIdx.x & 7;
    #pragma unroll
    for (int j = 0; j < 4; ++j) {
        int c = n0 + tx * 4 + j;
        t[ty][tx * 4 + j] = (c < Nd) ? W[(size_t)(k0 + ty) * Nd + c] : 0.f;
    }
    __syncthreads();
    ushort4 h, l;
    float a0 = t[tx * 4 + 0][ty], a1 = t[tx * 4 + 1][ty];
    float a2 = t[tx * 4 + 2][ty], a3 = t[tx * 4 + 3][ty];
    h.x = f2bf(a0); l.x = f2bf(a0 - bf2f(h.x));
    h.y = f2bf(a1); l.y = f2bf(a1 - bf2f(h.y));
    h.z = f2bf(a2); l.z = f2bf(a2 - bf2f(h.z));
    h.w = f2bf(a3); l.w = f2bf(a3 - bf2f(h.w));
    *(ushort4*)&Th[(size_t)(rowOff + n0 + ty) * HIDDEN + k0 + tx * 4] = h;
    *(ushort4*)&Tl[(size_t)(rowOff + n0 + ty) * HIDDEN + k0 + tx * 4] = l;
}

// ---------------------------------------------------------------------------
// unpack kvg[2048][384] -> k, v, gl
// ---------------------------------------------------------------------------
__global__ __launch_bounds__(256) void unpack_kvg(const float* __restrict__ kvg,
                                                  float* __restrict__ k,
                                                  float* __restrict__ v,
                                                  float* __restrict__ g) {
    int i = blockIdx.x, t = threadIdx.x;
    if (t < 128) {
        k[(size_t)i * DIM + t] = kvg[(size_t)i * KVGN + t];
        v[(size_t)i * DIM + t] = kvg[(size_t)i * KVGN + 128 + t];
    } else if (t < 176) {
        g[(size_t)i * 48 + (t - 128)] = kvg[(size_t)i * KVGN + 256 + (t - 128)];
    }
}

// ---------------------------------------------------------------------------
// Split-bf16 MFMA GEMM (fp32-grade), 128x128 tile, BK=32, 3 MFMA/frag pair.
// ---------------------------------------------------------------------------
__global__ __launch_bounds__(256) void gemm3s(const unsigned short* __restrict__ Ah,
                                              const unsigned short* __restrict__ Al,
                                              const unsigned short* __restrict__ Bh,
                                              const unsigned short* __restrict__ Bl,
                                              float* __restrict__ C,
                                              int M, int N, int K) {
    __shared__ unsigned short sAh[4][128][8], sAl[4][128][8];
    __shared__ unsigned short sBh[4][128][8], sBl[4][128][8];
    const int tid = threadIdx.x, lane = tid & 63, wave = tid >> 6;
    const int wr = wave >> 1, wc = wave & 1;
    const int brow = blockIdx.y * 128, bcol = blockIdx.x * 128;
    const int lr = lane & 15, lc = lane >> 4;
    const int sr = tid & 127, sc0 = tid >> 7;

    f32x4 acc[4][4];
    #pragma unroll
    for (int a = 0; a < 4; ++a)
        #pragma unroll
        for (int b = 0; b < 4; ++b) acc[a][b] = (f32x4){0.f, 0.f, 0.f, 0.f};

    for (int k0 = 0; k0 < K; k0 += 32) {
        #pragma unroll
        for (int i = 0; i < 2; ++i) {
            int c = i * 2 + sc0;
            size_t ao = (size_t)(brow + sr) * K + k0 + c * 8;
            size_t bo = (size_t)(bcol + sr) * K + k0 + c * 8;
            *(short8*)&sAh[c][sr][0] = *(const short8*)&Ah[ao];
            *(short8*)&sAl[c][sr][0] = *(const short8*)&Al[ao];
            *(short8*)&sBh[c][sr][0] = *(const short8*)&Bh[bo];
            *(short8*)&sBl[c][sr][0] = *(const short8*)&Bl[bo];
        }
        __syncthreads();
        short8 fah[4], fal[4], fbh[4], fbl[4];
        #pragma unroll
        for (int mi = 0; mi < 4; ++mi) {
            fah[mi] = *(short8*)&sAh[lc][wr * 64 + mi * 16 + lr][0];
            fal[mi] = *(short8*)&sAl[lc][wr * 64 + mi * 16 + lr][0];
        }
        #pragma unroll
        for (int ni = 0; ni < 4; ++ni) {
            fbh[ni] = *(short8*)&sBh[lc][wc * 64 + ni * 16 + lr][0];
            fbl[ni] = *(short8*)&sBl[lc][wc * 64 + ni * 16 + lr][0];
        }
        #pragma unroll
        for (int mi = 0; mi < 4; ++mi)
            #pragma unroll
            for (int ni = 0; ni < 4; ++ni) {
                acc[mi][ni] = __builtin_amdgcn_mfma_f32_16x16x32_bf16(fah[mi], fbh[ni], acc[mi][ni], 0, 0, 0);
                acc[mi][ni] = __builtin_amdgcn_mfma_f32_16x16x32_bf16(fal[mi], fbh[ni], acc[mi][ni], 0, 0, 0);
                acc[mi][ni] = __builtin_amdgcn_mfma_f32_16x16x32_bf16(fah[mi], fbl[ni], acc[mi][ni], 0, 0, 0);
            }
        __syncthreads();
    }
    #pragma unroll
    for (int mi = 0; mi < 4; ++mi)
        #pragma unroll
        for (int ni = 0; ni < 4; ++ni) {
            int col  = bcol + wc * 64 + ni * 16 + lr;
            int rowb = brow + wr * 64 + mi * 16 + lc * 4;
            #pragma unroll
            for (int r = 0; r < 4; ++r)
                C[(size_t)(rowb + r) * N + col] = acc[mi][ni][r];
        }
}

// ---------------------------------------------------------------------------
// Compress: ck[m]=rope(mean(k+pe), pos=32m), cv[m]=mean(v). Un-roped k input.
// ---------------------------------------------------------------------------
__global__ void compress_kernel(const float* __restrict__ k,
                                const float* __restrict__ v,
                                const float* __restrict__ pe,
                                float* __restrict__ ck,
                                float* __restrict__ cv) {
    int m = blockIdx.x, d = threadIdx.x;
    float sk = 0.f, sv = 0.f, sp = 0.f;
    for (int s = 0; s < 32; ++s) {
        sk += k[(size_t)(m * 32 + s) * DIM + d];
        sv += v[(size_t)(m * 32 + s) * DIM + d];
        sp += pe[s * DIM + d];
    }
    float ckv = (sk + sp) * (1.0f / 32.0f);
    cv[m * DIM + d] = sv * (1.0f / 32.0f);
    __shared__ float tmp[DIM];
    tmp[d] = ckv;
    __syncthreads();
    int j = d & 63;
    float inv = powf(10000.0f, -(float)(2 * j) / 128.0f);
    float ang = (float)(m * 32) * inv;
    float c = cosf(ang), s = sinf(ang);
    float x1 = tmp[j], x2 = tmp[j + 64];
    ck[m * DIM + d] = (d < 64) ? (x1 * c - x2 * s) : (x2 * c + x1 * s);
}

__global__ void rope_qk(float* __restrict__ q, float* __restrict__ k) {
    int i = blockIdx.x, j = threadIdx.x;
    float inv = powf(10000.0f, -(float)(2 * j) / 128.0f);
    float ang = (float)i * inv;
    float c = cosf(ang), s = sinf(ang);
    for (int h = 0; h < NHQ; ++h) {
        float* p = q + ((size_t)i * NHQ + h) * DIM;
        float x1 = p[j], x2 = p[j + 64];
        p[j]      = x1 * c - x2 * s;
        p[j + 64] = x2 * c + x1 * s;
    }
    float* p = k + (size_t)i * DIM;
    float x1 = p[j], x2 = p[j + 64];
    p[j]      = x1 * c - x2 * s;
    p[j + 64] = x2 * c + x1 * s;
}

// ---------------------------------------------------------------------------
// prep: qb16 = bf16(q * SCALE) [2048][2048]; kb16 = bf16(k) [2048][128]
// ---------------------------------------------------------------------------
__global__ __launch_bounds__(256) void prep_cast(const float* __restrict__ q,
                                                 const float* __restrict__ k,
                                                 unsigned short* __restrict__ qb,
                                                 unsigned short* __restrict__ kb) {
    int i = blockIdx.x, t = threadIdx.x;
    {
        int d0 = t * 8;
        float4 a = *(const float4*)&q[(size_t)i * HIDDEN + d0];
        float4 b = *(const float4*)&q[(size_t)i * HIDDEN + d0 + 4];
        ushort4 ha, hb;
        ha.x = f2bf(a.x * SCALEF); ha.y = f2bf(a.y * SCALEF);
        ha.z = f2bf(a.z * SCALEF); ha.w = f2bf(a.w * SCALEF);
        hb.x = f2bf(b.x * SCALEF); hb.y = f2bf(b.y * SCALEF);
        hb.z = f2bf(b.z * SCALEF); hb.w = f2bf(b.w * SCALEF);
        *(ushort4*)&qb[(size_t)i * HIDDEN + d0] = ha;
        *(ushort4*)&qb[(size_t)i * HIDDEN + d0 + 4] = hb;
    }
    if (t < 16) {
        int d0 = t * 8;
        float4 a = *(const float4*)&k[(size_t)i * DIM + d0];
        float4 b = *(const float4*)&k[(size_t)i * DIM + d0 + 4];
        ushort4 ha, hb;
        ha.x = f2bf(a.x); ha.y = f2bf(a.y); ha.z = f2bf(a.z); ha.w = f2bf(a.w);
        hb.x = f2bf(b.x); hb.y = f2bf(b.y); hb.z = f2bf(b.z); hb.w = f2bf(b.w);
        *(ushort4*)&kb[(size_t)i * DIM + d0] = ha;
        *(ushort4*)&kb[(size_t)i * DIM + d0 + 4] = hb;
    }
}

// ---------------------------------------------------------------------------
// vT16[128][2048] = bf16(v[2048][128])^T. 32x32 tiles, grid (4, 64).
// ---------------------------------------------------------------------------
__global__ __launch_bounds__(256) void tcast_v(const float* __restrict__ v,
                                               unsigned short* __restrict__ vT) {
    __shared__ float tbuf[32][33];
    const int r0 = blockIdx.y * 32, c0 = blockIdx.x * 32;
    const int ty = threadIdx.x >> 3, tx = threadIdx.x & 7;
    float4 val = *(const float4*)&v[(size_t)(r0 + ty) * DIM + c0 + tx * 4];
    tbuf[ty][tx * 4 + 0] = val.x; tbuf[ty][tx * 4 + 1] = val.y;
    tbuf[ty][tx * 4 + 2] = val.z; tbuf[ty][tx * 4 + 3] = val.w;
    __syncthreads();
    ushort4 o;
    o.x = f2bf(tbuf[tx * 4 + 0][ty]);
    o.y = f2bf(tbuf[tx * 4 + 1][ty]);
    o.z = f2bf(tbuf[tx * 4 + 2][ty]);
    o.w = f2bf(tbuf[tx * 4 + 3][ty]);
    *(ushort4*)&vT[(size_t)(c0 + ty) * SEQ + r0 + tx * 4] = o;
}

// ---------------------------------------------------------------------------
// Compressed attention per token: writes comb (fp32, full init) + blk scores.
// ---------------------------------------------------------------------------
__global__ __launch_bounds__(256) void cmp_flash(const float* __restrict__ q,
                                                 const float* __restrict__ ck,
                                                 const float* __restrict__ cv,
                                                 const float* __restrict__ gl,
                                                 float* __restrict__ comb,
                                                 float* __restrict__ blk) {
    const int i = blockIdx.x, tid = threadIdx.x, wave = tid >> 6, lane = tid & 63;
    __shared__ float Qs[16][132];
    __shared__ float KV[64][132];
    __shared__ float ss[16][66];

    for (int t = tid; t < 512; t += 256) {
        int r = t >> 5, c4 = (t & 31) * 4;
        *(float4*)&Qs[r][c4] = *(const float4*)&q[(size_t)i * HIDDEN + r * DIM + c4];
    }
    for (int t = tid; t < 2048; t += 256) {
        int r = t >> 5, c4 = (t & 31) * 4;
        *(float4*)&KV[r][c4] = *(const float4*)&ck[(size_t)r * DIM + c4];
    }
    __syncthreads();

    const int hi = lane & 15, mg = lane >> 4;
    float s4[4] = {0.f, 0.f, 0.f, 0.f};
    for (int d = 0; d < 128; d += 4) {
        float4 qv = *(float4*)&Qs[hi][d];
        #pragma unroll
        for (int jj = 0; jj < 4; ++jj) {
            float4 kv = *(float4*)&KV[wave * 16 + mg * 4 + jj][d];
            s4[jj] = fmaf(qv.x, kv.x, fmaf(qv.y, kv.y, fmaf(qv.z, kv.z, fmaf(qv.w, kv.w, s4[jj]))));
        }
    }
    #pragma unroll
    for (int jj = 0; jj < 4; ++jj) {
        int m = wave * 16 + mg * 4 + jj;
        ss[hi][m] = (i >= m * 32 + 31) ? s4[jj] * SCALEF : NEGF;
    }
    __syncthreads();

    for (int hh = 0; hh < 4; ++hh) {
        int h = wave * 4 + hh;
        float val = ss[h][lane];
        float mx = val;
        for (int o = 32; o; o >>= 1) mx = fmaxf(mx, __shfl_xor(mx, o));
        float e = (val <= NEGF * 0.5f) ? 0.f : __expf(val - mx);
        float z = e;
        for (int o = 32; o; o >>= 1) z += __shfl_xor(z, o);
        ss[h][lane] = (z > 0.f) ? e * (1.0f / z) : 0.f;
    }
    __syncthreads();

    if (tid < 64) {
        float sb = 0.f;
        for (int h = 0; h < 16; ++h) sb += ss[h][tid];
        blk[(size_t)i * NCB + tid] = sb;
    }

    for (int t = tid; t < 2048; t += 256) {
        int r = t >> 5, c4 = (t & 31) * 4;
        *(float4*)&KV[r][c4] = *(const float4*)&cv[(size_t)r * DIM + c4];
    }
    __syncthreads();

    const int h2 = tid & 15, dg = tid >> 4;
    float o8[8] = {0.f,0.f,0.f,0.f,0.f,0.f,0.f,0.f};
    for (int kk = 0; kk < 64; ++kk) {
        float p = ss[h2][kk];
        float4 va = *(float4*)&KV[kk][dg * 8];
        float4 vb = *(float4*)&KV[kk][dg * 8 + 4];
        o8[0] = fmaf(p, va.x, o8[0]); o8[1] = fmaf(p, va.y, o8[1]);
        o8[2] = fmaf(p, va.z, o8[2]); o8[3] = fmaf(p, va.w, o8[3]);
        o8[4] = fmaf(p, vb.x, o8[4]); o8[5] = fmaf(p, vb.y, o8[5]);
        o8[6] = fmaf(p, vb.z, o8[6]); o8[7] = fmaf(p, vb.w, o8[7]);
    }
    float g0 = sigmoidf_(gl[(size_t)i * 48 + h2 * 3 + 0]);
    #pragma unroll
    for (int x = 0; x < 8; ++x)
        comb[(size_t)i * HIDDEN + h2 * DIM + dg * 8 + x] = g0 * o8[x];
}

// ---------------------------------------------------------------------------
// Top-k (exact jax.lax.top_k tie semantics).
// ---------------------------------------------------------------------------
__global__ __launch_bounds__(256) void topk2(const float* __restrict__ blk,
                                             int* __restrict__ oidx) {
    __shared__ float L[256][68];
    int base = blockIdx.x * 256;
    for (int t = threadIdx.x; t < 256 * 16; t += 256) {
        int r = t >> 4, c4 = (t & 15) * 4;
        *(float4*)&L[r][c4] = *(const float4*)&blk[(size_t)(base + r) * NCB + c4];
    }
    __syncthreads();
    int i = base + threadIdx.x;
    int tb = i >> 5;
    unsigned long long used = 0ull;
    for (int t = 0; t < NTOP; ++t) {
        float best = -3e38f; int bi = 0;
        for (int m = 0; m < NCB; ++m) {
            if ((used >> m) & 1ull) continue;
            float s = L[threadIdx.x][m];
            if (m > tb) s = NEGF;
            if (m == 0 || (m <= tb && m > tb - 2)) s = 1e30f;
            if (s > best) { best = s; bi = m; }
        }
        used |= 1ull << bi;
        oidx[i * NTOP + t] = bi;
    }
}

// ---------------------------------------------------------------------------
// Sparse top-k attention via MFMA (swapped QK^T), bf16 inputs, per-token block.
// 4 waves; all waves duplicate QK^T for each 32-key chunk (8 MFMAs); PV is
// split across waves by output dims (wave w owns dims w*32..w*32+31).
// Lane (c = lane&15, g = lane>>4):
//   QK: accS = S^T -> lane holds keys kf*16+g*4+r for head c (softmax state)
//   PV: A = P[head][key] (per-wave LDS tile), B = V^T rows -> O[head g*4+r][dim]
// ---------------------------------------------------------------------------
__global__ __launch_bounds__(256) void sparse_mfma(const unsigned short* __restrict__ qb,
                                                   const unsigned short* __restrict__ kb,
                                                   const unsigned short* __restrict__ vT,
                                                   const int* __restrict__ idx,
                                                   const float* __restrict__ gl,
                                                   float* __restrict__ comb) {
    const int i = blockIdx.x;
    const int tid = threadIdx.x, wave = tid >> 6, lane = tid & 63;
    const int c = lane & 15, g = lane >> 4;

    __shared__ unsigned short Qs[16 * 128];   // 4 KB, XOR-swizzled rows
    __shared__ unsigned short Ks[32 * 128];   // 8 KB, XOR-swizzled rows
    __shared__ unsigned short VtS[128 * 36];  // 9 KB, 36-short row stride
    __shared__ float Ps[4][32][17];           // 8.5 KB per-wave P tiles
    __shared__ int sb[8];

    if (tid < 8) sb[tid] = idx[i * NTOP + tid];
    // stage Q (16 heads x 128), swizzle d0 ^ ((row&7)<<3); qb pre-scaled
    {
        int r = tid >> 4, d0 = (tid & 15) * 8;
        short8 v = *(const short8*)&qb[(size_t)i * HIDDEN + r * DIM + d0];
        *(short8*)&Qs[r * 128 + (d0 ^ ((r & 7) << 3))] = v;
    }
    __syncthreads();

    // hoist Q B-fragments (row = head c)
    short8 Qf[4];
    #pragma unroll
    for (int kc = 0; kc < 4; ++kc) {
        int d0 = kc * 32 + g * 8;
        Qf[kc] = *(short8*)&Qs[c * 128 + (d0 ^ ((c & 7) << 3))];
    }

    float m = -3e38f, l = 0.f;
    f32x4 accO[2];                    // wave dims: wave*32 + nf*16 + c
    accO[0] = (f32x4){0.f, 0.f, 0.f, 0.f};
    accO[1] = (f32x4){0.f, 0.f, 0.f, 0.f};

    for (int ch = 0; ch < 8; ++ch) {
        int kbase = sb[ch] * 32;
        // stage K chunk (swizzled) + V^T slab
        {
            int r = tid >> 3;
            int d0 = (tid & 7) * 16;
            #pragma unroll
            for (int s = 0; s < 2; ++s) {
                int dd = d0 + s * 8;
                short8 v = *(const short8*)&kb[(size_t)(kbase + r) * DIM + dd];
                *(short8*)&Ks[r * 128 + (dd ^ ((r & 7) << 3))] = v;
            }
            int d = tid >> 1;
            int k0 = (tid & 1) * 16;
            short8 v0 = *(const short8*)&vT[(size_t)d * SEQ + kbase + k0];
            short8 v1 = *(const short8*)&vT[(size_t)d * SEQ + kbase + k0 + 8];
            *(short8*)&VtS[d * 36 + k0] = v0;
            *(short8*)&VtS[d * 36 + k0 + 8] = v1;
        }
        __syncthreads();

        // swapped QK^T: accS[kf] = S^T tile (duplicated across waves)
        f32x4 accS[2];
        accS[0] = (f32x4){0.f, 0.f, 0.f, 0.f};
        accS[1] = (f32x4){0.f, 0.f, 0.f, 0.f};
        #pragma unroll
        for (int kf = 0; kf < 2; ++kf) {
            int krow = kf * 16 + c;
            #pragma unroll
            for (int kc = 0; kc < 4; ++kc) {
                int d0 = kc * 32 + g * 8;
                short8 Kf = *(short8*)&Ks[krow * 128 + (d0 ^ ((krow & 7) << 3))];
                accS[kf] = __builtin_amdgcn_mfma_f32_16x16x32_bf16(Kf, Qf[kc], accS[kf], 0, 0, 0);
            }
        }

        // causal mask (also kills fully-future filler blocks)
        float s8[8];
        float mx = -3e38f;
        #pragma unroll
        for (int kf = 0; kf < 2; ++kf)
            #pragma unroll
            for (int r = 0; r < 4; ++r) {
                int pos = kbase + kf * 16 + g * 4 + r;
                float sv = (pos <= i) ? accS[kf][r] : -3e38f;
                s8[kf * 4 + r] = sv;
                mx = fmaxf(mx, sv);
            }
        mx = fmaxf(mx, __shfl_xor(mx, 16));
        mx = fmaxf(mx, __shfl_xor(mx, 32));
        float mnew = fmaxf(m, mx);
        float corr = __expf(m - mnew);
        float psum = 0.f;
        float p8[8];
        #pragma unroll
        for (int j = 0; j < 8; ++j) {
            float p = (s8[j] <= -1e37f) ? 0.f : __expf(s8[j] - mnew);
            p8[j] = p;
            psum += p;
        }
        psum += __shfl_xor(psum, 16);
        psum += __shfl_xor(psum, 32);
        l = l * corr + psum;
        m = mnew;

        // P -> per-wave LDS tile [key][head]
        #pragma unroll
        for (int kf = 0; kf < 2; ++kf)
            #pragma unroll
            for (int r = 0; r < 4; ++r)
                Ps[wave][kf * 16 + g * 4 + r][c] = p8[kf * 4 + r];

        // rescale accO (row = head g*4+r; corr lives at lane = head)
        #pragma unroll
        for (int r = 0; r < 4; ++r) {
            float cr = __shfl(corr, g * 4 + r);
            accO[0][r] *= cr;
            accO[1][r] *= cr;
        }

        // P as A-fragment: row = head c, k = key g*8+j
        short8 paf;
        #pragma unroll
        for (int j = 0; j < 8; ++j)
            paf[j] = (short)f2bf(Ps[wave][g * 8 + j][c]);

        // PV: accO[nf] += P * V for this wave's dims
        #pragma unroll
        for (int nf = 0; nf < 2; ++nf) {
            short8 vf = *(short8*)&VtS[(wave * 32 + nf * 16 + c) * 36 + g * 8];
            accO[nf] = __builtin_amdgcn_mfma_f32_16x16x32_bf16(paf, vf, accO[nf], 0, 0, 0);
        }
        __syncthreads();   // next chunk staging overwrites Ks/VtS
    }

    // epilogue: O[head g*4+r][dim wave*32+nf*16+c] * g1 / l
    #pragma unroll
    for (int r = 0; r < 4; ++r) {
        int head = g * 4 + r;
        float lq = __shfl(l, head);
        float g1 = sigmoidf_(gl[(size_t)i * 48 + head * 3 + 1]);
        float sc = g1 / lq;
        #pragma unroll
        for (int nf = 0; nf < 2; ++nf)
            comb[(size_t)i * HIDDEN + head * DIM + wave * 32 + nf * 16 + c] += accO[nf][r] * sc;
    }
}

// ---------------------------------------------------------------------------
// Sliding-window attention via MFMA (swapped QK^T), bf16 inputs.
// ---------------------------------------------------------------------------
__global__ __launch_bounds__(256) void swin_mfma(const unsigned short* __restrict__ qb,
                                                 const unsigned short* __restrict__ kb,
                                                 const unsigned short* __restrict__ vT,
                                                 const float* __restrict__ gl,
                                                 float* __restrict__ comb) {
    const int h = blockIdx.x, qt = blockIdx.y;
    const int q0 = qt * 64;
    const int s0 = (q0 - WINSZ > 0) ? (q0 - WINSZ) : 0;
    const int nch = (q0 + 64 - s0) >> 5;
    const int tid = threadIdx.x, wave = tid >> 6, lane = tid & 63;
    const int c = lane & 15, g = lane >> 4;

    __shared__ unsigned short Qs[64 * 128];
    __shared__ unsigned short Ks[32 * 128];
    __shared__ unsigned short VtS[128 * 36];
    __shared__ float Ps[4][32][17];

    {
        int r = tid >> 2;
        int base = (tid & 3) * 32;
        #pragma unroll
        for (int s = 0; s < 4; ++s) {
            int d0 = base + s * 8;
            short8 v = *(const short8*)&qb[(size_t)(q0 + r) * HIDDEN + h * DIM + d0];
            *(short8*)&Qs[r * 128 + (d0 ^ ((r & 7) << 3))] = v;
        }
    }
    __syncthreads();

    short8 Qf[4];
    {
        int qrow = wave * 16 + c;
        #pragma unroll
        for (int kc = 0; kc < 4; ++kc) {
            int d0 = kc * 32 + g * 8;
            Qf[kc] = *(short8*)&Qs[qrow * 128 + (d0 ^ ((qrow & 7) << 3))];
        }
    }

    const int gq = q0 + wave * 16 + c;
    float m = -3e38f, l = 0.f;
    f32x4 accO[8];
    #pragma unroll
    for (int nf = 0; nf < 8; ++nf) accO[nf] = (f32x4){0.f, 0.f, 0.f, 0.f};

    for (int ch = 0; ch < nch; ++ch) {
        int kbase = s0 + ch * 32;
        {
            int r = tid >> 3;
            int d0 = (tid & 7) * 16;
            #pragma unroll
            for (int s = 0; s < 2; ++s) {
                int dd = d0 + s * 8;
                short8 v = *(const short8*)&kb[(size_t)(kbase + r) * DIM + dd];
                *(short8*)&Ks[r * 128 + (dd ^ ((r & 7) << 3))] = v;
            }
            int d = tid >> 1;
            int k0 = (tid & 1) * 16;
            short8 v0 = *(const short8*)&vT[(size_t)d * SEQ + kbase + k0];
            short8 v1 = *(const short8*)&vT[(size_t)d * SEQ + kbase + k0 + 8];
            *(short8*)&VtS[d * 36 + k0] = v0;
            *(short8*)&VtS[d * 36 + k0 + 8] = v1;
        }
        __syncthreads();

        f32x4 accS[2];
        accS[0] = (f32x4){0.f, 0.f, 0.f, 0.f};
        accS[1] = (f32x4){0.f, 0.f, 0.f, 0.f};
        #pragma unroll
        for (int kf = 0; kf < 2; ++kf) {
            int krow = kf * 16 + c;
            #pragma unroll
            for (int kc = 0; kc < 4; ++kc) {
                int d0 = kc * 32 + g * 8;
                short8 Kf = *(short8*)&Ks[krow * 128 + (d0 ^ ((krow & 7) << 3))];
                accS[kf] = __builtin_amdgcn_mfma_f32_16x16x32_bf16(Kf, Qf[kc], accS[kf], 0, 0, 0);
            }
        }

        float s8[8];
        float mx = -3e38f;
        #pragma unroll
        for (int kf = 0; kf < 2; ++kf)
            #pragma unroll
            for (int r = 0; r < 4; ++r) {
                int pos = kbase + kf * 16 + g * 4 + r;
                bool ok = (pos <= gq) && (pos >= gq - WINSZ);
                float sv = ok ? accS[kf][r] : -3e38f;
                s8[kf * 4 + r] = sv;
                mx = fmaxf(mx, sv);
            }
        mx = fmaxf(mx, __shfl_xor(mx, 16));
        mx = fmaxf(mx, __shfl_xor(mx, 32));
        float mnew = fmaxf(m, mx);
        float corr = __expf(m - mnew);
        float psum = 0.f;
        float p8[8];
        #pragma unroll
        for (int j = 0; j < 8; ++j) {
            float p = (s8[j] <= -1e37f) ? 0.f : __expf(s8[j] - mnew);
            p8[j] = p;
            psum += p;
        }
        psum += __shfl_xor(psum, 16);
        psum += __shfl_xor(psum, 32);
        l = l * corr + psum;
        m = mnew;

        #pragma unroll
        for (int kf = 0; kf < 2; ++kf)
            #pragma unroll
            for (int r = 0; r < 4; ++r)
                Ps[wave][kf * 16 + g * 4 + r][c] = p8[kf * 4 + r];

        #pragma unroll
        for (int r = 0; r < 4; ++r) {
            float cr = __shfl(corr, g * 4 + r);
            #pragma unroll
            for (int nf = 0; nf < 8; ++nf)
                accO[nf][r] *= cr;
        }

        short8 paf;
        #pragma unroll
        for (int j = 0; j < 8; ++j)
            paf[j] = (short)f2bf(Ps[wave][g * 8 + j][c]);

        #pragma unroll
        for (int nf = 0; nf < 8; ++nf) {
            short8 vf = *(short8*)&VtS[(nf * 16 + c) * 36 + g * 8];
            accO[nf] = __builtin_amdgcn_mfma_f32_16x16x32_bf16(paf, vf, accO[nf], 0, 0, 0);
        }
        __syncthreads();
    }

    #pragma unroll
    for (int r = 0; r < 4; ++r) {
        float lq = __shfl(l, g * 4 + r);
        int token = q0 + wave * 16 + g * 4 + r;
        float g2 = sigmoidf_(gl[(size_t)token * 48 + h * 3 + 2]);
        float sc = g2 / lq;
        #pragma unroll
        for (int nf = 0; nf < 8; ++nf)
            comb[(size_t)token * HIDDEN + h * DIM + nf * 16 + c] += accO[nf][r] * sc;
    }
}

// ---------------------------------------------------------------------------
extern "C" void kernel_launch(void* const* d_in, const int* in_sizes, int n_in,
                              void* d_out, int out_size, void* d_ws, size_t ws_size,
                              hipStream_t stream) {
    const float* x  = (const float*)d_in[0];
    const float* Wq = (const float*)d_in[2];
    const float* Wk = (const float*)d_in[3];
    const float* Wv = (const float*)d_in[4];
    const float* Wo = (const float*)d_in[5];
    const float* Wg = (const float*)d_in[6];
    const float* pe = (const float*)d_in[7];
    float* out = (float*)d_out;

    // workspace layout (36.7 MB, proven footprint)
    char* w = (char*)d_ws;
    float* q    = (float*)(w);               // 16 MB  (early: kvg scratch; late: comb hi/lo)
    float* comb = (float*)(w + 16777216);    // 16 MB  (early: x hi/lo; late: Wo hi/lo)
    float* kbuf = (float*)(w + 33554432);    // 1 MB
    float* vbuf = (float*)(w + 34603008);    // 1 MB
    float* gl   = (float*)(w + 35651584);    // 384 KB
    float* ck   = (float*)(w + 36044800);    // 32 KB
    float* cv   = (float*)(w + 36077568);    // 32 KB
    float* blk  = (float*)(w + 36110336);    // 512 KB
    int*   idx  = (int*)  (w + 36634624);    // 64 KB

    // scratch aliases
    unsigned short* Xh   = (unsigned short*)comb;            // x hi/lo (comb region)
    unsigned short* Xl   = Xh + 4194304;
    unsigned short* Wqh  = (unsigned short*)out;             // d_out dead until final
    unsigned short* Wql  = Wqh + 4194304;
    unsigned short* Ch   = (unsigned short*)q;               // q dead after attn
    unsigned short* Cl   = Ch + 4194304;
    unsigned short* Woh  = (unsigned short*)comb;            // comb dead after split
    unsigned short* Wol  = Woh + 4194304;
    float*          kvgOut = q;                              // q region (3 MB)
    unsigned short* kvgBth = (unsigned short*)(w + 4194304); // q region +4 MB
    unsigned short* kvgBtl = kvgBth + 786432;
    // bf16 attention inputs (d_out region, after q-proj consumes Wqh/Wql)
    unsigned short* qb16 = (unsigned short*)out;             // 8 MB
    unsigned short* kb16 = qb16 + 4194304;                   // 0.5 MB
    unsigned short* vT16 = kb16 + 262144;                    // 0.5 MB

    // 1. split x
    split_pair<<<4096, 256, 0, stream>>>(x, Xh, Xl);

    // 2. combined k/v/gate projection
    tsplit_g<<<dim3(4, 64), 256, 0, stream>>>(Wk, kvgBth, kvgBtl, 128, 0);
    tsplit_g<<<dim3(4, 64), 256, 0, stream>>>(Wv, kvgBth, kvgBtl, 128, 128);
    tsplit_g<<<dim3(2, 64), 256, 0, stream>>>(Wg, kvgBth, kvgBtl, 48,  256);
    gemm3s<<<dim3(3, 16), 256, 0, stream>>>(Xh, Xl, kvgBth, kvgBtl, kvgOut,
                                            SEQ, KVGN, HIDDEN);
    unpack_kvg<<<SEQ, 256, 0, stream>>>(kvgOut, kbuf, vbuf, gl);

    // 3. q projection
    tsplit<<<dim3(64, 64), 256, 0, stream>>>(Wq, Wqh, Wql);
    gemm3s<<<dim3(16, 16), 256, 0, stream>>>(Xh, Xl, Wqh, Wql, q, SEQ, HIDDEN, HIDDEN);

    // 4. compress (un-roped k) then rope q,k
    compress_kernel<<<NCB, DIM, 0, stream>>>(kbuf, vbuf, pe, ck, cv);
    rope_qk<<<SEQ, 64, 0, stream>>>(q, kbuf);

    // 5. bf16 prep for MFMA attention (d_out region now free)
    prep_cast<<<SEQ, 256, 0, stream>>>(q, kbuf, qb16, kb16);
    tcast_v<<<dim3(4, 64), 256, 0, stream>>>(vbuf, vT16);

    // 6. compressed attention -> comb fp32 (full init) + blk
    cmp_flash<<<SEQ, 256, 0, stream>>>(q, ck, cv, gl, comb, blk);

    // 7. top-k
    topk2<<<SEQ / 256, 256, 0, stream>>>(blk, idx);

    // 8. sparse attention via MFMA (comb += g1*out)
    sparse_mfma<<<SEQ, 256, 0, stream>>>(qb16, kb16, vT16, idx, gl, comb);

    // 9. sliding-window attention via MFMA (comb += g2*out)
    swin_mfma<<<dim3(16, 32), 256, 0, stream>>>(qb16, kb16, vT16, gl, comb);

    // 10. output projection
    split_pair<<<4096, 256, 0, stream>>>(comb, Ch, Cl);
    tsplit<<<dim3(64, 64), 256, 0, stream>>>(Wo, Woh, Wol);
    gemm3s<<<dim3(16, 16), 256, 0, stream>>>(Ch, Cl, Woh, Wol, out, SEQ, HIDDEN, HIDDEN);
}

// Round 8
// 576.242 us; speedup vs baseline: 6.6886x; 1.1328x over previous
//
#include <hip/hip_runtime.h>
#include <hip/hip_bf16.h>

constexpr int SEQ    = 2048;
constexpr int HIDDEN = 2048;
constexpr int NHQ    = 16;
constexpr int DIM    = 128;
constexpr int NCB    = 64;
constexpr int NTOP   = 8;
constexpr int WINSZ  = 512;
constexpr int KVGN   = 384;

#define SCALEF 0.08838834764831845f
#define NEGF  -1e30f

using short8 = __attribute__((ext_vector_type(8))) short;
using f32x4  = __attribute__((ext_vector_type(4))) float;

__device__ inline unsigned short f2bf(float f) {
    unsigned u = __float_as_uint(f);
    unsigned r = (u + 0x7fffu + ((u >> 16) & 1u)) >> 16;
    return (unsigned short)r;
}
__device__ inline float bf2f(unsigned short b) {
    return __uint_as_float(((unsigned)b) << 16);
}
__device__ inline float sigmoidf_(float x) { return 1.0f / (1.0f + __expf(-x)); }

// async global->LDS, 16 bytes per lane. LDS dest: wave-uniform base + lane*16.
__device__ inline void gload16(const unsigned short* g, unsigned short* l) {
    __builtin_amdgcn_global_load_lds(
        (const __attribute__((address_space(1))) unsigned int*)g,
        (__attribute__((address_space(3))) unsigned int*)l,
        16, 0, 0);
}

// ---------------------------------------------------------------------------
// split fp32 -> (hi, lo) bf16 pair, elementwise.
// ---------------------------------------------------------------------------
__global__ __launch_bounds__(256) void split_pair(const float* __restrict__ in,
                                                  unsigned short* __restrict__ hi,
                                                  unsigned short* __restrict__ lo) {
    int i = (blockIdx.x * 256 + threadIdx.x) * 4;
    float4 v = *(const float4*)&in[i];
    ushort4 h, l;
    h.x = f2bf(v.x); l.x = f2bf(v.x - bf2f(h.x));
    h.y = f2bf(v.y); l.y = f2bf(v.y - bf2f(h.y));
    h.z = f2bf(v.z); l.z = f2bf(v.z - bf2f(h.z));
    h.w = f2bf(v.w); l.w = f2bf(v.w - bf2f(h.w));
    *(ushort4*)&hi[i] = h;
    *(ushort4*)&lo[i] = l;
}

// ---------------------------------------------------------------------------
// transpose + split: W[2048][2048] fp32 -> Th/Tl[N][K] bf16. 32x32 tiles.
// ---------------------------------------------------------------------------
__global__ __launch_bounds__(256) void tsplit(const float* __restrict__ W,
                                              unsigned short* __restrict__ Th,
                                              unsigned short* __restrict__ Tl) {
    __shared__ float t[32][33];
    const int k0 = blockIdx.y * 32, n0 = blockIdx.x * 32;
    const int ty = threadIdx.x >> 3, tx = threadIdx.x & 7;
    float4 v = *(const float4*)&W[(size_t)(k0 + ty) * HIDDEN + n0 + tx * 4];
    t[ty][tx * 4 + 0] = v.x; t[ty][tx * 4 + 1] = v.y;
    t[ty][tx * 4 + 2] = v.z; t[ty][tx * 4 + 3] = v.w;
    __syncthreads();
    ushort4 h, l;
    float a0 = t[tx * 4 + 0][ty], a1 = t[tx * 4 + 1][ty];
    float a2 = t[tx * 4 + 2][ty], a3 = t[tx * 4 + 3][ty];
    h.x = f2bf(a0); l.x = f2bf(a0 - bf2f(h.x));
    h.y = f2bf(a1); l.y = f2bf(a1 - bf2f(h.y));
    h.z = f2bf(a2); l.z = f2bf(a2 - bf2f(h.z));
    h.w = f2bf(a3); l.w = f2bf(a3 - bf2f(h.w));
    *(ushort4*)&Th[(size_t)(n0 + ty) * HIDDEN + k0 + tx * 4] = h;
    *(ushort4*)&Tl[(size_t)(n0 + ty) * HIDDEN + k0 + tx * 4] = l;
}

// ---------------------------------------------------------------------------
// Generic guarded transpose+split: W[2048][Nd] -> rows [rowOff+n][k].
// ---------------------------------------------------------------------------
__global__ __launch_bounds__(256) void tsplit_g(const float* __restrict__ W,
                                                unsigned short* __restrict__ Th,
                                                unsigned short* __restrict__ Tl,
                                                int Nd, int rowOff) {
    __shared__ float t[32][33];
    const int k0 = blockIdx.y * 32, n0 = blockIdx.x * 32;
    const int ty = threadIdx.x >> 3, tx = threadIdx.x & 7;
    #pragma unroll
    for (int j = 0; j < 4; ++j) {
        int c = n0 + tx * 4 + j;
        t[ty][tx * 4 + j] = (c < Nd) ? W[(size_t)(k0 + ty) * Nd + c] : 0.f;
    }
    __syncthreads();
    ushort4 h, l;
    float a0 = t[tx * 4 + 0][ty], a1 = t[tx * 4 + 1][ty];
    float a2 = t[tx * 4 + 2][ty], a3 = t[tx * 4 + 3][ty];
    h.x = f2bf(a0); l.x = f2bf(a0 - bf2f(h.x));
    h.y = f2bf(a1); l.y = f2bf(a1 - bf2f(h.y));
    h.z = f2bf(a2); l.z = f2bf(a2 - bf2f(h.z));
    h.w = f2bf(a3); l.w = f2bf(a3 - bf2f(h.w));
    *(ushort4*)&Th[(size_t)(rowOff + n0 + ty) * HIDDEN + k0 + tx * 4] = h;
    *(ushort4*)&Tl[(size_t)(rowOff + n0 + ty) * HIDDEN + k0 + tx * 4] = l;
}

// ---------------------------------------------------------------------------
// unpack kvg[2048][384] -> k, v, gl
// ---------------------------------------------------------------------------
__global__ __launch_bounds__(256) void unpack_kvg(const float* __restrict__ kvg,
                                                  float* __restrict__ k,
                                                  float* __restrict__ v,
                                                  float* __restrict__ g) {
    int i = blockIdx.x, t = threadIdx.x;
    if (t < 128) {
        k[(size_t)i * DIM + t] = kvg[(size_t)i * KVGN + t];
        v[(size_t)i * DIM + t] = kvg[(size_t)i * KVGN + 128 + t];
    } else if (t < 176) {
        g[(size_t)i * 48 + (t - 128)] = kvg[(size_t)i * KVGN + 256 + (t - 128)];
    }
}

// ---------------------------------------------------------------------------
// Split-bf16 MFMA GEMM (fp32-grade): C = (Ah+Al) * (Bh+Bl)^T.
// BM=128, BN=64, BK=32; 4 waves (2x2), wave tile 64x32 (4x2 frags), 3 MFMA/pair.
// Staging via global_load_lds width=16 into a linear 1536-slot LDS arena:
//   slots [0,512) Ah, [512,1024) Al  (slot = c*128 + row, c = k-chunk of 8)
//   slots [1024,1280) Bh, [1280,1536) Bl (slot = c*64 + row)
// Wave w, round r stages slots [r*256 + w*64, +64) -> LDS linear in lane order.
// ---------------------------------------------------------------------------
__global__ __launch_bounds__(256) void gemm3s(const unsigned short* __restrict__ Ah,
                                              const unsigned short* __restrict__ Al,
                                              const unsigned short* __restrict__ Bh,
                                              const unsigned short* __restrict__ Bl,
                                              float* __restrict__ C,
                                              int M, int N, int K) {
    __shared__ __align__(16) unsigned short LDSG[1536 * 8];   // 24 KB
    const int tid = threadIdx.x, lane = tid & 63, wave = tid >> 6;
    const int wr = wave >> 1, wc = wave & 1;
    const int brow = blockIdx.y * 128, bcol = blockIdx.x * 64;
    const int lr = lane & 15, lc = lane >> 4;

    // per-thread staging source pointers (slot S = r*256 + tid), k0 = 0
    const unsigned short* gp[6];
    #pragma unroll
    for (int r = 0; r < 6; ++r) {
        int S = r * 256 + tid;
        if (S < 512) {
            gp[r] = &Ah[(size_t)(brow + (S & 127)) * K + (S >> 7) * 8];
        } else if (S < 1024) {
            int s = S - 512;
            gp[r] = &Al[(size_t)(brow + (s & 127)) * K + (s >> 7) * 8];
        } else if (S < 1280) {
            int s = S - 1024;
            gp[r] = &Bh[(size_t)(bcol + (s & 63)) * K + (s >> 6) * 8];
        } else {
            int s = S - 1280;
            gp[r] = &Bl[(size_t)(bcol + (s & 63)) * K + (s >> 6) * 8];
        }
    }

    f32x4 acc[4][2];
    #pragma unroll
    for (int a = 0; a < 4; ++a) {
        acc[a][0] = (f32x4){0.f, 0.f, 0.f, 0.f};
        acc[a][1] = (f32x4){0.f, 0.f, 0.f, 0.f};
    }

    for (int k0 = 0; k0 < K; k0 += 32) {
        #pragma unroll
        for (int r = 0; r < 6; ++r) {
            gload16(gp[r], &LDSG[(r * 256 + wave * 64) * 8]);
            gp[r] += 32;
        }
        __syncthreads();   // drains global_load_lds (vmcnt) + orders LDS

        short8 fah[4], fal[4], fbh[2], fbl[2];
        #pragma unroll
        for (int mi = 0; mi < 4; ++mi) {
            int arow = wr * 64 + mi * 16 + lr;
            fah[mi] = *(short8*)&LDSG[(lc * 128 + arow) * 8];
            fal[mi] = *(short8*)&LDSG[(512 + lc * 128 + arow) * 8];
        }
        #pragma unroll
        for (int ni = 0; ni < 2; ++ni) {
            int brw = wc * 32 + ni * 16 + lr;
            fbh[ni] = *(short8*)&LDSG[(1024 + lc * 64 + brw) * 8];
            fbl[ni] = *(short8*)&LDSG[(1280 + lc * 64 + brw) * 8];
        }
        #pragma unroll
        for (int mi = 0; mi < 4; ++mi)
            #pragma unroll
            for (int ni = 0; ni < 2; ++ni) {
                acc[mi][ni] = __builtin_amdgcn_mfma_f32_16x16x32_bf16(fah[mi], fbh[ni], acc[mi][ni], 0, 0, 0);
                acc[mi][ni] = __builtin_amdgcn_mfma_f32_16x16x32_bf16(fal[mi], fbh[ni], acc[mi][ni], 0, 0, 0);
                acc[mi][ni] = __builtin_amdgcn_mfma_f32_16x16x32_bf16(fah[mi], fbl[ni], acc[mi][ni], 0, 0, 0);
            }
        __syncthreads();   // LDS consumed; next iteration restages
    }

    #pragma unroll
    for (int mi = 0; mi < 4; ++mi)
        #pragma unroll
        for (int ni = 0; ni < 2; ++ni) {
            int col  = bcol + wc * 32 + ni * 16 + lr;
            int rowb = brow + wr * 64 + mi * 16 + lc * 4;
            #pragma unroll
            for (int r = 0; r < 4; ++r)
                C[(size_t)(rowb + r) * N + col] = acc[mi][ni][r];
        }
}

// ---------------------------------------------------------------------------
// Compress: ck[m]=rope(mean(k+pe), pos=32m), cv[m]=mean(v). Un-roped k input.
// ---------------------------------------------------------------------------
__global__ void compress_kernel(const float* __restrict__ k,
                                const float* __restrict__ v,
                                const float* __restrict__ pe,
                                float* __restrict__ ck,
                                float* __restrict__ cv) {
    int m = blockIdx.x, d = threadIdx.x;
    float sk = 0.f, sv = 0.f, sp = 0.f;
    for (int s = 0; s < 32; ++s) {
        sk += k[(size_t)(m * 32 + s) * DIM + d];
        sv += v[(size_t)(m * 32 + s) * DIM + d];
        sp += pe[s * DIM + d];
    }
    float ckv = (sk + sp) * (1.0f / 32.0f);
    cv[m * DIM + d] = sv * (1.0f / 32.0f);
    __shared__ float tmp[DIM];
    tmp[d] = ckv;
    __syncthreads();
    int j = d & 63;
    float inv = powf(10000.0f, -(float)(2 * j) / 128.0f);
    float ang = (float)(m * 32) * inv;
    float c = cosf(ang), s = sinf(ang);
    float x1 = tmp[j], x2 = tmp[j + 64];
    ck[m * DIM + d] = (d < 64) ? (x1 * c - x2 * s) : (x2 * c + x1 * s);
}

__global__ void rope_qk(float* __restrict__ q, float* __restrict__ k) {
    int i = blockIdx.x, j = threadIdx.x;
    float inv = powf(10000.0f, -(float)(2 * j) / 128.0f);
    float ang = (float)i * inv;
    float c = cosf(ang), s = sinf(ang);
    for (int h = 0; h < NHQ; ++h) {
        float* p = q + ((size_t)i * NHQ + h) * DIM;
        float x1 = p[j], x2 = p[j + 64];
        p[j]      = x1 * c - x2 * s;
        p[j + 64] = x2 * c + x1 * s;
    }
    float* p = k + (size_t)i * DIM;
    float x1 = p[j], x2 = p[j + 64];
    p[j]      = x1 * c - x2 * s;
    p[j + 64] = x2 * c + x1 * s;
}

// ---------------------------------------------------------------------------
// prep: qb16 = bf16(q * SCALE) [2048][2048]; kb16 = bf16(k) [2048][128]
// ---------------------------------------------------------------------------
__global__ __launch_bounds__(256) void prep_cast(const float* __restrict__ q,
                                                 const float* __restrict__ k,
                                                 unsigned short* __restrict__ qb,
                                                 unsigned short* __restrict__ kb) {
    int i = blockIdx.x, t = threadIdx.x;
    {
        int d0 = t * 8;
        float4 a = *(const float4*)&q[(size_t)i * HIDDEN + d0];
        float4 b = *(const float4*)&q[(size_t)i * HIDDEN + d0 + 4];
        ushort4 ha, hb;
        ha.x = f2bf(a.x * SCALEF); ha.y = f2bf(a.y * SCALEF);
        ha.z = f2bf(a.z * SCALEF); ha.w = f2bf(a.w * SCALEF);
        hb.x = f2bf(b.x * SCALEF); hb.y = f2bf(b.y * SCALEF);
        hb.z = f2bf(b.z * SCALEF); hb.w = f2bf(b.w * SCALEF);
        *(ushort4*)&qb[(size_t)i * HIDDEN + d0] = ha;
        *(ushort4*)&qb[(size_t)i * HIDDEN + d0 + 4] = hb;
    }
    if (t < 16) {
        int d0 = t * 8;
        float4 a = *(const float4*)&k[(size_t)i * DIM + d0];
        float4 b = *(const float4*)&k[(size_t)i * DIM + d0 + 4];
        ushort4 ha, hb;
        ha.x = f2bf(a.x); ha.y = f2bf(a.y); ha.z = f2bf(a.z); ha.w = f2bf(a.w);
        hb.x = f2bf(b.x); hb.y = f2bf(b.y); hb.z = f2bf(b.z); hb.w = f2bf(b.w);
        *(ushort4*)&kb[(size_t)i * DIM + d0] = ha;
        *(ushort4*)&kb[(size_t)i * DIM + d0 + 4] = hb;
    }
}

// ---------------------------------------------------------------------------
// vT16[128][2048] = bf16(v[2048][128])^T. 32x32 tiles, grid (4, 64).
// ---------------------------------------------------------------------------
__global__ __launch_bounds__(256) void tcast_v(const float* __restrict__ v,
                                               unsigned short* __restrict__ vT) {
    __shared__ float tbuf[32][33];
    const int r0 = blockIdx.y * 32, c0 = blockIdx.x * 32;
    const int ty = threadIdx.x >> 3, tx = threadIdx.x & 7;
    float4 val = *(const float4*)&v[(size_t)(r0 + ty) * DIM + c0 + tx * 4];
    tbuf[ty][tx * 4 + 0] = val.x; tbuf[ty][tx * 4 + 1] = val.y;
    tbuf[ty][tx * 4 + 2] = val.z; tbuf[ty][tx * 4 + 3] = val.w;
    __syncthreads();
    ushort4 o;
    o.x = f2bf(tbuf[tx * 4 + 0][ty]);
    o.y = f2bf(tbuf[tx * 4 + 1][ty]);
    o.z = f2bf(tbuf[tx * 4 + 2][ty]);
    o.w = f2bf(tbuf[tx * 4 + 3][ty]);
    *(ushort4*)&vT[(size_t)(c0 + ty) * SEQ + r0 + tx * 4] = o;
}

// ---------------------------------------------------------------------------
// Compressed attention per token: writes comb (fp32, full init) + blk scores.
// ---------------------------------------------------------------------------
__global__ __launch_bounds__(256) void cmp_flash(const float* __restrict__ q,
                                                 const float* __restrict__ ck,
                                                 const float* __restrict__ cv,
                                                 const float* __restrict__ gl,
                                                 float* __restrict__ comb,
                                                 float* __restrict__ blk) {
    const int i = blockIdx.x, tid = threadIdx.x, wave = tid >> 6, lane = tid & 63;
    __shared__ float Qs[16][132];
    __shared__ float KV[64][132];
    __shared__ float ss[16][66];

    for (int t = tid; t < 512; t += 256) {
        int r = t >> 5, c4 = (t & 31) * 4;
        *(float4*)&Qs[r][c4] = *(const float4*)&q[(size_t)i * HIDDEN + r * DIM + c4];
    }
    for (int t = tid; t < 2048; t += 256) {
        int r = t >> 5, c4 = (t & 31) * 4;
        *(float4*)&KV[r][c4] = *(const float4*)&ck[(size_t)r * DIM + c4];
    }
    __syncthreads();

    const int hi = lane & 15, mg = lane >> 4;
    float s4[4] = {0.f, 0.f, 0.f, 0.f};
    for (int d = 0; d < 128; d += 4) {
        float4 qv = *(float4*)&Qs[hi][d];
        #pragma unroll
        for (int jj = 0; jj < 4; ++jj) {
            float4 kv = *(float4*)&KV[wave * 16 + mg * 4 + jj][d];
            s4[jj] = fmaf(qv.x, kv.x, fmaf(qv.y, kv.y, fmaf(qv.z, kv.z, fmaf(qv.w, kv.w, s4[jj]))));
        }
    }
    #pragma unroll
    for (int jj = 0; jj < 4; ++jj) {
        int m = wave * 16 + mg * 4 + jj;
        ss[hi][m] = (i >= m * 32 + 31) ? s4[jj] * SCALEF : NEGF;
    }
    __syncthreads();

    for (int hh = 0; hh < 4; ++hh) {
        int h = wave * 4 + hh;
        float val = ss[h][lane];
        float mx = val;
        for (int o = 32; o; o >>= 1) mx = fmaxf(mx, __shfl_xor(mx, o));
        float e = (val <= NEGF * 0.5f) ? 0.f : __expf(val - mx);
        float z = e;
        for (int o = 32; o; o >>= 1) z += __shfl_xor(z, o);
        ss[h][lane] = (z > 0.f) ? e * (1.0f / z) : 0.f;
    }
    __syncthreads();

    if (tid < 64) {
        float sb = 0.f;
        for (int h = 0; h < 16; ++h) sb += ss[h][tid];
        blk[(size_t)i * NCB + tid] = sb;
    }

    for (int t = tid; t < 2048; t += 256) {
        int r = t >> 5, c4 = (t & 31) * 4;
        *(float4*)&KV[r][c4] = *(const float4*)&cv[(size_t)r * DIM + c4];
    }
    __syncthreads();

    const int h2 = tid & 15, dg = tid >> 4;
    float o8[8] = {0.f,0.f,0.f,0.f,0.f,0.f,0.f,0.f};
    for (int kk = 0; kk < 64; ++kk) {
        float p = ss[h2][kk];
        float4 va = *(float4*)&KV[kk][dg * 8];
        float4 vb = *(float4*)&KV[kk][dg * 8 + 4];
        o8[0] = fmaf(p, va.x, o8[0]); o8[1] = fmaf(p, va.y, o8[1]);
        o8[2] = fmaf(p, va.z, o8[2]); o8[3] = fmaf(p, va.w, o8[3]);
        o8[4] = fmaf(p, vb.x, o8[4]); o8[5] = fmaf(p, vb.y, o8[5]);
        o8[6] = fmaf(p, vb.z, o8[6]); o8[7] = fmaf(p, vb.w, o8[7]);
    }
    float g0 = sigmoidf_(gl[(size_t)i * 48 + h2 * 3 + 0]);
    #pragma unroll
    for (int x = 0; x < 8; ++x)
        comb[(size_t)i * HIDDEN + h2 * DIM + dg * 8 + x] = g0 * o8[x];
}

// ---------------------------------------------------------------------------
// Top-k (exact jax.lax.top_k tie semantics).
// ---------------------------------------------------------------------------
__global__ __launch_bounds__(256) void topk2(const float* __restrict__ blk,
                                             int* __restrict__ oidx) {
    __shared__ float L[256][68];
    int base = blockIdx.x * 256;
    for (int t = threadIdx.x; t < 256 * 16; t += 256) {
        int r = t >> 4, c4 = (t & 15) * 4;
        *(float4*)&L[r][c4] = *(const float4*)&blk[(size_t)(base + r) * NCB + c4];
    }
    __syncthreads();
    int i = base + threadIdx.x;
    int tb = i >> 5;
    unsigned long long used = 0ull;
    for (int t = 0; t < NTOP; ++t) {
        float best = -3e38f; int bi = 0;
        for (int m = 0; m < NCB; ++m) {
            if ((used >> m) & 1ull) continue;
            float s = L[threadIdx.x][m];
            if (m > tb) s = NEGF;
            if (m == 0 || (m <= tb && m > tb - 2)) s = 1e30f;
            if (s > best) { best = s; bi = m; }
        }
        used |= 1ull << bi;
        oidx[i * NTOP + t] = bi;
    }
}

// ---------------------------------------------------------------------------
// Sparse top-k attention via MFMA (swapped QK^T), bf16 inputs, per-token block.
// ---------------------------------------------------------------------------
__global__ __launch_bounds__(256) void sparse_mfma(const unsigned short* __restrict__ qb,
                                                   const unsigned short* __restrict__ kb,
                                                   const unsigned short* __restrict__ vT,
                                                   const int* __restrict__ idx,
                                                   const float* __restrict__ gl,
                                                   float* __restrict__ comb) {
    const int i = blockIdx.x;
    const int tid = threadIdx.x, wave = tid >> 6, lane = tid & 63;
    const int c = lane & 15, g = lane >> 4;

    __shared__ unsigned short Qs[16 * 128];
    __shared__ unsigned short Ks[32 * 128];
    __shared__ unsigned short VtS[128 * 36];
    __shared__ float Ps[4][32][17];
    __shared__ int sb[8];

    if (tid < 8) sb[tid] = idx[i * NTOP + tid];
    {
        int r = tid >> 4, d0 = (tid & 15) * 8;
        short8 v = *(const short8*)&qb[(size_t)i * HIDDEN + r * DIM + d0];
        *(short8*)&Qs[r * 128 + (d0 ^ ((r & 7) << 3))] = v;
    }
    __syncthreads();

    short8 Qf[4];
    #pragma unroll
    for (int kc = 0; kc < 4; ++kc) {
        int d0 = kc * 32 + g * 8;
        Qf[kc] = *(short8*)&Qs[c * 128 + (d0 ^ ((c & 7) << 3))];
    }

    float m = -3e38f, l = 0.f;
    f32x4 accO[2];
    accO[0] = (f32x4){0.f, 0.f, 0.f, 0.f};
    accO[1] = (f32x4){0.f, 0.f, 0.f, 0.f};

    for (int ch = 0; ch < 8; ++ch) {
        int kbase = sb[ch] * 32;
        {
            int r = tid >> 3;
            int d0 = (tid & 7) * 16;
            #pragma unroll
            for (int s = 0; s < 2; ++s) {
                int dd = d0 + s * 8;
                short8 v = *(const short8*)&kb[(size_t)(kbase + r) * DIM + dd];
                *(short8*)&Ks[r * 128 + (dd ^ ((r & 7) << 3))] = v;
            }
            int d = tid >> 1;
            int k0 = (tid & 1) * 16;
            short8 v0 = *(const short8*)&vT[(size_t)d * SEQ + kbase + k0];
            short8 v1 = *(const short8*)&vT[(size_t)d * SEQ + kbase + k0 + 8];
            *(short8*)&VtS[d * 36 + k0] = v0;
            *(short8*)&VtS[d * 36 + k0 + 8] = v1;
        }
        __syncthreads();

        f32x4 accS[2];
        accS[0] = (f32x4){0.f, 0.f, 0.f, 0.f};
        accS[1] = (f32x4){0.f, 0.f, 0.f, 0.f};
        #pragma unroll
        for (int kf = 0; kf < 2; ++kf) {
            int krow = kf * 16 + c;
            #pragma unroll
            for (int kc = 0; kc < 4; ++kc) {
                int d0 = kc * 32 + g * 8;
                short8 Kf = *(short8*)&Ks[krow * 128 + (d0 ^ ((krow & 7) << 3))];
                accS[kf] = __builtin_amdgcn_mfma_f32_16x16x32_bf16(Kf, Qf[kc], accS[kf], 0, 0, 0);
            }
        }

        float s8[8];
        float mx = -3e38f;
        #pragma unroll
        for (int kf = 0; kf < 2; ++kf)
            #pragma unroll
            for (int r = 0; r < 4; ++r) {
                int pos = kbase + kf * 16 + g * 4 + r;
                float sv = (pos <= i) ? accS[kf][r] : -3e38f;
                s8[kf * 4 + r] = sv;
                mx = fmaxf(mx, sv);
            }
        mx = fmaxf(mx, __shfl_xor(mx, 16));
        mx = fmaxf(mx, __shfl_xor(mx, 32));
        float mnew = fmaxf(m, mx);
        float corr = __expf(m - mnew);
        float psum = 0.f;
        float p8[8];
        #pragma unroll
        for (int j = 0; j < 8; ++j) {
            float p = (s8[j] <= -1e37f) ? 0.f : __expf(s8[j] - mnew);
            p8[j] = p;
            psum += p;
        }
        psum += __shfl_xor(psum, 16);
        psum += __shfl_xor(psum, 32);
        l = l * corr + psum;
        m = mnew;

        #pragma unroll
        for (int kf = 0; kf < 2; ++kf)
            #pragma unroll
            for (int r = 0; r < 4; ++r)
                Ps[wave][kf * 16 + g * 4 + r][c] = p8[kf * 4 + r];

        #pragma unroll
        for (int r = 0; r < 4; ++r) {
            float cr = __shfl(corr, g * 4 + r);
            accO[0][r] *= cr;
            accO[1][r] *= cr;
        }

        short8 paf;
        #pragma unroll
        for (int j = 0; j < 8; ++j)
            paf[j] = (short)f2bf(Ps[wave][g * 8 + j][c]);

        #pragma unroll
        for (int nf = 0; nf < 2; ++nf) {
            short8 vf = *(short8*)&VtS[(wave * 32 + nf * 16 + c) * 36 + g * 8];
            accO[nf] = __builtin_amdgcn_mfma_f32_16x16x32_bf16(paf, vf, accO[nf], 0, 0, 0);
        }
        __syncthreads();
    }

    #pragma unroll
    for (int r = 0; r < 4; ++r) {
        int head = g * 4 + r;
        float lq = __shfl(l, head);
        float g1 = sigmoidf_(gl[(size_t)i * 48 + head * 3 + 1]);
        float sc = g1 / lq;
        #pragma unroll
        for (int nf = 0; nf < 2; ++nf)
            comb[(size_t)i * HIDDEN + head * DIM + wave * 32 + nf * 16 + c] += accO[nf][r] * sc;
    }
}

// ---------------------------------------------------------------------------
// Sliding-window attention via MFMA (swapped QK^T), bf16 inputs.
// ---------------------------------------------------------------------------
__global__ __launch_bounds__(256) void swin_mfma(const unsigned short* __restrict__ qb,
                                                 const unsigned short* __restrict__ kb,
                                                 const unsigned short* __restrict__ vT,
                                                 const float* __restrict__ gl,
                                                 float* __restrict__ comb) {
    const int h = blockIdx.x, qt = blockIdx.y;
    const int q0 = qt * 64;
    const int s0 = (q0 - WINSZ > 0) ? (q0 - WINSZ) : 0;
    const int nch = (q0 + 64 - s0) >> 5;
    const int tid = threadIdx.x, wave = tid >> 6, lane = tid & 63;
    const int c = lane & 15, g = lane >> 4;

    __shared__ unsigned short Qs[64 * 128];
    __shared__ unsigned short Ks[32 * 128];
    __shared__ unsigned short VtS[128 * 36];
    __shared__ float Ps[4][32][17];

    {
        int r = tid >> 2;
        int base = (tid & 3) * 32;
        #pragma unroll
        for (int s = 0; s < 4; ++s) {
            int d0 = base + s * 8;
            short8 v = *(const short8*)&qb[(size_t)(q0 + r) * HIDDEN + h * DIM + d0];
            *(short8*)&Qs[r * 128 + (d0 ^ ((r & 7) << 3))] = v;
        }
    }
    __syncthreads();

    short8 Qf[4];
    {
        int qrow = wave * 16 + c;
        #pragma unroll
        for (int kc = 0; kc < 4; ++kc) {
            int d0 = kc * 32 + g * 8;
            Qf[kc] = *(short8*)&Qs[qrow * 128 + (d0 ^ ((qrow & 7) << 3))];
        }
    }

    const int gq = q0 + wave * 16 + c;
    float m = -3e38f, l = 0.f;
    f32x4 accO[8];
    #pragma unroll
    for (int nf = 0; nf < 8; ++nf) accO[nf] = (f32x4){0.f, 0.f, 0.f, 0.f};

    for (int ch = 0; ch < nch; ++ch) {
        int kbase = s0 + ch * 32;
        {
            int r = tid >> 3;
            int d0 = (tid & 7) * 16;
            #pragma unroll
            for (int s = 0; s < 2; ++s) {
                int dd = d0 + s * 8;
                short8 v = *(const short8*)&kb[(size_t)(kbase + r) * DIM + dd];
                *(short8*)&Ks[r * 128 + (dd ^ ((r & 7) << 3))] = v;
            }
            int d = tid >> 1;
            int k0 = (tid & 1) * 16;
            short8 v0 = *(const short8*)&vT[(size_t)d * SEQ + kbase + k0];
            short8 v1 = *(const short8*)&vT[(size_t)d * SEQ + kbase + k0 + 8];
            *(short8*)&VtS[d * 36 + k0] = v0;
            *(short8*)&VtS[d * 36 + k0 + 8] = v1;
        }
        __syncthreads();

        f32x4 accS[2];
        accS[0] = (f32x4){0.f, 0.f, 0.f, 0.f};
        accS[1] = (f32x4){0.f, 0.f, 0.f, 0.f};
        #pragma unroll
        for (int kf = 0; kf < 2; ++kf) {
            int krow = kf * 16 + c;
            #pragma unroll
            for (int kc = 0; kc < 4; ++kc) {
                int d0 = kc * 32 + g * 8;
                short8 Kf = *(short8*)&Ks[krow * 128 + (d0 ^ ((krow & 7) << 3))];
                accS[kf] = __builtin_amdgcn_mfma_f32_16x16x32_bf16(Kf, Qf[kc], accS[kf], 0, 0, 0);
            }
        }

        float s8[8];
        float mx = -3e38f;
        #pragma unroll
        for (int kf = 0; kf < 2; ++kf)
            #pragma unroll
            for (int r = 0; r < 4; ++r) {
                int pos = kbase + kf * 16 + g * 4 + r;
                bool ok = (pos <= gq) && (pos >= gq - WINSZ);
                float sv = ok ? accS[kf][r] : -3e38f;
                s8[kf * 4 + r] = sv;
                mx = fmaxf(mx, sv);
            }
        mx = fmaxf(mx, __shfl_xor(mx, 16));
        mx = fmaxf(mx, __shfl_xor(mx, 32));
        float mnew = fmaxf(m, mx);
        float corr = __expf(m - mnew);
        float psum = 0.f;
        float p8[8];
        #pragma unroll
        for (int j = 0; j < 8; ++j) {
            float p = (s8[j] <= -1e37f) ? 0.f : __expf(s8[j] - mnew);
            p8[j] = p;
            psum += p;
        }
        psum += __shfl_xor(psum, 16);
        psum += __shfl_xor(psum, 32);
        l = l * corr + psum;
        m = mnew;

        #pragma unroll
        for (int kf = 0; kf < 2; ++kf)
            #pragma unroll
            for (int r = 0; r < 4; ++r)
                Ps[wave][kf * 16 + g * 4 + r][c] = p8[kf * 4 + r];

        #pragma unroll
        for (int r = 0; r < 4; ++r) {
            float cr = __shfl(corr, g * 4 + r);
            #pragma unroll
            for (int nf = 0; nf < 8; ++nf)
                accO[nf][r] *= cr;
        }

        short8 paf;
        #pragma unroll
        for (int j = 0; j < 8; ++j)
            paf[j] = (short)f2bf(Ps[wave][g * 8 + j][c]);

        #pragma unroll
        for (int nf = 0; nf < 8; ++nf) {
            short8 vf = *(short8*)&VtS[(nf * 16 + c) * 36 + g * 8];
            accO[nf] = __builtin_amdgcn_mfma_f32_16x16x32_bf16(paf, vf, accO[nf], 0, 0, 0);
        }
        __syncthreads();
    }

    #pragma unroll
    for (int r = 0; r < 4; ++r) {
        float lq = __shfl(l, g * 4 + r);
        int token = q0 + wave * 16 + g * 4 + r;
        float g2 = sigmoidf_(gl[(size_t)token * 48 + h * 3 + 2]);
        float sc = g2 / lq;
        #pragma unroll
        for (int nf = 0; nf < 8; ++nf)
            comb[(size_t)token * HIDDEN + h * DIM + nf * 16 + c] += accO[nf][r] * sc;
    }
}

// ---------------------------------------------------------------------------
extern "C" void kernel_launch(void* const* d_in, const int* in_sizes, int n_in,
                              void* d_out, int out_size, void* d_ws, size_t ws_size,
                              hipStream_t stream) {
    const float* x  = (const float*)d_in[0];
    const float* Wq = (const float*)d_in[2];
    const float* Wk = (const float*)d_in[3];
    const float* Wv = (const float*)d_in[4];
    const float* Wo = (const float*)d_in[5];
    const float* Wg = (const float*)d_in[6];
    const float* pe = (const float*)d_in[7];
    float* out = (float*)d_out;

    // workspace layout (36.7 MB, proven footprint)
    char* w = (char*)d_ws;
    float* q    = (float*)(w);               // 16 MB  (early: kvg scratch; late: comb hi/lo)
    float* comb = (float*)(w + 16777216);    // 16 MB  (early: x hi/lo; late: Wo hi/lo)
    float* kbuf = (float*)(w + 33554432);    // 1 MB
    float* vbuf = (float*)(w + 34603008);    // 1 MB
    float* gl   = (float*)(w + 35651584);    // 384 KB
    float* ck   = (float*)(w + 36044800);    // 32 KB
    float* cv   = (float*)(w + 36077568);    // 32 KB
    float* blk  = (float*)(w + 36110336);    // 512 KB
    int*   idx  = (int*)  (w + 36634624);    // 64 KB

    // scratch aliases
    unsigned short* Xh   = (unsigned short*)comb;            // x hi/lo (comb region)
    unsigned short* Xl   = Xh + 4194304;
    unsigned short* Wqh  = (unsigned short*)out;             // d_out dead until final
    unsigned short* Wql  = Wqh + 4194304;
    unsigned short* Ch   = (unsigned short*)q;               // q dead after attn
    unsigned short* Cl   = Ch + 4194304;
    unsigned short* Woh  = (unsigned short*)comb;            // comb dead after split
    unsigned short* Wol  = Woh + 4194304;
    float*          kvgOut = q;                              // q region (3 MB)
    unsigned short* kvgBth = (unsigned short*)(w + 4194304); // q region +4 MB
    unsigned short* kvgBtl = kvgBth + 786432;
    // bf16 attention inputs (d_out region, after q-proj consumes Wqh/Wql)
    unsigned short* qb16 = (unsigned short*)out;             // 8 MB
    unsigned short* kb16 = qb16 + 4194304;                   // 0.5 MB
    unsigned short* vT16 = kb16 + 262144;                    // 0.5 MB

    // 1. split x
    split_pair<<<4096, 256, 0, stream>>>(x, Xh, Xl);

    // 2. combined k/v/gate projection
    tsplit_g<<<dim3(4, 64), 256, 0, stream>>>(Wk, kvgBth, kvgBtl, 128, 0);
    tsplit_g<<<dim3(4, 64), 256, 0, stream>>>(Wv, kvgBth, kvgBtl, 128, 128);
    tsplit_g<<<dim3(2, 64), 256, 0, stream>>>(Wg, kvgBth, kvgBtl, 48,  256);
    gemm3s<<<dim3(KVGN / 64, 16), 256, 0, stream>>>(Xh, Xl, kvgBth, kvgBtl, kvgOut,
                                                    SEQ, KVGN, HIDDEN);
    unpack_kvg<<<SEQ, 256, 0, stream>>>(kvgOut, kbuf, vbuf, gl);

    // 3. q projection
    tsplit<<<dim3(64, 64), 256, 0, stream>>>(Wq, Wqh, Wql);
    gemm3s<<<dim3(32, 16), 256, 0, stream>>>(Xh, Xl, Wqh, Wql, q, SEQ, HIDDEN, HIDDEN);

    // 4. compress (un-roped k) then rope q,k
    compress_kernel<<<NCB, DIM, 0, stream>>>(kbuf, vbuf, pe, ck, cv);
    rope_qk<<<SEQ, 64, 0, stream>>>(q, kbuf);

    // 5. bf16 prep for MFMA attention (d_out region now free)
    prep_cast<<<SEQ, 256, 0, stream>>>(q, kbuf, qb16, kb16);
    tcast_v<<<dim3(4, 64), 256, 0, stream>>>(vbuf, vT16);

    // 6. compressed attention -> comb fp32 (full init) + blk
    cmp_flash<<<SEQ, 256, 0, stream>>>(q, ck, cv, gl, comb, blk);

    // 7. top-k
    topk2<<<SEQ / 256, 256, 0, stream>>>(blk, idx);

    // 8. sparse attention via MFMA (comb += g1*out)
    sparse_mfma<<<SEQ, 256, 0, stream>>>(qb16, kb16, vT16, idx, gl, comb);

    // 9. sliding-window attention via MFMA (comb += g2*out)
    swin_mfma<<<dim3(16, 32), 256, 0, stream>>>(qb16, kb16, vT16, gl, comb);

    // 10. output projection
    split_pair<<<4096, 256, 0, stream>>>(comb, Ch, Cl);
    tsplit<<<dim3(64, 64), 256, 0, stream>>>(Wo, Woh, Wol);
    gemm3s<<<dim3(32, 16), 256, 0, stream>>>(Ch, Cl, Woh, Wol, out, SEQ, HIDDEN, HIDDEN);
}

// Round 9
// 566.157 us; speedup vs baseline: 6.8077x; 1.0178x over previous
//
#include <hip/hip_runtime.h>
#include <hip/hip_bf16.h>

constexpr int SEQ    = 2048;
constexpr int HIDDEN = 2048;
constexpr int NHQ    = 16;
constexpr int DIM    = 128;
constexpr int NCB    = 64;
constexpr int NTOP   = 8;
constexpr int WINSZ  = 512;
constexpr int KVGN   = 384;

#define SCALEF 0.08838834764831845f
#define NEGF  -1e30f

using short8 = __attribute__((ext_vector_type(8))) short;
using f32x4  = __attribute__((ext_vector_type(4))) float;

__device__ inline unsigned short f2bf(float f) {
    unsigned u = __float_as_uint(f);
    unsigned r = (u + 0x7fffu + ((u >> 16) & 1u)) >> 16;
    return (unsigned short)r;
}
__device__ inline float bf2f(unsigned short b) {
    return __uint_as_float(((unsigned)b) << 16);
}
__device__ inline float sigmoidf_(float x) { return 1.0f / (1.0f + __expf(-x)); }

// async global->LDS, 16 bytes per lane. LDS dest: wave-uniform base + lane*16.
__device__ inline void gload16(const unsigned short* g, unsigned short* l) {
    __builtin_amdgcn_global_load_lds(
        (const __attribute__((address_space(1))) unsigned int*)g,
        (__attribute__((address_space(3))) unsigned int*)l,
        16, 0, 0);
}

// ---------------------------------------------------------------------------
// split fp32 -> (hi, lo) bf16 pair, elementwise.
// ---------------------------------------------------------------------------
__global__ __launch_bounds__(256) void split_pair(const float* __restrict__ in,
                                                  unsigned short* __restrict__ hi,
                                                  unsigned short* __restrict__ lo) {
    int i = (blockIdx.x * 256 + threadIdx.x) * 4;
    float4 v = *(const float4*)&in[i];
    ushort4 h, l;
    h.x = f2bf(v.x); l.x = f2bf(v.x - bf2f(h.x));
    h.y = f2bf(v.y); l.y = f2bf(v.y - bf2f(h.y));
    h.z = f2bf(v.z); l.z = f2bf(v.z - bf2f(h.z));
    h.w = f2bf(v.w); l.w = f2bf(v.w - bf2f(h.w));
    *(ushort4*)&hi[i] = h;
    *(ushort4*)&lo[i] = l;
}

// ---------------------------------------------------------------------------
// transpose + split: W[2048][2048] fp32 -> Th/Tl[N][K] bf16. 32x32 tiles.
// ---------------------------------------------------------------------------
__global__ __launch_bounds__(256) void tsplit(const float* __restrict__ W,
                                              unsigned short* __restrict__ Th,
                                              unsigned short* __restrict__ Tl) {
    __shared__ float t[32][33];
    const int k0 = blockIdx.y * 32, n0 = blockIdx.x * 32;
    const int ty = threadIdx.x >> 3, tx = threadIdx.x & 7;
    float4 v = *(const float4*)&W[(size_t)(k0 + ty) * HIDDEN + n0 + tx * 4];
    t[ty][tx * 4 + 0] = v.x; t[ty][tx * 4 + 1] = v.y;
    t[ty][tx * 4 + 2] = v.z; t[ty][tx * 4 + 3] = v.w;
    __syncthreads();
    ushort4 h, l;
    float a0 = t[tx * 4 + 0][ty], a1 = t[tx * 4 + 1][ty];
    float a2 = t[tx * 4 + 2][ty], a3 = t[tx * 4 + 3][ty];
    h.x = f2bf(a0); l.x = f2bf(a0 - bf2f(h.x));
    h.y = f2bf(a1); l.y = f2bf(a1 - bf2f(h.y));
    h.z = f2bf(a2); l.z = f2bf(a2 - bf2f(h.z));
    h.w = f2bf(a3); l.w = f2bf(a3 - bf2f(h.w));
    *(ushort4*)&Th[(size_t)(n0 + ty) * HIDDEN + k0 + tx * 4] = h;
    *(ushort4*)&Tl[(size_t)(n0 + ty) * HIDDEN + k0 + tx * 4] = l;
}

// ---------------------------------------------------------------------------
// Generic guarded transpose+split: W[2048][Nd] -> rows [rowOff+n][k].
// ---------------------------------------------------------------------------
__global__ __launch_bounds__(256) void tsplit_g(const float* __restrict__ W,
                                                unsigned short* __restrict__ Th,
                                                unsigned short* __restrict__ Tl,
                                                int Nd, int rowOff) {
    __shared__ float t[32][33];
    const int k0 = blockIdx.y * 32, n0 = blockIdx.x * 32;
    const int ty = threadIdx.x >> 3, tx = threadIdx.x & 7;
    #pragma unroll
    for (int j = 0; j < 4; ++j) {
        int c = n0 + tx * 4 + j;
        t[ty][tx * 4 + j] = (c < Nd) ? W[(size_t)(k0 + ty) * Nd + c] : 0.f;
    }
    __syncthreads();
    ushort4 h, l;
    float a0 = t[tx * 4 + 0][ty], a1 = t[tx * 4 + 1][ty];
    float a2 = t[tx * 4 + 2][ty], a3 = t[tx * 4 + 3][ty];
    h.x = f2bf(a0); l.x = f2bf(a0 - bf2f(h.x));
    h.y = f2bf(a1); l.y = f2bf(a1 - bf2f(h.y));
    h.z = f2bf(a2); l.z = f2bf(a2 - bf2f(h.z));
    h.w = f2bf(a3); l.w = f2bf(a3 - bf2f(h.w));
    *(ushort4*)&Th[(size_t)(rowOff + n0 + ty) * HIDDEN + k0 + tx * 4] = h;
    *(ushort4*)&Tl[(size_t)(rowOff + n0 + ty) * HIDDEN + k0 + tx * 4] = l;
}

// ---------------------------------------------------------------------------
// unpack kvg[2048][384] -> k, v, gl
// ---------------------------------------------------------------------------
__global__ __launch_bounds__(256) void unpack_kvg(const float* __restrict__ kvg,
                                                  float* __restrict__ k,
                                                  float* __restrict__ v,
                                                  float* __restrict__ g) {
    int i = blockIdx.x, t = threadIdx.x;
    if (t < 128) {
        k[(size_t)i * DIM + t] = kvg[(size_t)i * KVGN + t];
        v[(size_t)i * DIM + t] = kvg[(size_t)i * KVGN + 128 + t];
    } else if (t < 176) {
        g[(size_t)i * 48 + (t - 128)] = kvg[(size_t)i * KVGN + 256 + (t - 128)];
    }
}

// ---------------------------------------------------------------------------
// Split-bf16 MFMA GEMM (fp32-grade): C = (Ah+Al) * (Bh+Bl)^T.
// BM=128, BN=64, BK=32; 4 waves (2x2), wave tile 64x32 (4x2 frags), 3 MFMA/pair.
// DOUBLE-BUFFERED staging via global_load_lds width=16: at the top of each
// K-step the 6 prefetch loads for tile t+1 are issued into buf^1, then tile t
// is computed from buf, then ONE __syncthreads (drains vmcnt) flips buffers.
// Load latency overlaps the compute phase instead of preceding it.
// Slot map per arena (1536 slots x 16B):
//   [0,512) Ah (slot = c*128 + row), [512,1024) Al
//   [1024,1280) Bh (slot = c*64 + row), [1280,1536) Bl
// ---------------------------------------------------------------------------
__global__ __launch_bounds__(256) void gemm3s(const unsigned short* __restrict__ Ah,
                                              const unsigned short* __restrict__ Al,
                                              const unsigned short* __restrict__ Bh,
                                              const unsigned short* __restrict__ Bl,
                                              float* __restrict__ C,
                                              int M, int N, int K) {
    __shared__ __align__(16) unsigned short LDSG[2][1536 * 8];   // 48 KB
    const int tid = threadIdx.x, lane = tid & 63, wave = tid >> 6;
    const int wr = wave >> 1, wc = wave & 1;
    const int brow = blockIdx.y * 128, bcol = blockIdx.x * 64;
    const int lr = lane & 15, lc = lane >> 4;

    // per-thread staging source pointers (slot S = r*256 + tid), k0 = 0
    const unsigned short* gp[6];
    #pragma unroll
    for (int r = 0; r < 6; ++r) {
        int S = r * 256 + tid;
        if (S < 512) {
            gp[r] = &Ah[(size_t)(brow + (S & 127)) * K + (S >> 7) * 8];
        } else if (S < 1024) {
            int s = S - 512;
            gp[r] = &Al[(size_t)(brow + (s & 127)) * K + (s >> 7) * 8];
        } else if (S < 1280) {
            int s = S - 1024;
            gp[r] = &Bh[(size_t)(bcol + (s & 63)) * K + (s >> 6) * 8];
        } else {
            int s = S - 1280;
            gp[r] = &Bl[(size_t)(bcol + (s & 63)) * K + (s >> 6) * 8];
        }
    }

    f32x4 acc[4][2];
    #pragma unroll
    for (int a = 0; a < 4; ++a) {
        acc[a][0] = (f32x4){0.f, 0.f, 0.f, 0.f};
        acc[a][1] = (f32x4){0.f, 0.f, 0.f, 0.f};
    }

    const int ldsBase = wave * 64 * 8;   // wave-uniform within each round band

    // prologue: stage tile 0 into buf 0
    #pragma unroll
    for (int r = 0; r < 6; ++r) {
        gload16(gp[r], &LDSG[0][r * 256 * 8 + ldsBase]);
        gp[r] += 32;
    }
    __syncthreads();

    const int nt = K >> 5;   // K-steps
    int cur = 0;
    for (int kt = 1; kt <= nt; ++kt) {
        // prefetch tile kt into buf cur^1 (skipped on the last step)
        if (kt < nt) {
            #pragma unroll
            for (int r = 0; r < 6; ++r) {
                gload16(gp[r], &LDSG[cur ^ 1][r * 256 * 8 + ldsBase]);
                gp[r] += 32;
            }
        }

        // compute tile kt-1 from buf cur
        const unsigned short* B0 = &LDSG[cur][0];
        short8 fah[4], fal[4], fbh[2], fbl[2];
        #pragma unroll
        for (int mi = 0; mi < 4; ++mi) {
            int arow = wr * 64 + mi * 16 + lr;
            fah[mi] = *(const short8*)&B0[(lc * 128 + arow) * 8];
            fal[mi] = *(const short8*)&B0[(512 + lc * 128 + arow) * 8];
        }
        #pragma unroll
        for (int ni = 0; ni < 2; ++ni) {
            int brw = wc * 32 + ni * 16 + lr;
            fbh[ni] = *(const short8*)&B0[(1024 + lc * 64 + brw) * 8];
            fbl[ni] = *(const short8*)&B0[(1280 + lc * 64 + brw) * 8];
        }
        #pragma unroll
        for (int mi = 0; mi < 4; ++mi)
            #pragma unroll
            for (int ni = 0; ni < 2; ++ni) {
                acc[mi][ni] = __builtin_amdgcn_mfma_f32_16x16x32_bf16(fah[mi], fbh[ni], acc[mi][ni], 0, 0, 0);
                acc[mi][ni] = __builtin_amdgcn_mfma_f32_16x16x32_bf16(fal[mi], fbh[ni], acc[mi][ni], 0, 0, 0);
                acc[mi][ni] = __builtin_amdgcn_mfma_f32_16x16x32_bf16(fah[mi], fbl[ni], acc[mi][ni], 0, 0, 0);
            }

        __syncthreads();   // drains prefetch (vmcnt) + separates read/write of buffers
        cur ^= 1;
    }

    #pragma unroll
    for (int mi = 0; mi < 4; ++mi)
        #pragma unroll
        for (int ni = 0; ni < 2; ++ni) {
            int col  = bcol + wc * 32 + ni * 16 + lr;
            int rowb = brow + wr * 64 + mi * 16 + lc * 4;
            #pragma unroll
            for (int r = 0; r < 4; ++r)
                C[(size_t)(rowb + r) * N + col] = acc[mi][ni][r];
        }
}

// ---------------------------------------------------------------------------
// Compress: ck[m]=rope(mean(k+pe), pos=32m), cv[m]=mean(v). Un-roped k input.
// ---------------------------------------------------------------------------
__global__ void compress_kernel(const float* __restrict__ k,
                                const float* __restrict__ v,
                                const float* __restrict__ pe,
                                float* __restrict__ ck,
                                float* __restrict__ cv) {
    int m = blockIdx.x, d = threadIdx.x;
    float sk = 0.f, sv = 0.f, sp = 0.f;
    for (int s = 0; s < 32; ++s) {
        sk += k[(size_t)(m * 32 + s) * DIM + d];
        sv += v[(size_t)(m * 32 + s) * DIM + d];
        sp += pe[s * DIM + d];
    }
    float ckv = (sk + sp) * (1.0f / 32.0f);
    cv[m * DIM + d] = sv * (1.0f / 32.0f);
    __shared__ float tmp[DIM];
    tmp[d] = ckv;
    __syncthreads();
    int j = d & 63;
    float inv = powf(10000.0f, -(float)(2 * j) / 128.0f);
    float ang = (float)(m * 32) * inv;
    float c = cosf(ang), s = sinf(ang);
    float x1 = tmp[j], x2 = tmp[j + 64];
    ck[m * DIM + d] = (d < 64) ? (x1 * c - x2 * s) : (x2 * c + x1 * s);
}

__global__ void rope_qk(float* __restrict__ q, float* __restrict__ k) {
    int i = blockIdx.x, j = threadIdx.x;
    float inv = powf(10000.0f, -(float)(2 * j) / 128.0f);
    float ang = (float)i * inv;
    float c = cosf(ang), s = sinf(ang);
    for (int h = 0; h < NHQ; ++h) {
        float* p = q + ((size_t)i * NHQ + h) * DIM;
        float x1 = p[j], x2 = p[j + 64];
        p[j]      = x1 * c - x2 * s;
        p[j + 64] = x2 * c + x1 * s;
    }
    float* p = k + (size_t)i * DIM;
    float x1 = p[j], x2 = p[j + 64];
    p[j]      = x1 * c - x2 * s;
    p[j + 64] = x2 * c + x1 * s;
}

// ---------------------------------------------------------------------------
// prep: qb16 = bf16(q * SCALE) [2048][2048]; kb16 = bf16(k) [2048][128]
// ---------------------------------------------------------------------------
__global__ __launch_bounds__(256) void prep_cast(const float* __restrict__ q,
                                                 const float* __restrict__ k,
                                                 unsigned short* __restrict__ qb,
                                                 unsigned short* __restrict__ kb) {
    int i = blockIdx.x, t = threadIdx.x;
    {
        int d0 = t * 8;
        float4 a = *(const float4*)&q[(size_t)i * HIDDEN + d0];
        float4 b = *(const float4*)&q[(size_t)i * HIDDEN + d0 + 4];
        ushort4 ha, hb;
        ha.x = f2bf(a.x * SCALEF); ha.y = f2bf(a.y * SCALEF);
        ha.z = f2bf(a.z * SCALEF); ha.w = f2bf(a.w * SCALEF);
        hb.x = f2bf(b.x * SCALEF); hb.y = f2bf(b.y * SCALEF);
        hb.z = f2bf(b.z * SCALEF); hb.w = f2bf(b.w * SCALEF);
        *(ushort4*)&qb[(size_t)i * HIDDEN + d0] = ha;
        *(ushort4*)&qb[(size_t)i * HIDDEN + d0 + 4] = hb;
    }
    if (t < 16) {
        int d0 = t * 8;
        float4 a = *(const float4*)&k[(size_t)i * DIM + d0];
        float4 b = *(const float4*)&k[(size_t)i * DIM + d0 + 4];
        ushort4 ha, hb;
        ha.x = f2bf(a.x); ha.y = f2bf(a.y); ha.z = f2bf(a.z); ha.w = f2bf(a.w);
        hb.x = f2bf(b.x); hb.y = f2bf(b.y); hb.z = f2bf(b.z); hb.w = f2bf(b.w);
        *(ushort4*)&kb[(size_t)i * DIM + d0] = ha;
        *(ushort4*)&kb[(size_t)i * DIM + d0 + 4] = hb;
    }
}

// ---------------------------------------------------------------------------
// vT16[128][2048] = bf16(v[2048][128])^T. 32x32 tiles, grid (4, 64).
// ---------------------------------------------------------------------------
__global__ __launch_bounds__(256) void tcast_v(const float* __restrict__ v,
                                               unsigned short* __restrict__ vT) {
    __shared__ float tbuf[32][33];
    const int r0 = blockIdx.y * 32, c0 = blockIdx.x * 32;
    const int ty = threadIdx.x >> 3, tx = threadIdx.x & 7;
    float4 val = *(const float4*)&v[(size_t)(r0 + ty) * DIM + c0 + tx * 4];
    tbuf[ty][tx * 4 + 0] = val.x; tbuf[ty][tx * 4 + 1] = val.y;
    tbuf[ty][tx * 4 + 2] = val.z; tbuf[ty][tx * 4 + 3] = val.w;
    __syncthreads();
    ushort4 o;
    o.x = f2bf(tbuf[tx * 4 + 0][ty]);
    o.y = f2bf(tbuf[tx * 4 + 1][ty]);
    o.z = f2bf(tbuf[tx * 4 + 2][ty]);
    o.w = f2bf(tbuf[tx * 4 + 3][ty]);
    *(ushort4*)&vT[(size_t)(c0 + ty) * SEQ + r0 + tx * 4] = o;
}

// ---------------------------------------------------------------------------
// Compressed attention per token: writes comb (fp32, full init) + blk scores.
// ---------------------------------------------------------------------------
__global__ __launch_bounds__(256) void cmp_flash(const float* __restrict__ q,
                                                 const float* __restrict__ ck,
                                                 const float* __restrict__ cv,
                                                 const float* __restrict__ gl,
                                                 float* __restrict__ comb,
                                                 float* __restrict__ blk) {
    const int i = blockIdx.x, tid = threadIdx.x, wave = tid >> 6, lane = tid & 63;
    __shared__ float Qs[16][132];
    __shared__ float KV[64][132];
    __shared__ float ss[16][66];

    for (int t = tid; t < 512; t += 256) {
        int r = t >> 5, c4 = (t & 31) * 4;
        *(float4*)&Qs[r][c4] = *(const float4*)&q[(size_t)i * HIDDEN + r * DIM + c4];
    }
    for (int t = tid; t < 2048; t += 256) {
        int r = t >> 5, c4 = (t & 31) * 4;
        *(float4*)&KV[r][c4] = *(const float4*)&ck[(size_t)r * DIM + c4];
    }
    __syncthreads();

    const int hi = lane & 15, mg = lane >> 4;
    float s4[4] = {0.f, 0.f, 0.f, 0.f};
    for (int d = 0; d < 128; d += 4) {
        float4 qv = *(float4*)&Qs[hi][d];
        #pragma unroll
        for (int jj = 0; jj < 4; ++jj) {
            float4 kv = *(float4*)&KV[wave * 16 + mg * 4 + jj][d];
            s4[jj] = fmaf(qv.x, kv.x, fmaf(qv.y, kv.y, fmaf(qv.z, kv.z, fmaf(qv.w, kv.w, s4[jj]))));
        }
    }
    #pragma unroll
    for (int jj = 0; jj < 4; ++jj) {
        int m = wave * 16 + mg * 4 + jj;
        ss[hi][m] = (i >= m * 32 + 31) ? s4[jj] * SCALEF : NEGF;
    }
    __syncthreads();

    for (int hh = 0; hh < 4; ++hh) {
        int h = wave * 4 + hh;
        float val = ss[h][lane];
        float mx = val;
        for (int o = 32; o; o >>= 1) mx = fmaxf(mx, __shfl_xor(mx, o));
        float e = (val <= NEGF * 0.5f) ? 0.f : __expf(val - mx);
        float z = e;
        for (int o = 32; o; o >>= 1) z += __shfl_xor(z, o);
        ss[h][lane] = (z > 0.f) ? e * (1.0f / z) : 0.f;
    }
    __syncthreads();

    if (tid < 64) {
        float sb = 0.f;
        for (int h = 0; h < 16; ++h) sb += ss[h][tid];
        blk[(size_t)i * NCB + tid] = sb;
    }

    for (int t = tid; t < 2048; t += 256) {
        int r = t >> 5, c4 = (t & 31) * 4;
        *(float4*)&KV[r][c4] = *(const float4*)&cv[(size_t)r * DIM + c4];
    }
    __syncthreads();

    const int h2 = tid & 15, dg = tid >> 4;
    float o8[8] = {0.f,0.f,0.f,0.f,0.f,0.f,0.f,0.f};
    for (int kk = 0; kk < 64; ++kk) {
        float p = ss[h2][kk];
        float4 va = *(float4*)&KV[kk][dg * 8];
        float4 vb = *(float4*)&KV[kk][dg * 8 + 4];
        o8[0] = fmaf(p, va.x, o8[0]); o8[1] = fmaf(p, va.y, o8[1]);
        o8[2] = fmaf(p, va.z, o8[2]); o8[3] = fmaf(p, va.w, o8[3]);
        o8[4] = fmaf(p, vb.x, o8[4]); o8[5] = fmaf(p, vb.y, o8[5]);
        o8[6] = fmaf(p, vb.z, o8[6]); o8[7] = fmaf(p, vb.w, o8[7]);
    }
    float g0 = sigmoidf_(gl[(size_t)i * 48 + h2 * 3 + 0]);
    #pragma unroll
    for (int x = 0; x < 8; ++x)
        comb[(size_t)i * HIDDEN + h2 * DIM + dg * 8 + x] = g0 * o8[x];
}

// ---------------------------------------------------------------------------
// Top-k (exact jax.lax.top_k tie semantics).
// ---------------------------------------------------------------------------
__global__ __launch_bounds__(256) void topk2(const float* __restrict__ blk,
                                             int* __restrict__ oidx) {
    __shared__ float L[256][68];
    int base = blockIdx.x * 256;
    for (int t = threadIdx.x; t < 256 * 16; t += 256) {
        int r = t >> 4, c4 = (t & 15) * 4;
        *(float4*)&L[r][c4] = *(const float4*)&blk[(size_t)(base + r) * NCB + c4];
    }
    __syncthreads();
    int i = base + threadIdx.x;
    int tb = i >> 5;
    unsigned long long used = 0ull;
    for (int t = 0; t < NTOP; ++t) {
        float best = -3e38f; int bi = 0;
        for (int m = 0; m < NCB; ++m) {
            if ((used >> m) & 1ull) continue;
            float s = L[threadIdx.x][m];
            if (m > tb) s = NEGF;
            if (m == 0 || (m <= tb && m > tb - 2)) s = 1e30f;
            if (s > best) { best = s; bi = m; }
        }
        used |= 1ull << bi;
        oidx[i * NTOP + t] = bi;
    }
}

// ---------------------------------------------------------------------------
// Sparse top-k attention via MFMA (swapped QK^T), bf16 inputs, per-token block.
// ---------------------------------------------------------------------------
__global__ __launch_bounds__(256) void sparse_mfma(const unsigned short* __restrict__ qb,
                                                   const unsigned short* __restrict__ kb,
                                                   const unsigned short* __restrict__ vT,
                                                   const int* __restrict__ idx,
                                                   const float* __restrict__ gl,
                                                   float* __restrict__ comb) {
    const int i = blockIdx.x;
    const int tid = threadIdx.x, wave = tid >> 6, lane = tid & 63;
    const int c = lane & 15, g = lane >> 4;

    __shared__ unsigned short Qs[16 * 128];
    __shared__ unsigned short Ks[32 * 128];
    __shared__ unsigned short VtS[128 * 36];
    __shared__ float Ps[4][32][17];
    __shared__ int sb[8];

    if (tid < 8) sb[tid] = idx[i * NTOP + tid];
    {
        int r = tid >> 4, d0 = (tid & 15) * 8;
        short8 v = *(const short8*)&qb[(size_t)i * HIDDEN + r * DIM + d0];
        *(short8*)&Qs[r * 128 + (d0 ^ ((r & 7) << 3))] = v;
    }
    __syncthreads();

    short8 Qf[4];
    #pragma unroll
    for (int kc = 0; kc < 4; ++kc) {
        int d0 = kc * 32 + g * 8;
        Qf[kc] = *(short8*)&Qs[c * 128 + (d0 ^ ((c & 7) << 3))];
    }

    float m = -3e38f, l = 0.f;
    f32x4 accO[2];
    accO[0] = (f32x4){0.f, 0.f, 0.f, 0.f};
    accO[1] = (f32x4){0.f, 0.f, 0.f, 0.f};

    for (int ch = 0; ch < 8; ++ch) {
        int kbase = sb[ch] * 32;
        {
            int r = tid >> 3;
            int d0 = (tid & 7) * 16;
            #pragma unroll
            for (int s = 0; s < 2; ++s) {
                int dd = d0 + s * 8;
                short8 v = *(const short8*)&kb[(size_t)(kbase + r) * DIM + dd];
                *(short8*)&Ks[r * 128 + (dd ^ ((r & 7) << 3))] = v;
            }
            int d = tid >> 1;
            int k0 = (tid & 1) * 16;
            short8 v0 = *(const short8*)&vT[(size_t)d * SEQ + kbase + k0];
            short8 v1 = *(const short8*)&vT[(size_t)d * SEQ + kbase + k0 + 8];
            *(short8*)&VtS[d * 36 + k0] = v0;
            *(short8*)&VtS[d * 36 + k0 + 8] = v1;
        }
        __syncthreads();

        f32x4 accS[2];
        accS[0] = (f32x4){0.f, 0.f, 0.f, 0.f};
        accS[1] = (f32x4){0.f, 0.f, 0.f, 0.f};
        #pragma unroll
        for (int kf = 0; kf < 2; ++kf) {
            int krow = kf * 16 + c;
            #pragma unroll
            for (int kc = 0; kc < 4; ++kc) {
                int d0 = kc * 32 + g * 8;
                short8 Kf = *(short8*)&Ks[krow * 128 + (d0 ^ ((krow & 7) << 3))];
                accS[kf] = __builtin_amdgcn_mfma_f32_16x16x32_bf16(Kf, Qf[kc], accS[kf], 0, 0, 0);
            }
        }

        float s8[8];
        float mx = -3e38f;
        #pragma unroll
        for (int kf = 0; kf < 2; ++kf)
            #pragma unroll
            for (int r = 0; r < 4; ++r) {
                int pos = kbase + kf * 16 + g * 4 + r;
                float sv = (pos <= i) ? accS[kf][r] : -3e38f;
                s8[kf * 4 + r] = sv;
                mx = fmaxf(mx, sv);
            }
        mx = fmaxf(mx, __shfl_xor(mx, 16));
        mx = fmaxf(mx, __shfl_xor(mx, 32));
        float mnew = fmaxf(m, mx);
        float corr = __expf(m - mnew);
        float psum = 0.f;
        float p8[8];
        #pragma unroll
        for (int j = 0; j < 8; ++j) {
            float p = (s8[j] <= -1e37f) ? 0.f : __expf(s8[j] - mnew);
            p8[j] = p;
            psum += p;
        }
        psum += __shfl_xor(psum, 16);
        psum += __shfl_xor(psum, 32);
        l = l * corr + psum;
        m = mnew;

        #pragma unroll
        for (int kf = 0; kf < 2; ++kf)
            #pragma unroll
            for (int r = 0; r < 4; ++r)
                Ps[wave][kf * 16 + g * 4 + r][c] = p8[kf * 4 + r];

        #pragma unroll
        for (int r = 0; r < 4; ++r) {
            float cr = __shfl(corr, g * 4 + r);
            accO[0][r] *= cr;
            accO[1][r] *= cr;
        }

        short8 paf;
        #pragma unroll
        for (int j = 0; j < 8; ++j)
            paf[j] = (short)f2bf(Ps[wave][g * 8 + j][c]);

        #pragma unroll
        for (int nf = 0; nf < 2; ++nf) {
            short8 vf = *(short8*)&VtS[(wave * 32 + nf * 16 + c) * 36 + g * 8];
            accO[nf] = __builtin_amdgcn_mfma_f32_16x16x32_bf16(paf, vf, accO[nf], 0, 0, 0);
        }
        __syncthreads();
    }

    #pragma unroll
    for (int r = 0; r < 4; ++r) {
        int head = g * 4 + r;
        float lq = __shfl(l, head);
        float g1 = sigmoidf_(gl[(size_t)i * 48 + head * 3 + 1]);
        float sc = g1 / lq;
        #pragma unroll
        for (int nf = 0; nf < 2; ++nf)
            comb[(size_t)i * HIDDEN + head * DIM + wave * 32 + nf * 16 + c] += accO[nf][r] * sc;
    }
}

// ---------------------------------------------------------------------------
// Sliding-window attention via MFMA (swapped QK^T), bf16 inputs.
// ---------------------------------------------------------------------------
__global__ __launch_bounds__(256) void swin_mfma(const unsigned short* __restrict__ qb,
                                                 const unsigned short* __restrict__ kb,
                                                 const unsigned short* __restrict__ vT,
                                                 const float* __restrict__ gl,
                                                 float* __restrict__ comb) {
    const int h = blockIdx.x, qt = blockIdx.y;
    const int q0 = qt * 64;
    const int s0 = (q0 - WINSZ > 0) ? (q0 - WINSZ) : 0;
    const int nch = (q0 + 64 - s0) >> 5;
    const int tid = threadIdx.x, wave = tid >> 6, lane = tid & 63;
    const int c = lane & 15, g = lane >> 4;

    __shared__ unsigned short Qs[64 * 128];
    __shared__ unsigned short Ks[32 * 128];
    __shared__ unsigned short VtS[128 * 36];
    __shared__ float Ps[4][32][17];

    {
        int r = tid >> 2;
        int base = (tid & 3) * 32;
        #pragma unroll
        for (int s = 0; s < 4; ++s) {
            int d0 = base + s * 8;
            short8 v = *(const short8*)&qb[(size_t)(q0 + r) * HIDDEN + h * DIM + d0];
            *(short8*)&Qs[r * 128 + (d0 ^ ((r & 7) << 3))] = v;
        }
    }
    __syncthreads();

    short8 Qf[4];
    {
        int qrow = wave * 16 + c;
        #pragma unroll
        for (int kc = 0; kc < 4; ++kc) {
            int d0 = kc * 32 + g * 8;
            Qf[kc] = *(short8*)&Qs[qrow * 128 + (d0 ^ ((qrow & 7) << 3))];
        }
    }

    const int gq = q0 + wave * 16 + c;
    float m = -3e38f, l = 0.f;
    f32x4 accO[8];
    #pragma unroll
    for (int nf = 0; nf < 8; ++nf) accO[nf] = (f32x4){0.f, 0.f, 0.f, 0.f};

    for (int ch = 0; ch < nch; ++ch) {
        int kbase = s0 + ch * 32;
        {
            int r = tid >> 3;
            int d0 = (tid & 7) * 16;
            #pragma unroll
            for (int s = 0; s < 2; ++s) {
                int dd = d0 + s * 8;
                short8 v = *(const short8*)&kb[(size_t)(kbase + r) * DIM + dd];
                *(short8*)&Ks[r * 128 + (dd ^ ((r & 7) << 3))] = v;
            }
            int d = tid >> 1;
            int k0 = (tid & 1) * 16;
            short8 v0 = *(const short8*)&vT[(size_t)d * SEQ + kbase + k0];
            short8 v1 = *(const short8*)&vT[(size_t)d * SEQ + kbase + k0 + 8];
            *(short8*)&VtS[d * 36 + k0] = v0;
            *(short8*)&VtS[d * 36 + k0 + 8] = v1;
        }
        __syncthreads();

        f32x4 accS[2];
        accS[0] = (f32x4){0.f, 0.f, 0.f, 0.f};
        accS[1] = (f32x4){0.f, 0.f, 0.f, 0.f};
        #pragma unroll
        for (int kf = 0; kf < 2; ++kf) {
            int krow = kf * 16 + c;
            #pragma unroll
            for (int kc = 0; kc < 4; ++kc) {
                int d0 = kc * 32 + g * 8;
                short8 Kf = *(short8*)&Ks[krow * 128 + (d0 ^ ((krow & 7) << 3))];
                accS[kf] = __builtin_amdgcn_mfma_f32_16x16x32_bf16(Kf, Qf[kc], accS[kf], 0, 0, 0);
            }
        }

        float s8[8];
        float mx = -3e38f;
        #pragma unroll
        for (int kf = 0; kf < 2; ++kf)
            #pragma unroll
            for (int r = 0; r < 4; ++r) {
                int pos = kbase + kf * 16 + g * 4 + r;
                bool ok = (pos <= gq) && (pos >= gq - WINSZ);
                float sv = ok ? accS[kf][r] : -3e38f;
                s8[kf * 4 + r] = sv;
                mx = fmaxf(mx, sv);
            }
        mx = fmaxf(mx, __shfl_xor(mx, 16));
        mx = fmaxf(mx, __shfl_xor(mx, 32));
        float mnew = fmaxf(m, mx);
        float corr = __expf(m - mnew);
        float psum = 0.f;
        float p8[8];
        #pragma unroll
        for (int j = 0; j < 8; ++j) {
            float p = (s8[j] <= -1e37f) ? 0.f : __expf(s8[j] - mnew);
            p8[j] = p;
            psum += p;
        }
        psum += __shfl_xor(psum, 16);
        psum += __shfl_xor(psum, 32);
        l = l * corr + psum;
        m = mnew;

        #pragma unroll
        for (int kf = 0; kf < 2; ++kf)
            #pragma unroll
            for (int r = 0; r < 4; ++r)
                Ps[wave][kf * 16 + g * 4 + r][c] = p8[kf * 4 + r];

        #pragma unroll
        for (int r = 0; r < 4; ++r) {
            float cr = __shfl(corr, g * 4 + r);
            #pragma unroll
            for (int nf = 0; nf < 8; ++nf)
                accO[nf][r] *= cr;
        }

        short8 paf;
        #pragma unroll
        for (int j = 0; j < 8; ++j)
            paf[j] = (short)f2bf(Ps[wave][g * 8 + j][c]);

        #pragma unroll
        for (int nf = 0; nf < 8; ++nf) {
            short8 vf = *(short8*)&VtS[(nf * 16 + c) * 36 + g * 8];
            accO[nf] = __builtin_amdgcn_mfma_f32_16x16x32_bf16(paf, vf, accO[nf], 0, 0, 0);
        }
        __syncthreads();
    }

    #pragma unroll
    for (int r = 0; r < 4; ++r) {
        float lq = __shfl(l, g * 4 + r);
        int token = q0 + wave * 16 + g * 4 + r;
        float g2 = sigmoidf_(gl[(size_t)token * 48 + h * 3 + 2]);
        float sc = g2 / lq;
        #pragma unroll
        for (int nf = 0; nf < 8; ++nf)
            comb[(size_t)token * HIDDEN + h * DIM + nf * 16 + c] += accO[nf][r] * sc;
    }
}

// ---------------------------------------------------------------------------
extern "C" void kernel_launch(void* const* d_in, const int* in_sizes, int n_in,
                              void* d_out, int out_size, void* d_ws, size_t ws_size,
                              hipStream_t stream) {
    const float* x  = (const float*)d_in[0];
    const float* Wq = (const float*)d_in[2];
    const float* Wk = (const float*)d_in[3];
    const float* Wv = (const float*)d_in[4];
    const float* Wo = (const float*)d_in[5];
    const float* Wg = (const float*)d_in[6];
    const float* pe = (const float*)d_in[7];
    float* out = (float*)d_out;

    // workspace layout (36.7 MB, proven footprint)
    char* w = (char*)d_ws;
    float* q    = (float*)(w);               // 16 MB  (early: kvg scratch; late: comb hi/lo)
    float* comb = (float*)(w + 16777216);    // 16 MB  (early: x hi/lo; late: Wo hi/lo)
    float* kbuf = (float*)(w + 33554432);    // 1 MB
    float* vbuf = (float*)(w + 34603008);    // 1 MB
    float* gl   = (float*)(w + 35651584);    // 384 KB
    float* ck   = (float*)(w + 36044800);    // 32 KB
    float* cv   = (float*)(w + 36077568);    // 32 KB
    float* blk  = (float*)(w + 36110336);    // 512 KB
    int*   idx  = (int*)  (w + 36634624);    // 64 KB

    // scratch aliases
    unsigned short* Xh   = (unsigned short*)comb;            // x hi/lo (comb region)
    unsigned short* Xl   = Xh + 4194304;
    unsigned short* Wqh  = (unsigned short*)out;             // d_out dead until final
    unsigned short* Wql  = Wqh + 4194304;
    unsigned short* Ch   = (unsigned short*)q;               // q dead after attn
    unsigned short* Cl   = Ch + 4194304;
    unsigned short* Woh  = (unsigned short*)comb;            // comb dead after split
    unsigned short* Wol  = Woh + 4194304;
    float*          kvgOut = q;                              // q region (3 MB)
    unsigned short* kvgBth = (unsigned short*)(w + 4194304); // q region +4 MB
    unsigned short* kvgBtl = kvgBth + 786432;
    // bf16 attention inputs (d_out region, after q-proj consumes Wqh/Wql)
    unsigned short* qb16 = (unsigned short*)out;             // 8 MB
    unsigned short* kb16 = qb16 + 4194304;                   // 0.5 MB
    unsigned short* vT16 = kb16 + 262144;                    // 0.5 MB

    // 1. split x
    split_pair<<<4096, 256, 0, stream>>>(x, Xh, Xl);

    // 2. combined k/v/gate projection
    tsplit_g<<<dim3(4, 64), 256, 0, stream>>>(Wk, kvgBth, kvgBtl, 128, 0);
    tsplit_g<<<dim3(4, 64), 256, 0, stream>>>(Wv, kvgBth, kvgBtl, 128, 128);
    tsplit_g<<<dim3(2, 64), 256, 0, stream>>>(Wg, kvgBth, kvgBtl, 48,  256);
    gemm3s<<<dim3(KVGN / 64, 16), 256, 0, stream>>>(Xh, Xl, kvgBth, kvgBtl, kvgOut,
                                                    SEQ, KVGN, HIDDEN);
    unpack_kvg<<<SEQ, 256, 0, stream>>>(kvgOut, kbuf, vbuf, gl);

    // 3. q projection
    tsplit<<<dim3(64, 64), 256, 0, stream>>>(Wq, Wqh, Wql);
    gemm3s<<<dim3(32, 16), 256, 0, stream>>>(Xh, Xl, Wqh, Wql, q, SEQ, HIDDEN, HIDDEN);

    // 4. compress (un-roped k) then rope q,k
    compress_kernel<<<NCB, DIM, 0, stream>>>(kbuf, vbuf, pe, ck, cv);
    rope_qk<<<SEQ, 64, 0, stream>>>(q, kbuf);

    // 5. bf16 prep for MFMA attention (d_out region now free)
    prep_cast<<<SEQ, 256, 0, stream>>>(q, kbuf, qb16, kb16);
    tcast_v<<<dim3(4, 64), 256, 0, stream>>>(vbuf, vT16);

    // 6. compressed attention -> comb fp32 (full init) + blk
    cmp_flash<<<SEQ, 256, 0, stream>>>(q, ck, cv, gl, comb, blk);

    // 7. top-k
    topk2<<<SEQ / 256, 256, 0, stream>>>(blk, idx);

    // 8. sparse attention via MFMA (comb += g1*out)
    sparse_mfma<<<SEQ, 256, 0, stream>>>(qb16, kb16, vT16, idx, gl, comb);

    // 9. sliding-window attention via MFMA (comb += g2*out)
    swin_mfma<<<dim3(16, 32), 256, 0, stream>>>(qb16, kb16, vT16, gl, comb);

    // 10. output projection
    split_pair<<<4096, 256, 0, stream>>>(comb, Ch, Cl);
    tsplit<<<dim3(64, 64), 256, 0, stream>>>(Wo, Woh, Wol);
    gemm3s<<<dim3(32, 16), 256, 0, stream>>>(Ch, Cl, Woh, Wol, out, SEQ, HIDDEN, HIDDEN);
}

// Round 10
// 528.520 us; speedup vs baseline: 7.2925x; 1.0712x over previous
//
#include <hip/hip_runtime.h>
#include <hip/hip_bf16.h>

constexpr int SEQ    = 2048;
constexpr int HIDDEN = 2048;
constexpr int NHQ    = 16;
constexpr int DIM    = 128;
constexpr int NCB    = 64;
constexpr int NTOP   = 8;
constexpr int WINSZ  = 512;
constexpr int KVGN   = 384;

#define SCALEF 0.08838834764831845f
#define NEGF  -1e30f

using short8 = __attribute__((ext_vector_type(8))) short;
using f32x4  = __attribute__((ext_vector_type(4))) float;

__device__ inline unsigned short f2bf(float f) {
    unsigned u = __float_as_uint(f);
    unsigned r = (u + 0x7fffu + ((u >> 16) & 1u)) >> 16;
    return (unsigned short)r;
}
__device__ inline float bf2f(unsigned short b) {
    return __uint_as_float(((unsigned)b) << 16);
}
__device__ inline float sigmoidf_(float x) { return 1.0f / (1.0f + __expf(-x)); }

// async global->LDS, 16 bytes per lane. LDS dest: wave-uniform base + lane*16.
__device__ inline void gload16(const unsigned short* g, unsigned short* l) {
    __builtin_amdgcn_global_load_lds(
        (const __attribute__((address_space(1))) unsigned int*)g,
        (__attribute__((address_space(3))) unsigned int*)l,
        16, 0, 0);
}

// ---------------------------------------------------------------------------
// zero n floats (n % 1024 == 0), grid = n/1024
// ---------------------------------------------------------------------------
__global__ __launch_bounds__(256) void zero_f4(float* __restrict__ p) {
    int i = (blockIdx.x * 256 + threadIdx.x) * 4;
    *(float4*)&p[i] = make_float4(0.f, 0.f, 0.f, 0.f);
}

// ---------------------------------------------------------------------------
// split fp32 -> (hi, lo) bf16 pair, elementwise.
// ---------------------------------------------------------------------------
__global__ __launch_bounds__(256) void split_pair(const float* __restrict__ in,
                                                  unsigned short* __restrict__ hi,
                                                  unsigned short* __restrict__ lo) {
    int i = (blockIdx.x * 256 + threadIdx.x) * 4;
    float4 v = *(const float4*)&in[i];
    ushort4 h, l;
    h.x = f2bf(v.x); l.x = f2bf(v.x - bf2f(h.x));
    h.y = f2bf(v.y); l.y = f2bf(v.y - bf2f(h.y));
    h.z = f2bf(v.z); l.z = f2bf(v.z - bf2f(h.z));
    h.w = f2bf(v.w); l.w = f2bf(v.w - bf2f(h.w));
    *(ushort4*)&hi[i] = h;
    *(ushort4*)&lo[i] = l;
}

// ---------------------------------------------------------------------------
// cast fp32 -> bf16 flat
// ---------------------------------------------------------------------------
__global__ __launch_bounds__(256) void cast_bf16(const float* __restrict__ in,
                                                 unsigned short* __restrict__ out) {
    int i = (blockIdx.x * 256 + threadIdx.x) * 4;
    float4 v = *(const float4*)&in[i];
    ushort4 o;
    o.x = f2bf(v.x); o.y = f2bf(v.y); o.z = f2bf(v.z); o.w = f2bf(v.w);
    *(ushort4*)&out[i] = o;
}

// ---------------------------------------------------------------------------
// transpose + split: W[2048][2048] fp32 -> Th/Tl[N][K] bf16. 32x32 tiles.
// ---------------------------------------------------------------------------
__global__ __launch_bounds__(256) void tsplit(const float* __restrict__ W,
                                              unsigned short* __restrict__ Th,
                                              unsigned short* __restrict__ Tl) {
    __shared__ float t[32][33];
    const int k0 = blockIdx.y * 32, n0 = blockIdx.x * 32;
    const int ty = threadIdx.x >> 3, tx = threadIdx.x & 7;
    float4 v = *(const float4*)&W[(size_t)(k0 + ty) * HIDDEN + n0 + tx * 4];
    t[ty][tx * 4 + 0] = v.x; t[ty][tx * 4 + 1] = v.y;
    t[ty][tx * 4 + 2] = v.z; t[ty][tx * 4 + 3] = v.w;
    __syncthreads();
    ushort4 h, l;
    float a0 = t[tx * 4 + 0][ty], a1 = t[tx * 4 + 1][ty];
    float a2 = t[tx * 4 + 2][ty], a3 = t[tx * 4 + 3][ty];
    h.x = f2bf(a0); l.x = f2bf(a0 - bf2f(h.x));
    h.y = f2bf(a1); l.y = f2bf(a1 - bf2f(h.y));
    h.z = f2bf(a2); l.z = f2bf(a2 - bf2f(h.z));
    h.w = f2bf(a3); l.w = f2bf(a3 - bf2f(h.w));
    *(ushort4*)&Th[(size_t)(n0 + ty) * HIDDEN + k0 + tx * 4] = h;
    *(ushort4*)&Tl[(size_t)(n0 + ty) * HIDDEN + k0 + tx * 4] = l;
}

// ---------------------------------------------------------------------------
// transpose + cast (single bf16): W[2048][2048] -> Wt[N][K]. 32x32 tiles.
// ---------------------------------------------------------------------------
__global__ __launch_bounds__(256) void tcast(const float* __restrict__ W,
                                             unsigned short* __restrict__ Wt) {
    __shared__ float t[32][33];
    const int k0 = blockIdx.y * 32, n0 = blockIdx.x * 32;
    const int ty = threadIdx.x >> 3, tx = threadIdx.x & 7;
    float4 v = *(const float4*)&W[(size_t)(k0 + ty) * HIDDEN + n0 + tx * 4];
    t[ty][tx * 4 + 0] = v.x; t[ty][tx * 4 + 1] = v.y;
    t[ty][tx * 4 + 2] = v.z; t[ty][tx * 4 + 3] = v.w;
    __syncthreads();
    ushort4 o;
    o.x = f2bf(t[tx * 4 + 0][ty]);
    o.y = f2bf(t[tx * 4 + 1][ty]);
    o.z = f2bf(t[tx * 4 + 2][ty]);
    o.w = f2bf(t[tx * 4 + 3][ty]);
    *(ushort4*)&Wt[(size_t)(n0 + ty) * HIDDEN + k0 + tx * 4] = o;
}

// ---------------------------------------------------------------------------
// Generic guarded transpose+split: W[2048][Nd] -> rows [rowOff+n][k].
// ---------------------------------------------------------------------------
__global__ __launch_bounds__(256) void tsplit_g(const float* __restrict__ W,
                                                unsigned short* __restrict__ Th,
                                                unsigned short* __restrict__ Tl,
                                                int Nd, int rowOff) {
    __shared__ float t[32][33];
    const int k0 = blockIdx.y * 32, n0 = blockIdx.x * 32;
    const int ty = threadIdx.x >> 3, tx = threadIdx.x & 7;
    #pragma unroll
    for (int j = 0; j < 4; ++j) {
        int c = n0 + tx * 4 + j;
        t[ty][tx * 4 + j] = (c < Nd) ? W[(size_t)(k0 + ty) * Nd + c] : 0.f;
    }
    __syncthreads();
    ushort4 h, l;
    float a0 = t[tx * 4 + 0][ty], a1 = t[tx * 4 + 1][ty];
    float a2 = t[tx * 4 + 2][ty], a3 = t[tx * 4 + 3][ty];
    h.x = f2bf(a0); l.x = f2bf(a0 - bf2f(h.x));
    h.y = f2bf(a1); l.y = f2bf(a1 - bf2f(h.y));
    h.z = f2bf(a2); l.z = f2bf(a2 - bf2f(h.z));
    h.w = f2bf(a3); l.w = f2bf(a3 - bf2f(h.w));
    *(ushort4*)&Th[(size_t)(rowOff + n0 + ty) * HIDDEN + k0 + tx * 4] = h;
    *(ushort4*)&Tl[(size_t)(rowOff + n0 + ty) * HIDDEN + k0 + tx * 4] = l;
}

// ---------------------------------------------------------------------------
// unpack kvg[2048][384] -> k, v, gl
// ---------------------------------------------------------------------------
__global__ __launch_bounds__(256) void unpack_kvg(const float* __restrict__ kvg,
                                                  float* __restrict__ k,
                                                  float* __restrict__ v,
                                                  float* __restrict__ g) {
    int i = blockIdx.x, t = threadIdx.x;
    if (t < 128) {
        k[(size_t)i * DIM + t] = kvg[(size_t)i * KVGN + t];
        v[(size_t)i * DIM + t] = kvg[(size_t)i * KVGN + 128 + t];
    } else if (t < 176) {
        g[(size_t)i * 48 + (t - 128)] = kvg[(size_t)i * KVGN + 256 + (t - 128)];
    }
}

// ---------------------------------------------------------------------------
// Split-bf16 MFMA GEMM (fp32-grade): C += (Ah+Al) * (Bh+Bl)^T, split-K via
// blockIdx.z (C must be zeroed first; atomicAdd write). Single-buffer staging
// via global_load_lds width=16, BM=128, BN=64, BK=32, 4 waves, 3 MFMA/pair.
// Slot map (1536 slots x 16B): [0,512) Ah (c*128+row), [512,1024) Al,
// [1024,1280) Bh (c*64+row), [1280,1536) Bl.
// ---------------------------------------------------------------------------
__global__ __launch_bounds__(256) void gemm3s(const unsigned short* __restrict__ Ah,
                                              const unsigned short* __restrict__ Al,
                                              const unsigned short* __restrict__ Bh,
                                              const unsigned short* __restrict__ Bl,
                                              float* __restrict__ C,
                                              int M, int N, int K) {
    __shared__ __align__(16) unsigned short LDSG[1536 * 8];   // 24 KB
    const int tid = threadIdx.x, lane = tid & 63, wave = tid >> 6;
    const int wr = wave >> 1, wc = wave & 1;
    const int brow = blockIdx.y * 128, bcol = blockIdx.x * 64;
    const int lr = lane & 15, lc = lane >> 4;
    const int Kpart = K / gridDim.z;
    const int kOff  = blockIdx.z * Kpart;

    const unsigned short* gp[6];
    #pragma unroll
    for (int r = 0; r < 6; ++r) {
        int S = r * 256 + tid;
        if (S < 512) {
            gp[r] = &Ah[(size_t)(brow + (S & 127)) * K + kOff + (S >> 7) * 8];
        } else if (S < 1024) {
            int s = S - 512;
            gp[r] = &Al[(size_t)(brow + (s & 127)) * K + kOff + (s >> 7) * 8];
        } else if (S < 1280) {
            int s = S - 1024;
            gp[r] = &Bh[(size_t)(bcol + (s & 63)) * K + kOff + (s >> 6) * 8];
        } else {
            int s = S - 1280;
            gp[r] = &Bl[(size_t)(bcol + (s & 63)) * K + kOff + (s >> 6) * 8];
        }
    }

    f32x4 acc[4][2];
    #pragma unroll
    for (int a = 0; a < 4; ++a) {
        acc[a][0] = (f32x4){0.f, 0.f, 0.f, 0.f};
        acc[a][1] = (f32x4){0.f, 0.f, 0.f, 0.f};
    }

    const int nt = Kpart >> 5;
    for (int kt = 0; kt < nt; ++kt) {
        #pragma unroll
        for (int r = 0; r < 6; ++r) {
            gload16(gp[r], &LDSG[(r * 256 + wave * 64) * 8]);
            gp[r] += 32;
        }
        __syncthreads();

        short8 fah[4], fal[4], fbh[2], fbl[2];
        #pragma unroll
        for (int mi = 0; mi < 4; ++mi) {
            int arow = wr * 64 + mi * 16 + lr;
            fah[mi] = *(short8*)&LDSG[(lc * 128 + arow) * 8];
            fal[mi] = *(short8*)&LDSG[(512 + lc * 128 + arow) * 8];
        }
        #pragma unroll
        for (int ni = 0; ni < 2; ++ni) {
            int brw = wc * 32 + ni * 16 + lr;
            fbh[ni] = *(short8*)&LDSG[(1024 + lc * 64 + brw) * 8];
            fbl[ni] = *(short8*)&LDSG[(1280 + lc * 64 + brw) * 8];
        }
        #pragma unroll
        for (int mi = 0; mi < 4; ++mi)
            #pragma unroll
            for (int ni = 0; ni < 2; ++ni) {
                acc[mi][ni] = __builtin_amdgcn_mfma_f32_16x16x32_bf16(fah[mi], fbh[ni], acc[mi][ni], 0, 0, 0);
                acc[mi][ni] = __builtin_amdgcn_mfma_f32_16x16x32_bf16(fal[mi], fbh[ni], acc[mi][ni], 0, 0, 0);
                acc[mi][ni] = __builtin_amdgcn_mfma_f32_16x16x32_bf16(fah[mi], fbl[ni], acc[mi][ni], 0, 0, 0);
            }
        __syncthreads();
    }

    #pragma unroll
    for (int mi = 0; mi < 4; ++mi)
        #pragma unroll
        for (int ni = 0; ni < 2; ++ni) {
            int col  = bcol + wc * 32 + ni * 16 + lr;
            int rowb = brow + wr * 64 + mi * 16 + lc * 4;
            #pragma unroll
            for (int r = 0; r < 4; ++r)
                atomicAdd(&C[(size_t)(rowb + r) * N + col], acc[mi][ni][r]);
        }
}

// ---------------------------------------------------------------------------
// Single-pass bf16 MFMA GEMM: C += A * B^T, split-K via blockIdx.z, atomicAdd.
// Same skeleton, 768 slots (12 KB): [0,512) A, [512,768) B.
// ---------------------------------------------------------------------------
__global__ __launch_bounds__(256) void gemm1s(const unsigned short* __restrict__ A,
                                              const unsigned short* __restrict__ B,
                                              float* __restrict__ C,
                                              int M, int N, int K) {
    __shared__ __align__(16) unsigned short LDSG[768 * 8];   // 12 KB
    const int tid = threadIdx.x, lane = tid & 63, wave = tid >> 6;
    const int wr = wave >> 1, wc = wave & 1;
    const int brow = blockIdx.y * 128, bcol = blockIdx.x * 64;
    const int lr = lane & 15, lc = lane >> 4;
    const int Kpart = K / gridDim.z;
    const int kOff  = blockIdx.z * Kpart;

    const unsigned short* gp[3];
    #pragma unroll
    for (int r = 0; r < 3; ++r) {
        int S = r * 256 + tid;
        if (S < 512) {
            gp[r] = &A[(size_t)(brow + (S & 127)) * K + kOff + (S >> 7) * 8];
        } else {
            int s = S - 512;
            gp[r] = &B[(size_t)(bcol + (s & 63)) * K + kOff + (s >> 6) * 8];
        }
    }

    f32x4 acc[4][2];
    #pragma unroll
    for (int a = 0; a < 4; ++a) {
        acc[a][0] = (f32x4){0.f, 0.f, 0.f, 0.f};
        acc[a][1] = (f32x4){0.f, 0.f, 0.f, 0.f};
    }

    const int nt = Kpart >> 5;
    for (int kt = 0; kt < nt; ++kt) {
        #pragma unroll
        for (int r = 0; r < 3; ++r) {
            gload16(gp[r], &LDSG[(r * 256 + wave * 64) * 8]);
            gp[r] += 32;
        }
        __syncthreads();

        short8 fa[4], fb[2];
        #pragma unroll
        for (int mi = 0; mi < 4; ++mi) {
            int arow = wr * 64 + mi * 16 + lr;
            fa[mi] = *(short8*)&LDSG[(lc * 128 + arow) * 8];
        }
        #pragma unroll
        for (int ni = 0; ni < 2; ++ni) {
            int brw = wc * 32 + ni * 16 + lr;
            fb[ni] = *(short8*)&LDSG[(512 + lc * 64 + brw) * 8];
        }
        #pragma unroll
        for (int mi = 0; mi < 4; ++mi)
            #pragma unroll
            for (int ni = 0; ni < 2; ++ni)
                acc[mi][ni] = __builtin_amdgcn_mfma_f32_16x16x32_bf16(fa[mi], fb[ni], acc[mi][ni], 0, 0, 0);
        __syncthreads();
    }

    #pragma unroll
    for (int mi = 0; mi < 4; ++mi)
        #pragma unroll
        for (int ni = 0; ni < 2; ++ni) {
            int col  = bcol + wc * 32 + ni * 16 + lr;
            int rowb = brow + wr * 64 + mi * 16 + lc * 4;
            #pragma unroll
            for (int r = 0; r < 4; ++r)
                atomicAdd(&C[(size_t)(rowb + r) * N + col], acc[mi][ni][r]);
        }
}

// ---------------------------------------------------------------------------
// Compress: ck[m]=rope(mean(k+pe), pos=32m), cv[m]=mean(v). Un-roped k input.
// ---------------------------------------------------------------------------
__global__ void compress_kernel(const float* __restrict__ k,
                                const float* __restrict__ v,
                                const float* __restrict__ pe,
                                float* __restrict__ ck,
                                float* __restrict__ cv) {
    int m = blockIdx.x, d = threadIdx.x;
    float sk = 0.f, sv = 0.f, sp = 0.f;
    for (int s = 0; s < 32; ++s) {
        sk += k[(size_t)(m * 32 + s) * DIM + d];
        sv += v[(size_t)(m * 32 + s) * DIM + d];
        sp += pe[s * DIM + d];
    }
    float ckv = (sk + sp) * (1.0f / 32.0f);
    cv[m * DIM + d] = sv * (1.0f / 32.0f);
    __shared__ float tmp[DIM];
    tmp[d] = ckv;
    __syncthreads();
    int j = d & 63;
    float inv = powf(10000.0f, -(float)(2 * j) / 128.0f);
    float ang = (float)(m * 32) * inv;
    float c = cosf(ang), s = sinf(ang);
    float x1 = tmp[j], x2 = tmp[j + 64];
    ck[m * DIM + d] = (d < 64) ? (x1 * c - x2 * s) : (x2 * c + x1 * s);
}

__global__ void rope_qk(float* __restrict__ q, float* __restrict__ k) {
    int i = blockIdx.x, j = threadIdx.x;
    float inv = powf(10000.0f, -(float)(2 * j) / 128.0f);
    float ang = (float)i * inv;
    float c = cosf(ang), s = sinf(ang);
    for (int h = 0; h < NHQ; ++h) {
        float* p = q + ((size_t)i * NHQ + h) * DIM;
        float x1 = p[j], x2 = p[j + 64];
        p[j]      = x1 * c - x2 * s;
        p[j + 64] = x2 * c + x1 * s;
    }
    float* p = k + (size_t)i * DIM;
    float x1 = p[j], x2 = p[j + 64];
    p[j]      = x1 * c - x2 * s;
    p[j + 64] = x2 * c + x1 * s;
}

// ---------------------------------------------------------------------------
// prep: qb16 = bf16(q * SCALE) [2048][2048]; kb16 = bf16(k) [2048][128]
// ---------------------------------------------------------------------------
__global__ __launch_bounds__(256) void prep_cast(const float* __restrict__ q,
                                                 const float* __restrict__ k,
                                                 unsigned short* __restrict__ qb,
                                                 unsigned short* __restrict__ kb) {
    int i = blockIdx.x, t = threadIdx.x;
    {
        int d0 = t * 8;
        float4 a = *(const float4*)&q[(size_t)i * HIDDEN + d0];
        float4 b = *(const float4*)&q[(size_t)i * HIDDEN + d0 + 4];
        ushort4 ha, hb;
        ha.x = f2bf(a.x * SCALEF); ha.y = f2bf(a.y * SCALEF);
        ha.z = f2bf(a.z * SCALEF); ha.w = f2bf(a.w * SCALEF);
        hb.x = f2bf(b.x * SCALEF); hb.y = f2bf(b.y * SCALEF);
        hb.z = f2bf(b.z * SCALEF); hb.w = f2bf(b.w * SCALEF);
        *(ushort4*)&qb[(size_t)i * HIDDEN + d0] = ha;
        *(ushort4*)&qb[(size_t)i * HIDDEN + d0 + 4] = hb;
    }
    if (t < 16) {
        int d0 = t * 8;
        float4 a = *(const float4*)&k[(size_t)i * DIM + d0];
        float4 b = *(const float4*)&k[(size_t)i * DIM + d0 + 4];
        ushort4 ha, hb;
        ha.x = f2bf(a.x); ha.y = f2bf(a.y); ha.z = f2bf(a.z); ha.w = f2bf(a.w);
        hb.x = f2bf(b.x); hb.y = f2bf(b.y); hb.z = f2bf(b.z); hb.w = f2bf(b.w);
        *(ushort4*)&kb[(size_t)i * DIM + d0] = ha;
        *(ushort4*)&kb[(size_t)i * DIM + d0 + 4] = hb;
    }
}

// ---------------------------------------------------------------------------
// vT16[128][2048] = bf16(v[2048][128])^T. 32x32 tiles, grid (4, 64).
// ---------------------------------------------------------------------------
__global__ __launch_bounds__(256) void tcast_v(const float* __restrict__ v,
                                               unsigned short* __restrict__ vT) {
    __shared__ float tbuf[32][33];
    const int r0 = blockIdx.y * 32, c0 = blockIdx.x * 32;
    const int ty = threadIdx.x >> 3, tx = threadIdx.x & 7;
    float4 val = *(const float4*)&v[(size_t)(r0 + ty) * DIM + c0 + tx * 4];
    tbuf[ty][tx * 4 + 0] = val.x; tbuf[ty][tx * 4 + 1] = val.y;
    tbuf[ty][tx * 4 + 2] = val.z; tbuf[ty][tx * 4 + 3] = val.w;
    __syncthreads();
    ushort4 o;
    o.x = f2bf(tbuf[tx * 4 + 0][ty]);
    o.y = f2bf(tbuf[tx * 4 + 1][ty]);
    o.z = f2bf(tbuf[tx * 4 + 2][ty]);
    o.w = f2bf(tbuf[tx * 4 + 3][ty]);
    *(ushort4*)&vT[(size_t)(c0 + ty) * SEQ + r0 + tx * 4] = o;
}

// ---------------------------------------------------------------------------
// Compressed attention per token: writes comb (fp32, full init) + blk scores.
// ---------------------------------------------------------------------------
__global__ __launch_bounds__(256) void cmp_flash(const float* __restrict__ q,
                                                 const float* __restrict__ ck,
                                                 const float* __restrict__ cv,
                                                 const float* __restrict__ gl,
                                                 float* __restrict__ comb,
                                                 float* __restrict__ blk) {
    const int i = blockIdx.x, tid = threadIdx.x, wave = tid >> 6, lane = tid & 63;
    __shared__ float Qs[16][132];
    __shared__ float KV[64][132];
    __shared__ float ss[16][66];

    for (int t = tid; t < 512; t += 256) {
        int r = t >> 5, c4 = (t & 31) * 4;
        *(float4*)&Qs[r][c4] = *(const float4*)&q[(size_t)i * HIDDEN + r * DIM + c4];
    }
    for (int t = tid; t < 2048; t += 256) {
        int r = t >> 5, c4 = (t & 31) * 4;
        *(float4*)&KV[r][c4] = *(const float4*)&ck[(size_t)r * DIM + c4];
    }
    __syncthreads();

    const int hi = lane & 15, mg = lane >> 4;
    float s4[4] = {0.f, 0.f, 0.f, 0.f};
    for (int d = 0; d < 128; d += 4) {
        float4 qv = *(float4*)&Qs[hi][d];
        #pragma unroll
        for (int jj = 0; jj < 4; ++jj) {
            float4 kv = *(float4*)&KV[wave * 16 + mg * 4 + jj][d];
            s4[jj] = fmaf(qv.x, kv.x, fmaf(qv.y, kv.y, fmaf(qv.z, kv.z, fmaf(qv.w, kv.w, s4[jj]))));
        }
    }
    #pragma unroll
    for (int jj = 0; jj < 4; ++jj) {
        int m = wave * 16 + mg * 4 + jj;
        ss[hi][m] = (i >= m * 32 + 31) ? s4[jj] * SCALEF : NEGF;
    }
    __syncthreads();

    for (int hh = 0; hh < 4; ++hh) {
        int h = wave * 4 + hh;
        float val = ss[h][lane];
        float mx = val;
        for (int o = 32; o; o >>= 1) mx = fmaxf(mx, __shfl_xor(mx, o));
        float e = (val <= NEGF * 0.5f) ? 0.f : __expf(val - mx);
        float z = e;
        for (int o = 32; o; o >>= 1) z += __shfl_xor(z, o);
        ss[h][lane] = (z > 0.f) ? e * (1.0f / z) : 0.f;
    }
    __syncthreads();

    if (tid < 64) {
        float sb = 0.f;
        for (int h = 0; h < 16; ++h) sb += ss[h][tid];
        blk[(size_t)i * NCB + tid] = sb;
    }

    for (int t = tid; t < 2048; t += 256) {
        int r = t >> 5, c4 = (t & 31) * 4;
        *(float4*)&KV[r][c4] = *(const float4*)&cv[(size_t)r * DIM + c4];
    }
    __syncthreads();

    const int h2 = tid & 15, dg = tid >> 4;
    float o8[8] = {0.f,0.f,0.f,0.f,0.f,0.f,0.f,0.f};
    for (int kk = 0; kk < 64; ++kk) {
        float p = ss[h2][kk];
        float4 va = *(float4*)&KV[kk][dg * 8];
        float4 vb = *(float4*)&KV[kk][dg * 8 + 4];
        o8[0] = fmaf(p, va.x, o8[0]); o8[1] = fmaf(p, va.y, o8[1]);
        o8[2] = fmaf(p, va.z, o8[2]); o8[3] = fmaf(p, va.w, o8[3]);
        o8[4] = fmaf(p, vb.x, o8[4]); o8[5] = fmaf(p, vb.y, o8[5]);
        o8[6] = fmaf(p, vb.z, o8[6]); o8[7] = fmaf(p, vb.w, o8[7]);
    }
    float g0 = sigmoidf_(gl[(size_t)i * 48 + h2 * 3 + 0]);
    #pragma unroll
    for (int x = 0; x < 8; ++x)
        comb[(size_t)i * HIDDEN + h2 * DIM + dg * 8 + x] = g0 * o8[x];
}

// ---------------------------------------------------------------------------
// Top-k (exact jax.lax.top_k tie semantics).
// ---------------------------------------------------------------------------
__global__ __launch_bounds__(256) void topk2(const float* __restrict__ blk,
                                             int* __restrict__ oidx) {
    __shared__ float L[256][68];
    int base = blockIdx.x * 256;
    for (int t = threadIdx.x; t < 256 * 16; t += 256) {
        int r = t >> 4, c4 = (t & 15) * 4;
        *(float4*)&L[r][c4] = *(const float4*)&blk[(size_t)(base + r) * NCB + c4];
    }
    __syncthreads();
    int i = base + threadIdx.x;
    int tb = i >> 5;
    unsigned long long used = 0ull;
    for (int t = 0; t < NTOP; ++t) {
        float best = -3e38f; int bi = 0;
        for (int m = 0; m < NCB; ++m) {
            if ((used >> m) & 1ull) continue;
            float s = L[threadIdx.x][m];
            if (m > tb) s = NEGF;
            if (m == 0 || (m <= tb && m > tb - 2)) s = 1e30f;
            if (s > best) { best = s; bi = m; }
        }
        used |= 1ull << bi;
        oidx[i * NTOP + t] = bi;
    }
}

// ---------------------------------------------------------------------------
// Sparse top-k attention via MFMA (swapped QK^T), bf16 inputs, per-token block.
// ---------------------------------------------------------------------------
__global__ __launch_bounds__(256) void sparse_mfma(const unsigned short* __restrict__ qb,
                                                   const unsigned short* __restrict__ kb,
                                                   const unsigned short* __restrict__ vT,
                                                   const int* __restrict__ idx,
                                                   const float* __restrict__ gl,
                                                   float* __restrict__ comb) {
    const int i = blockIdx.x;
    const int tid = threadIdx.x, wave = tid >> 6, lane = tid & 63;
    const int c = lane & 15, g = lane >> 4;

    __shared__ unsigned short Qs[16 * 128];
    __shared__ unsigned short Ks[32 * 128];
    __shared__ unsigned short VtS[128 * 36];
    __shared__ float Ps[4][32][17];
    __shared__ int sb[8];

    if (tid < 8) sb[tid] = idx[i * NTOP + tid];
    {
        int r = tid >> 4, d0 = (tid & 15) * 8;
        short8 v = *(const short8*)&qb[(size_t)i * HIDDEN + r * DIM + d0];
        *(short8*)&Qs[r * 128 + (d0 ^ ((r & 7) << 3))] = v;
    }
    __syncthreads();

    short8 Qf[4];
    #pragma unroll
    for (int kc = 0; kc < 4; ++kc) {
        int d0 = kc * 32 + g * 8;
        Qf[kc] = *(short8*)&Qs[c * 128 + (d0 ^ ((c & 7) << 3))];
    }

    float m = -3e38f, l = 0.f;
    f32x4 accO[2];
    accO[0] = (f32x4){0.f, 0.f, 0.f, 0.f};
    accO[1] = (f32x4){0.f, 0.f, 0.f, 0.f};

    for (int ch = 0; ch < 8; ++ch) {
        int kbase = sb[ch] * 32;
        {
            int r = tid >> 3;
            int d0 = (tid & 7) * 16;
            #pragma unroll
            for (int s = 0; s < 2; ++s) {
                int dd = d0 + s * 8;
                short8 v = *(const short8*)&kb[(size_t)(kbase + r) * DIM + dd];
                *(short8*)&Ks[r * 128 + (dd ^ ((r & 7) << 3))] = v;
            }
            int d = tid >> 1;
            int k0 = (tid & 1) * 16;
            short8 v0 = *(const short8*)&vT[(size_t)d * SEQ + kbase + k0];
            short8 v1 = *(const short8*)&vT[(size_t)d * SEQ + kbase + k0 + 8];
            *(short8*)&VtS[d * 36 + k0] = v0;
            *(short8*)&VtS[d * 36 + k0 + 8] = v1;
        }
        __syncthreads();

        f32x4 accS[2];
        accS[0] = (f32x4){0.f, 0.f, 0.f, 0.f};
        accS[1] = (f32x4){0.f, 0.f, 0.f, 0.f};
        #pragma unroll
        for (int kf = 0; kf < 2; ++kf) {
            int krow = kf * 16 + c;
            #pragma unroll
            for (int kc = 0; kc < 4; ++kc) {
                int d0 = kc * 32 + g * 8;
                short8 Kf = *(short8*)&Ks[krow * 128 + (d0 ^ ((krow & 7) << 3))];
                accS[kf] = __builtin_amdgcn_mfma_f32_16x16x32_bf16(Kf, Qf[kc], accS[kf], 0, 0, 0);
            }
        }

        float s8[8];
        float mx = -3e38f;
        #pragma unroll
        for (int kf = 0; kf < 2; ++kf)
            #pragma unroll
            for (int r = 0; r < 4; ++r) {
                int pos = kbase + kf * 16 + g * 4 + r;
                float sv = (pos <= i) ? accS[kf][r] : -3e38f;
                s8[kf * 4 + r] = sv;
                mx = fmaxf(mx, sv);
            }
        mx = fmaxf(mx, __shfl_xor(mx, 16));
        mx = fmaxf(mx, __shfl_xor(mx, 32));
        float mnew = fmaxf(m, mx);
        float corr = __expf(m - mnew);
        float psum = 0.f;
        float p8[8];
        #pragma unroll
        for (int j = 0; j < 8; ++j) {
            float p = (s8[j] <= -1e37f) ? 0.f : __expf(s8[j] - mnew);
            p8[j] = p;
            psum += p;
        }
        psum += __shfl_xor(psum, 16);
        psum += __shfl_xor(psum, 32);
        l = l * corr + psum;
        m = mnew;

        #pragma unroll
        for (int kf = 0; kf < 2; ++kf)
            #pragma unroll
            for (int r = 0; r < 4; ++r)
                Ps[wave][kf * 16 + g * 4 + r][c] = p8[kf * 4 + r];

        #pragma unroll
        for (int r = 0; r < 4; ++r) {
            float cr = __shfl(corr, g * 4 + r);
            accO[0][r] *= cr;
            accO[1][r] *= cr;
        }

        short8 paf;
        #pragma unroll
        for (int j = 0; j < 8; ++j)
            paf[j] = (short)f2bf(Ps[wave][g * 8 + j][c]);

        #pragma unroll
        for (int nf = 0; nf < 2; ++nf) {
            short8 vf = *(short8*)&VtS[(wave * 32 + nf * 16 + c) * 36 + g * 8];
            accO[nf] = __builtin_amdgcn_mfma_f32_16x16x32_bf16(paf, vf, accO[nf], 0, 0, 0);
        }
        __syncthreads();
    }

    #pragma unroll
    for (int r = 0; r < 4; ++r) {
        int head = g * 4 + r;
        float lq = __shfl(l, head);
        float g1 = sigmoidf_(gl[(size_t)i * 48 + head * 3 + 1]);
        float sc = g1 / lq;
        #pragma unroll
        for (int nf = 0; nf < 2; ++nf)
            comb[(size_t)i * HIDDEN + head * DIM + wave * 32 + nf * 16 + c] += accO[nf][r] * sc;
    }
}

// ---------------------------------------------------------------------------
// Sliding-window attention via MFMA (swapped QK^T), bf16 inputs.
// ---------------------------------------------------------------------------
__global__ __launch_bounds__(256) void swin_mfma(const unsigned short* __restrict__ qb,
                                                 const unsigned short* __restrict__ kb,
                                                 const unsigned short* __restrict__ vT,
                                                 const float* __restrict__ gl,
                                                 float* __restrict__ comb) {
    const int h = blockIdx.x, qt = blockIdx.y;
    const int q0 = qt * 64;
    const int s0 = (q0 - WINSZ > 0) ? (q0 - WINSZ) : 0;
    const int nch = (q0 + 64 - s0) >> 5;
    const int tid = threadIdx.x, wave = tid >> 6, lane = tid & 63;
    const int c = lane & 15, g = lane >> 4;

    __shared__ unsigned short Qs[64 * 128];
    __shared__ unsigned short Ks[32 * 128];
    __shared__ unsigned short VtS[128 * 36];
    __shared__ float Ps[4][32][17];

    {
        int r = tid >> 2;
        int base = (tid & 3) * 32;
        #pragma unroll
        for (int s = 0; s < 4; ++s) {
            int d0 = base + s * 8;
            short8 v = *(const short8*)&qb[(size_t)(q0 + r) * HIDDEN + h * DIM + d0];
            *(short8*)&Qs[r * 128 + (d0 ^ ((r & 7) << 3))] = v;
        }
    }
    __syncthreads();

    short8 Qf[4];
    {
        int qrow = wave * 16 + c;
        #pragma unroll
        for (int kc = 0; kc < 4; ++kc) {
            int d0 = kc * 32 + g * 8;
            Qf[kc] = *(short8*)&Qs[qrow * 128 + (d0 ^ ((qrow & 7) << 3))];
        }
    }

    const int gq = q0 + wave * 16 + c;
    float m = -3e38f, l = 0.f;
    f32x4 accO[8];
    #pragma unroll
    for (int nf = 0; nf < 8; ++nf) accO[nf] = (f32x4){0.f, 0.f, 0.f, 0.f};

    for (int ch = 0; ch < nch; ++ch) {
        int kbase = s0 + ch * 32;
        {
            int r = tid >> 3;
            int d0 = (tid & 7) * 16;
            #pragma unroll
            for (int s = 0; s < 2; ++s) {
                int dd = d0 + s * 8;
                short8 v = *(const short8*)&kb[(size_t)(kbase + r) * DIM + dd];
                *(short8*)&Ks[r * 128 + (dd ^ ((r & 7) << 3))] = v;
            }
            int d = tid >> 1;
            int k0 = (tid & 1) * 16;
            short8 v0 = *(const short8*)&vT[(size_t)d * SEQ + kbase + k0];
            short8 v1 = *(const short8*)&vT[(size_t)d * SEQ + kbase + k0 + 8];
            *(short8*)&VtS[d * 36 + k0] = v0;
            *(short8*)&VtS[d * 36 + k0 + 8] = v1;
        }
        __syncthreads();

        f32x4 accS[2];
        accS[0] = (f32x4){0.f, 0.f, 0.f, 0.f};
        accS[1] = (f32x4){0.f, 0.f, 0.f, 0.f};
        #pragma unroll
        for (int kf = 0; kf < 2; ++kf) {
            int krow = kf * 16 + c;
            #pragma unroll
            for (int kc = 0; kc < 4; ++kc) {
                int d0 = kc * 32 + g * 8;
                short8 Kf = *(short8*)&Ks[krow * 128 + (d0 ^ ((krow & 7) << 3))];
                accS[kf] = __builtin_amdgcn_mfma_f32_16x16x32_bf16(Kf, Qf[kc], accS[kf], 0, 0, 0);
            }
        }

        float s8[8];
        float mx = -3e38f;
        #pragma unroll
        for (int kf = 0; kf < 2; ++kf)
            #pragma unroll
            for (int r = 0; r < 4; ++r) {
                int pos = kbase + kf * 16 + g * 4 + r;
                bool ok = (pos <= gq) && (pos >= gq - WINSZ);
                float sv = ok ? accS[kf][r] : -3e38f;
                s8[kf * 4 + r] = sv;
                mx = fmaxf(mx, sv);
            }
        mx = fmaxf(mx, __shfl_xor(mx, 16));
        mx = fmaxf(mx, __shfl_xor(mx, 32));
        float mnew = fmaxf(m, mx);
        float corr = __expf(m - mnew);
        float psum = 0.f;
        float p8[8];
        #pragma unroll
        for (int j = 0; j < 8; ++j) {
            float p = (s8[j] <= -1e37f) ? 0.f : __expf(s8[j] - mnew);
            p8[j] = p;
            psum += p;
        }
        psum += __shfl_xor(psum, 16);
        psum += __shfl_xor(psum, 32);
        l = l * corr + psum;
        m = mnew;

        #pragma unroll
        for (int kf = 0; kf < 2; ++kf)
            #pragma unroll
            for (int r = 0; r < 4; ++r)
                Ps[wave][kf * 16 + g * 4 + r][c] = p8[kf * 4 + r];

        #pragma unroll
        for (int r = 0; r < 4; ++r) {
            float cr = __shfl(corr, g * 4 + r);
            #pragma unroll
            for (int nf = 0; nf < 8; ++nf)
                accO[nf][r] *= cr;
        }

        short8 paf;
        #pragma unroll
        for (int j = 0; j < 8; ++j)
            paf[j] = (short)f2bf(Ps[wave][g * 8 + j][c]);

        #pragma unroll
        for (int nf = 0; nf < 8; ++nf) {
            short8 vf = *(short8*)&VtS[(nf * 16 + c) * 36 + g * 8];
            accO[nf] = __builtin_amdgcn_mfma_f32_16x16x32_bf16(paf, vf, accO[nf], 0, 0, 0);
        }
        __syncthreads();
    }

    #pragma unroll
    for (int r = 0; r < 4; ++r) {
        float lq = __shfl(l, g * 4 + r);
        int token = q0 + wave * 16 + g * 4 + r;
        float g2 = sigmoidf_(gl[(size_t)token * 48 + h * 3 + 2]);
        float sc = g2 / lq;
        #pragma unroll
        for (int nf = 0; nf < 8; ++nf)
            comb[(size_t)token * HIDDEN + h * DIM + nf * 16 + c] += accO[nf][r] * sc;
    }
}

// ---------------------------------------------------------------------------
extern "C" void kernel_launch(void* const* d_in, const int* in_sizes, int n_in,
                              void* d_out, int out_size, void* d_ws, size_t ws_size,
                              hipStream_t stream) {
    const float* x  = (const float*)d_in[0];
    const float* Wq = (const float*)d_in[2];
    const float* Wk = (const float*)d_in[3];
    const float* Wv = (const float*)d_in[4];
    const float* Wo = (const float*)d_in[5];
    const float* Wg = (const float*)d_in[6];
    const float* pe = (const float*)d_in[7];
    float* out = (float*)d_out;

    // workspace layout (36.7 MB, proven footprint)
    char* w = (char*)d_ws;
    float* q    = (float*)(w);               // 16 MB  (early: kvg scratch; late: comb bf16)
    float* comb = (float*)(w + 16777216);    // 16 MB  (early: x hi/lo; late: Wo bf16)
    float* kbuf = (float*)(w + 33554432);    // 1 MB
    float* vbuf = (float*)(w + 34603008);    // 1 MB
    float* gl   = (float*)(w + 35651584);    // 384 KB
    float* ck   = (float*)(w + 36044800);    // 32 KB
    float* cv   = (float*)(w + 36077568);    // 32 KB
    float* blk  = (float*)(w + 36110336);    // 512 KB
    int*   idx  = (int*)  (w + 36634624);    // 64 KB

    // scratch aliases
    unsigned short* Xh   = (unsigned short*)comb;            // x hi/lo (comb region)
    unsigned short* Xl   = Xh + 4194304;
    unsigned short* Wqh  = (unsigned short*)out;             // d_out dead until final
    unsigned short* Wql  = Wqh + 4194304;
    unsigned short* Ch   = (unsigned short*)q;               // q dead after cmp_flash
    unsigned short* Woh  = (unsigned short*)comb;            // comb dead after cast
    float*          kvgOut = q;                              // q region (3 MB)
    unsigned short* kvgBth = (unsigned short*)(w + 4194304); // q region +4 MB
    unsigned short* kvgBtl = kvgBth + 786432;
    // bf16 attention inputs (d_out region, after q-proj consumes Wqh/Wql)
    unsigned short* qb16 = (unsigned short*)out;             // 8 MB
    unsigned short* kb16 = qb16 + 4194304;                   // 0.5 MB
    unsigned short* vT16 = kb16 + 262144;                    // 0.5 MB

    // 1. split x
    split_pair<<<4096, 256, 0, stream>>>(x, Xh, Xl);

    // 2. combined k/v/gate projection (split-K=4, atomic accumulate)
    tsplit_g<<<dim3(4, 64), 256, 0, stream>>>(Wk, kvgBth, kvgBtl, 128, 0);
    tsplit_g<<<dim3(4, 64), 256, 0, stream>>>(Wv, kvgBth, kvgBtl, 128, 128);
    tsplit_g<<<dim3(2, 64), 256, 0, stream>>>(Wg, kvgBth, kvgBtl, 48,  256);
    zero_f4<<<768, 256, 0, stream>>>(kvgOut);                       // 2048*384
    gemm3s<<<dim3(KVGN / 64, 16, 4), 256, 0, stream>>>(Xh, Xl, kvgBth, kvgBtl,
                                                       kvgOut, SEQ, KVGN, HIDDEN);
    unpack_kvg<<<SEQ, 256, 0, stream>>>(kvgOut, kbuf, vbuf, gl);

    // 3. q projection (split-K=2, atomic accumulate; zeroing kills kvg scratch)
    tsplit<<<dim3(64, 64), 256, 0, stream>>>(Wq, Wqh, Wql);
    zero_f4<<<4096, 256, 0, stream>>>(q);                           // 2048*2048
    gemm3s<<<dim3(32, 16, 2), 256, 0, stream>>>(Xh, Xl, Wqh, Wql, q,
                                                SEQ, HIDDEN, HIDDEN);

    // 4. compress (un-roped k) then rope q,k
    compress_kernel<<<NCB, DIM, 0, stream>>>(kbuf, vbuf, pe, ck, cv);
    rope_qk<<<SEQ, 64, 0, stream>>>(q, kbuf);

    // 5. bf16 prep for MFMA attention (d_out region now free)
    prep_cast<<<SEQ, 256, 0, stream>>>(q, kbuf, qb16, kb16);
    tcast_v<<<dim3(4, 64), 256, 0, stream>>>(vbuf, vT16);

    // 6. compressed attention -> comb fp32 (full init; Xh/Xl dead) + blk
    cmp_flash<<<SEQ, 256, 0, stream>>>(q, ck, cv, gl, comb, blk);

    // 7. top-k
    topk2<<<SEQ / 256, 256, 0, stream>>>(blk, idx);

    // 8. sparse attention via MFMA (comb += g1*out)
    sparse_mfma<<<SEQ, 256, 0, stream>>>(qb16, kb16, vT16, idx, gl, comb);

    // 9. sliding-window attention via MFMA (comb += g2*out)
    swin_mfma<<<dim3(16, 32), 256, 0, stream>>>(qb16, kb16, vT16, gl, comb);

    // 10. output projection: single-pass bf16 (no selection downstream),
    //     split-K=2 atomic accumulate into zeroed d_out
    cast_bf16<<<4096, 256, 0, stream>>>(comb, Ch);                  // q region (dead)
    tcast<<<dim3(64, 64), 256, 0, stream>>>(Wo, Woh);               // comb region (dead)
    zero_f4<<<4096, 256, 0, stream>>>(out);
    gemm1s<<<dim3(32, 16, 2), 256, 0, stream>>>(Ch, Woh, out, SEQ, HIDDEN, HIDDEN);
}